// Round 1
// baseline (2849.070 us; speedup 1.0000x reference)
//
#include <hip/hip_runtime.h>
#include <hip/hip_bf16.h>
#include <math.h>

#define NN 50000
#define EE 800000
#define ET_ 850000
#define NG 64

// ---- monotone float<->uint encoding for atomicMax-based segment max ----
__device__ __forceinline__ unsigned fenc(float f){
  unsigned u = __float_as_uint(f);
  return (u & 0x80000000u) ? ~u : (u | 0x80000000u);
}
__device__ __forceinline__ float fdec(unsigned u){
  unsigned b = (u & 0x80000000u) ? (u ^ 0x80000000u) : ~u;
  return __uint_as_float(b);
}

// ---------- GEMM: H = X @ W  (X:[N,128], W:[128,128]) ----------
__global__ __launch_bounds__(256) void gemm_xw(const float* __restrict__ X,
    const float* __restrict__ W, float* __restrict__ H, int N){
  __shared__ float Ws[64*128];   // 32 KB (half of W's k-rows at a time)
  __shared__ float Xs[64*128];   // 32 KB (64 rows of X, full k)
  const int t = threadIdx.x;
  const int row0 = blockIdx.x * 64;
  for (int i = t*4; i < 64*128; i += 1024){
    int r = i >> 7, c = i & 127;
    int gr = row0 + r;
    float4 v = make_float4(0.f,0.f,0.f,0.f);
    if (gr < N) v = *(const float4*)(X + (size_t)gr*128 + c);
    *(float4*)(Xs + i) = v;
  }
  const int col = t & 127;
  const int rg  = (t >> 7) * 32;   // this thread's 32-row group
  float acc[32];
  #pragma unroll
  for (int r=0;r<32;r++) acc[r]=0.f;
  for (int ko=0; ko<128; ko+=64){
    __syncthreads();
    for (int i = t*4; i < 64*128; i += 1024)
      *(float4*)(Ws + i) = *(const float4*)(W + (size_t)ko*128 + i);
    __syncthreads();
    for (int k=0;k<64;k+=4){
      float w0 = Ws[(k+0)*128+col];
      float w1 = Ws[(k+1)*128+col];
      float w2 = Ws[(k+2)*128+col];
      float w3 = Ws[(k+3)*128+col];
      #pragma unroll
      for (int r=0;r<32;r++){
        float4 xv = *(const float4*)(Xs + (rg+r)*128 + ko + k);
        acc[r] += xv.x*w0 + xv.y*w1 + xv.z*w2 + xv.w*w3;
      }
    }
  }
  for (int r=0;r<32;r++){
    int gr = row0 + rg + r;
    if (gr < N) H[(size_t)gr*128 + col] = acc[r];
  }
}

// ---------- per-(node,head) attention logit prep ----------
__global__ __launch_bounds__(256) void attn_prep(const float* __restrict__ hbuf,
    const float* __restrict__ av, const float* __restrict__ dv,
    float* __restrict__ esrc, float* __restrict__ edst){
  int idx = blockIdx.x*256 + threadIdx.x;
  if (idx >= NN*4) return;
  int n = idx >> 2, hh = idx & 3;
  const float* hp = hbuf + (size_t)n*128 + hh*32;
  const float* ap = av + hh*32;
  const float* dp = dv + hh*32;
  float ss = 0.f, ds = 0.f;
  #pragma unroll
  for (int k=0;k<32;k+=4){
    float4 hv = *(const float4*)(hp + k);
    float4 a4 = *(const float4*)(ap + k);
    float4 d4 = *(const float4*)(dp + k);
    ss += hv.x*a4.x + hv.y*a4.y + hv.z*a4.z + hv.w*a4.w;
    ds += hv.x*d4.x + hv.y*d4.y + hv.z*d4.z + hv.w*d4.w;
  }
  esrc[idx] = ss; edst[idx] = ds;
}

// ---------- edge pass A: logits + segment max ----------
__global__ __launch_bounds__(256) void edge_logits(const int* __restrict__ ei,
    const float* __restrict__ esrc, const float* __restrict__ edst,
    float* __restrict__ ebuf, unsigned* __restrict__ mbuf){
  int i = blockIdx.x*256 + threadIdx.x;
  if (i >= ET_) return;
  int s, d;
  if (i < EE){ s = ei[i]; d = ei[EE + i]; } else { s = i - EE; d = s; }
  float4 es = *(const float4*)(esrc + (size_t)s*4);
  float4 ed = *(const float4*)(edst + (size_t)d*4);
  float4 e;
  e.x = es.x + ed.x; e.x = (e.x > 0.f) ? e.x : 0.2f*e.x;
  e.y = es.y + ed.y; e.y = (e.y > 0.f) ? e.y : 0.2f*e.y;
  e.z = es.z + ed.z; e.z = (e.z > 0.f) ? e.z : 0.2f*e.z;
  e.w = es.w + ed.w; e.w = (e.w > 0.f) ? e.w : 0.2f*e.w;
  *(float4*)(ebuf + (size_t)i*4) = e;
  atomicMax(mbuf + (size_t)d*4+0, fenc(e.x));
  atomicMax(mbuf + (size_t)d*4+1, fenc(e.y));
  atomicMax(mbuf + (size_t)d*4+2, fenc(e.z));
  atomicMax(mbuf + (size_t)d*4+3, fenc(e.w));
}

// ---------- edge pass B: exp + denom ----------
__global__ __launch_bounds__(256) void edge_exp(const int* __restrict__ ei,
    const unsigned* __restrict__ mbuf, float* __restrict__ ebuf,
    float* __restrict__ denom){
  int i = blockIdx.x*256 + threadIdx.x;
  if (i >= ET_) return;
  int d = (i < EE) ? ei[EE + i] : (i - EE);
  float4 e = *(const float4*)(ebuf + (size_t)i*4);
  float4 ex;
  ex.x = expf(e.x - fdec(mbuf[(size_t)d*4+0]));
  ex.y = expf(e.y - fdec(mbuf[(size_t)d*4+1]));
  ex.z = expf(e.z - fdec(mbuf[(size_t)d*4+2]));
  ex.w = expf(e.w - fdec(mbuf[(size_t)d*4+3]));
  *(float4*)(ebuf + (size_t)i*4) = ex;
  unsafeAtomicAdd(denom + (size_t)d*4+0, ex.x);
  unsafeAtomicAdd(denom + (size_t)d*4+1, ex.y);
  unsafeAtomicAdd(denom + (size_t)d*4+2, ex.z);
  unsafeAtomicAdd(denom + (size_t)d*4+3, ex.w);
}

// ---------- edge pass C: alpha-weighted scatter aggregate (1 wave / edge) ----------
__global__ __launch_bounds__(256) void edge_aggregate(const int* __restrict__ ei,
    const float* __restrict__ hbuf, const float* __restrict__ exbuf,
    const float* __restrict__ denom, float* __restrict__ agg){
  int wid  = blockIdx.x*4 + (threadIdx.x >> 6);
  int lane = threadIdx.x & 63;
  if (wid >= ET_) return;
  int s, d;
  if (wid < EE){ s = ei[wid]; d = ei[EE + wid]; } else { s = wid - EE; d = s; }
  float4 ex = *(const float4*)(exbuf + (size_t)wid*4);
  float4 dn = *(const float4*)(denom + (size_t)d*4);
  float al[4];
  al[0] = ex.x/(dn.x+1e-16f);
  al[1] = ex.y/(dn.y+1e-16f);
  al[2] = ex.z/(dn.z+1e-16f);
  al[3] = ex.w/(dn.w+1e-16f);
  const float* hp = hbuf + (size_t)s*128;
  float*       ap = agg  + (size_t)d*128;
  float v0 = hp[lane], v1 = hp[64+lane];
  unsafeAtomicAdd(ap + lane,    v0 * al[lane>>5]);
  unsafeAtomicAdd(ap + 64+lane, v1 * al[2+(lane>>5)]);
}

// ---------- epilogue 1: +bias, *type-weight, BN stats ----------
__global__ __launch_bounds__(256) void epi1(float* __restrict__ y,
    const float* __restrict__ bias, const int* __restrict__ ntype,
    double* __restrict__ bnsum, double* __restrict__ bnsumsq, int N){
  __shared__ float red[256][8];
  const int t = threadIdx.x;
  const int c4 = (t & 31) * 4;
  const int rowInBlk = t >> 5;          // 0..7
  const int stride = gridDim.x * 8;
  float4 bb = *(const float4*)(bias + c4);
  float s0=0,s1=0,s2=0,s3=0,q0=0,q1=0,q2=0,q3=0;
  for (int n = blockIdx.x*8 + rowInBlk; n < N; n += stride){
    float aw = (ntype[n]==0) ? 1.5f : 1.0f;
    float4 v = *(float4*)(y + (size_t)n*128 + c4);
    v.x = (v.x + bb.x)*aw;
    v.y = (v.y + bb.y)*aw;
    v.z = (v.z + bb.z)*aw;
    v.w = (v.w + bb.w)*aw;
    *(float4*)(y + (size_t)n*128 + c4) = v;
    s0+=v.x; s1+=v.y; s2+=v.z; s3+=v.w;
    q0+=v.x*v.x; q1+=v.y*v.y; q2+=v.z*v.z; q3+=v.w*v.w;
  }
  red[t][0]=s0; red[t][1]=s1; red[t][2]=s2; red[t][3]=s3;
  red[t][4]=q0; red[t][5]=q1; red[t][6]=q2; red[t][7]=q3;
  __syncthreads();
  if (t < 32){
    float a[8] = {0,0,0,0,0,0,0,0};
    for (int j=0;j<8;j++){
      #pragma unroll
      for (int k2=0;k2<8;k2++) a[k2] += red[j*32+t][k2];
    }
    atomicAdd(bnsum   + t*4+0, (double)a[0]);
    atomicAdd(bnsum   + t*4+1, (double)a[1]);
    atomicAdd(bnsum   + t*4+2, (double)a[2]);
    atomicAdd(bnsum   + t*4+3, (double)a[3]);
    atomicAdd(bnsumsq + t*4+0, (double)a[4]);
    atomicAdd(bnsumsq + t*4+1, (double)a[5]);
    atomicAdd(bnsumsq + t*4+2, (double)a[6]);
    atomicAdd(bnsumsq + t*4+3, (double)a[7]);
  }
}

// ---------- BN finalize: scale/shift per channel ----------
__global__ void bn_final(const double* __restrict__ bnsum, const double* __restrict__ bnsumsq,
    const float* __restrict__ gma, const float* __restrict__ bta,
    float* __restrict__ scale, float* __restrict__ shift, int N){
  int c = threadIdx.x;
  double mu  = bnsum[c] / N;
  double var = bnsumsq[c] / N - mu*mu;
  if (var < 0.0) var = 0.0;
  float inv = (float)(1.0 / sqrt(var + 1e-5));
  float sc  = inv * gma[c];
  scale[c] = sc;
  shift[c] = bta[c] - (float)mu * sc;
}

// ---------- BN apply + ReLU (in place) ----------
__global__ __launch_bounds__(256) void bn_apply(float* __restrict__ y,
    const float* __restrict__ scale, const float* __restrict__ shift){
  size_t i = ((size_t)blockIdx.x*256 + threadIdx.x)*4;
  const size_t total  = (size_t)NN*128;
  const size_t stride = (size_t)gridDim.x*256*4;
  for (; i < total; i += stride){
    int c = (int)(i & 127);
    float4 v  = *(float4*)(y + i);
    float4 sc = *(const float4*)(scale + c);
    float4 sh = *(const float4*)(shift + c);
    v.x = fmaxf(fmaf(v.x, sc.x, sh.x), 0.f);
    v.y = fmaxf(fmaf(v.y, sc.y, sh.y), 0.f);
    v.z = fmaxf(fmaf(v.z, sc.z, sh.z), 0.f);
    v.w = fmaxf(fmaf(v.w, sc.w, sh.w), 0.f);
    *(float4*)(y + i) = v;
  }
}

// ---------- global mean pool (sum + count) ----------
__global__ __launch_bounds__(256) void pool_kernel(const float* __restrict__ y,
    const int* __restrict__ batch, float* __restrict__ pooled, float* __restrict__ cnt){
  int idx = blockIdx.x*256 + threadIdx.x;
  if (idx >= NN*32) return;
  int n = idx >> 5, c4 = (idx & 31)*4;
  int g = batch[n];
  float4 v = *(const float4*)(y + (size_t)n*128 + c4);
  unsafeAtomicAdd(pooled + (size_t)g*128 + c4+0, v.x);
  unsafeAtomicAdd(pooled + (size_t)g*128 + c4+1, v.y);
  unsafeAtomicAdd(pooled + (size_t)g*128 + c4+2, v.z);
  unsafeAtomicAdd(pooled + (size_t)g*128 + c4+3, v.w);
  if (c4 == 0) unsafeAtomicAdd(cnt + g, 1.0f);
}

// ---------- MLP head ----------
__global__ __launch_bounds__(128) void mlp_kernel(const float* __restrict__ pooled,
    const float* __restrict__ cnt, const float* __restrict__ fc1w,
    const float* __restrict__ fc1b, const float* __restrict__ fc2w,
    const float* __restrict__ fc2b, float* __restrict__ out){
  __shared__ float p[128];
  __shared__ float hid[32];
  int g = blockIdx.x, t = threadIdx.x;
  float c = cnt[g]; if (c < 1.f) c = 1.f;
  p[t] = pooled[(size_t)g*128 + t] / c;
  __syncthreads();
  if (t < 32){
    float a = fc1b[t];
    for (int k=0;k<128;k++) a += p[k]*fc1w[k*32+t];
    a = (a > 0.f) ? a : 0.f;
    hid[t] = a * fc2w[t];
  }
  __syncthreads();
  if (t == 0){
    float sacc = fc2b[0];
    #pragma unroll
    for (int j=0;j<32;j++) sacc += hid[j];
    out[g] = sacc;
  }
}

extern "C" void kernel_launch(void* const* d_in, const int* in_sizes, int n_in,
                              void* d_out, int out_size, void* d_ws, size_t ws_size,
                              hipStream_t stream){
  const float* x     = (const float*)d_in[0];
  const int*   ei    = (const int*)d_in[1];
  const int*   ntype = (const int*)d_in[2];
  const int*   batch = (const int*)d_in[3];
  const float* Wl[3]  = {(const float*)d_in[4],  (const float*)d_in[10], (const float*)d_in[16]};
  const float* asl[3] = {(const float*)d_in[5],  (const float*)d_in[11], (const float*)d_in[17]};
  const float* adl[3] = {(const float*)d_in[6],  (const float*)d_in[12], (const float*)d_in[18]};
  const float* bl[3]  = {(const float*)d_in[7],  (const float*)d_in[13], (const float*)d_in[19]};
  const float* gl[3]  = {(const float*)d_in[8],  (const float*)d_in[14], (const float*)d_in[20]};
  const float* bel[3] = {(const float*)d_in[9],  (const float*)d_in[15], (const float*)d_in[21]};
  const float* fc1w = (const float*)d_in[22];
  const float* fc1b = (const float*)d_in[23];
  const float* fc2w = (const float*)d_in[24];
  const float* fc2b = (const float*)d_in[25];

  char* base = (char*)d_ws;
  size_t off = 0;
  auto alloc = [&](size_t bytes)->char*{
    size_t o = (off + 255) & ~(size_t)255; off = o + bytes; return base + o;
  };
  float*    hbuf    = (float*)   alloc((size_t)NN*128*4);
  float*    ebuf    = (float*)   alloc((size_t)ET_*4*4);
  float*    esrc    = (float*)   alloc((size_t)NN*4*4);
  float*    edst    = (float*)   alloc((size_t)NN*4*4);
  char*     z0      =            alloc(0);
  unsigned* mbuf    = (unsigned*)alloc((size_t)NN*4*4);
  float*    denom   = (float*)   alloc((size_t)NN*4*4);
  double*   bnsum   = (double*)  alloc(128*8);
  double*   bnsumsq = (double*)  alloc(128*8);
  size_t zbytes = (size_t)((char*)(bnsumsq+128) - z0);
  float*    aggA    = (float*)   alloc((size_t)NN*128*4);
  float*    aggB    = (float*)   alloc((size_t)NN*128*4);
  char*     p0      =            alloc(0);
  float*    pooled  = (float*)   alloc((size_t)NG*128*4);
  float*    cnt     = (float*)   alloc((size_t)NG*4);
  size_t pbytes = (size_t)((char*)(cnt+NG) - p0);
  float*    scale   = (float*)   alloc(128*4);
  float*    shift   = (float*)   alloc(128*4);
  if (off > ws_size) return;   // insufficient workspace; fail loudly via wrong output

  const int gemmBlocks = (NN + 63)/64;
  for (int l = 0; l < 3; l++){
    const float* in = (l==0) ? x : ((l==1) ? aggA : aggB);
    float* agg = (l==1) ? aggB : aggA;
    hipMemsetAsync(z0,  0, zbytes, stream);
    hipMemsetAsync(agg, 0, (size_t)NN*128*4, stream);
    gemm_xw<<<gemmBlocks, 256, 0, stream>>>(in, Wl[l], hbuf, NN);
    attn_prep<<<(NN*4+255)/256, 256, 0, stream>>>(hbuf, asl[l], adl[l], esrc, edst);
    edge_logits<<<(ET_+255)/256, 256, 0, stream>>>(ei, esrc, edst, ebuf, mbuf);
    edge_exp<<<(ET_+255)/256, 256, 0, stream>>>(ei, mbuf, ebuf, denom);
    edge_aggregate<<<(ET_+3)/4, 256, 0, stream>>>(ei, hbuf, ebuf, denom, agg);
    epi1<<<256, 256, 0, stream>>>(agg, bl[l], ntype, bnsum, bnsumsq, NN);
    bn_final<<<1, 128, 0, stream>>>(bnsum, bnsumsq, gl[l], bel[l], scale, shift, NN);
    bn_apply<<<2048, 256, 0, stream>>>(agg, scale, shift);
  }
  hipMemsetAsync(p0, 0, pbytes, stream);
  pool_kernel<<<(NN*32+255)/256, 256, 0, stream>>>(aggA, batch, pooled, cnt);
  mlp_kernel<<<NG, 128, 0, stream>>>(pooled, cnt, fc1w, fc1b, fc2w, fc2b, (float*)d_out);
}

// Round 2
// 987.986 us; speedup vs baseline: 2.8837x; 2.8837x over previous
//
#include <hip/hip_runtime.h>
#include <hip/hip_bf16.h>
#include <math.h>

#define NN 50000
#define EE 800000
#define ET_ 850000
#define NG 64

// ---------- GEMM: H = X @ W  (X:[N,128], W:[128,128]), optional fused BN+ReLU on X ----------
__global__ __launch_bounds__(256) void gemm_xw(const float* __restrict__ X,
    const float* __restrict__ W, float* __restrict__ H, int N,
    const float* __restrict__ scale, const float* __restrict__ shift){
  __shared__ float Ws[64*128];
  __shared__ float Xs[64*128];
  const int t = threadIdx.x;
  const int row0 = blockIdx.x * 64;
  for (int i = t*4; i < 64*128; i += 1024){
    int r = i >> 7, c = i & 127;
    int gr = row0 + r;
    float4 v = make_float4(0.f,0.f,0.f,0.f);
    if (gr < N) v = *(const float4*)(X + (size_t)gr*128 + c);
    if (scale){
      float4 sc = *(const float4*)(scale + c);
      float4 sh = *(const float4*)(shift + c);
      v.x = fmaxf(fmaf(v.x, sc.x, sh.x), 0.f);
      v.y = fmaxf(fmaf(v.y, sc.y, sh.y), 0.f);
      v.z = fmaxf(fmaf(v.z, sc.z, sh.z), 0.f);
      v.w = fmaxf(fmaf(v.w, sc.w, sh.w), 0.f);
    }
    *(float4*)(Xs + i) = v;
  }
  const int col = t & 127;
  const int rg  = (t >> 7) * 32;
  float acc[32];
  #pragma unroll
  for (int r=0;r<32;r++) acc[r]=0.f;
  for (int ko=0; ko<128; ko+=64){
    __syncthreads();
    for (int i = t*4; i < 64*128; i += 1024)
      *(float4*)(Ws + i) = *(const float4*)(W + (size_t)ko*128 + i);
    __syncthreads();
    for (int k=0;k<64;k+=4){
      float w0 = Ws[(k+0)*128+col];
      float w1 = Ws[(k+1)*128+col];
      float w2 = Ws[(k+2)*128+col];
      float w3 = Ws[(k+3)*128+col];
      #pragma unroll
      for (int r=0;r<32;r++){
        float4 xv = *(const float4*)(Xs + (rg+r)*128 + ko + k);
        acc[r] += xv.x*w0 + xv.y*w1 + xv.z*w2 + xv.w*w3;
      }
    }
  }
  for (int r=0;r<32;r++){
    int gr = row0 + rg + r;
    if (gr < N) H[(size_t)gr*128 + col] = acc[r];
  }
}

// ---------- per-(node,head) attention logit prep ----------
__global__ __launch_bounds__(256) void attn_prep(const float* __restrict__ hbuf,
    const float* __restrict__ av, const float* __restrict__ dv,
    float* __restrict__ esrc, float* __restrict__ edst){
  int idx = blockIdx.x*256 + threadIdx.x;
  if (idx >= NN*4) return;
  int n = idx >> 2, hh = idx & 3;
  const float* hp = hbuf + (size_t)n*128 + hh*32;
  const float* ap = av + hh*32;
  const float* dp = dv + hh*32;
  float ss = 0.f, ds = 0.f;
  #pragma unroll
  for (int k=0;k<32;k+=4){
    float4 hv = *(const float4*)(hp + k);
    float4 a4 = *(const float4*)(ap + k);
    float4 d4 = *(const float4*)(dp + k);
    ss += hv.x*a4.x + hv.y*a4.y + hv.z*a4.z + hv.w*a4.w;
    ds += hv.x*d4.x + hv.y*d4.y + hv.z*d4.z + hv.w*d4.w;
  }
  esrc[idx] = ss; edst[idx] = ds;
}

// ---------- CSR build: histogram ----------
__global__ __launch_bounds__(256) void hist_kernel(const int* __restrict__ ei,
    int* __restrict__ cnt){
  int i = blockIdx.x*256 + threadIdx.x;
  if (i >= ET_) return;
  int d = (i < EE) ? ei[EE + i] : (i - EE);
  atomicAdd(cnt + d, 1);
}

// ---------- CSR build: single-block scan -> rowptr + head ----------
__global__ __launch_bounds__(1024) void scan_kernel(const int* __restrict__ cnt,
    int* __restrict__ rowptr, int* __restrict__ head){
  __shared__ int part[1024];
  const int t = threadIdx.x;
  const int per = (NN + 1023)/1024;   // 49
  const int b = t*per;
  int s = 0;
  for (int i=0;i<per;i++){ int idx=b+i; if (idx<NN) s += cnt[idx]; }
  part[t]=s; __syncthreads();
  for (int o=1;o<1024;o<<=1){
    int v = (t>=o)? part[t-o] : 0;
    __syncthreads();
    part[t]+=v;
    __syncthreads();
  }
  int run = (t==0)? 0 : part[t-1];
  for (int i=0;i<per;i++){
    int idx=b+i;
    if (idx<NN){ rowptr[idx]=run; head[idx]=run; run += cnt[idx]; }
  }
  if (t==0) rowptr[NN] = ET_;
}

// ---------- CSR build: scatter src ids ----------
__global__ __launch_bounds__(256) void scatter_kernel(const int* __restrict__ ei,
    int* __restrict__ head, int* __restrict__ csr_src){
  int i = blockIdx.x*256 + threadIdx.x;
  if (i >= ET_) return;
  int s, d;
  if (i < EE){ s = ei[i]; d = ei[EE + i]; } else { s = i - EE; d = s; }
  int pos = atomicAdd(head + d, 1);
  csr_src[pos] = s;
}

// ---------- fused GAT aggregate: one wave per destination node ----------
// softmax (no max-shift; identical up to 1e-16 eps) + alpha-weighted gather
// + bias + type-weight. Writes y[d]. No atomics.
__global__ __launch_bounds__(256) void gat_fused(const int* __restrict__ rowptr,
    const int* __restrict__ csr_src, const float* __restrict__ esrc,
    const float* __restrict__ edst, const float* __restrict__ hbuf,
    const float* __restrict__ bias, const int* __restrict__ ntype,
    float* __restrict__ y){
  const int wid  = blockIdx.x*4 + (threadIdx.x >> 6);
  const int lane = threadIdx.x & 63;
  if (wid >= NN) return;
  const int d = wid;
  const int beg = rowptr[d], end = rowptr[d+1];
  const float4 ed4 = *(const float4*)(edst + (size_t)d*4);

  float dn0=0.f, dn1=0.f, dn2=0.f, dn3=0.f;
  float2 acc = make_float2(0.f, 0.f);
  const int c0 = lane*2;                 // channels c0, c0+1; head = lane>>4

  for (int j0 = beg; j0 < end; j0 += 64){
    int j = j0 + lane;
    int s = d;
    float ex0=0.f, ex1=0.f, ex2=0.f, ex3=0.f;
    if (j < end){
      s = csr_src[j];
      float4 es = *(const float4*)(esrc + (size_t)s*4);
      float e0 = es.x + ed4.x; e0 = (e0 > 0.f) ? e0 : 0.2f*e0;
      float e1 = es.y + ed4.y; e1 = (e1 > 0.f) ? e1 : 0.2f*e1;
      float e2 = es.z + ed4.z; e2 = (e2 > 0.f) ? e2 : 0.2f*e2;
      float e3 = es.w + ed4.w; e3 = (e3 > 0.f) ? e3 : 0.2f*e3;
      ex0 = expf(e0); ex1 = expf(e1); ex2 = expf(e2); ex3 = expf(e3);
      dn0 += ex0; dn1 += ex1; dn2 += ex2; dn3 += ex3;
    }
    const int cnt2 = (end - j0 < 64) ? (end - j0) : 64;
    for (int jj = 0; jj < cnt2; jj++){
      int   sj = __shfl(s,   jj);
      float p0 = __shfl(ex0, jj);
      float p1 = __shfl(ex1, jj);
      float p2 = __shfl(ex2, jj);
      float p3 = __shfl(ex3, jj);
      float w = (lane < 16) ? p0 : (lane < 32) ? p1 : (lane < 48) ? p2 : p3;
      float2 hv = *(const float2*)(hbuf + (size_t)sj*128 + c0);
      acc.x = fmaf(hv.x, w, acc.x);
      acc.y = fmaf(hv.y, w, acc.y);
    }
  }
  // reduce denominators across lanes
  #pragma unroll
  for (int o = 32; o; o >>= 1){
    dn0 += __shfl_xor(dn0, o);
    dn1 += __shfl_xor(dn1, o);
    dn2 += __shfl_xor(dn2, o);
    dn3 += __shfl_xor(dn3, o);
  }
  float dsel = (lane < 16) ? dn0 : (lane < 32) ? dn1 : (lane < 48) ? dn2 : dn3;
  float inv = 1.f / (dsel + 1e-16f);
  float aw = (ntype[d] == 0) ? 1.5f : 1.0f;
  float2 bb = *(const float2*)(bias + c0);
  float2 o2;
  o2.x = (acc.x*inv + bb.x) * aw;
  o2.y = (acc.y*inv + bb.y) * aw;
  *(float2*)(y + (size_t)d*128 + c0) = o2;
}

// ---------- BN stats (read-only) ----------
__global__ __launch_bounds__(256) void epi_stats(const float* __restrict__ y,
    double* __restrict__ bnsum, double* __restrict__ bnsumsq, int N){
  __shared__ float red[256][8];
  const int t = threadIdx.x;
  const int c4 = (t & 31) * 4;
  const int rowInBlk = t >> 5;
  const int stride = gridDim.x * 8;
  float s0=0,s1=0,s2=0,s3=0,q0=0,q1=0,q2=0,q3=0;
  for (int n = blockIdx.x*8 + rowInBlk; n < N; n += stride){
    float4 v = *(const float4*)(y + (size_t)n*128 + c4);
    s0+=v.x; s1+=v.y; s2+=v.z; s3+=v.w;
    q0+=v.x*v.x; q1+=v.y*v.y; q2+=v.z*v.z; q3+=v.w*v.w;
  }
  red[t][0]=s0; red[t][1]=s1; red[t][2]=s2; red[t][3]=s3;
  red[t][4]=q0; red[t][5]=q1; red[t][6]=q2; red[t][7]=q3;
  __syncthreads();
  if (t < 32){
    float a[8] = {0,0,0,0,0,0,0,0};
    for (int j=0;j<8;j++){
      #pragma unroll
      for (int k2=0;k2<8;k2++) a[k2] += red[j*32+t][k2];
    }
    atomicAdd(bnsum   + t*4+0, (double)a[0]);
    atomicAdd(bnsum   + t*4+1, (double)a[1]);
    atomicAdd(bnsum   + t*4+2, (double)a[2]);
    atomicAdd(bnsum   + t*4+3, (double)a[3]);
    atomicAdd(bnsumsq + t*4+0, (double)a[4]);
    atomicAdd(bnsumsq + t*4+1, (double)a[5]);
    atomicAdd(bnsumsq + t*4+2, (double)a[6]);
    atomicAdd(bnsumsq + t*4+3, (double)a[7]);
  }
}

// ---------- BN finalize ----------
__global__ void bn_final(const double* __restrict__ bnsum, const double* __restrict__ bnsumsq,
    const float* __restrict__ gma, const float* __restrict__ bta,
    float* __restrict__ scale, float* __restrict__ shift, int N){
  int c = threadIdx.x;
  double mu  = bnsum[c] / N;
  double var = bnsumsq[c] / N - mu*mu;
  if (var < 0.0) var = 0.0;
  float inv = (float)(1.0 / sqrt(var + 1e-5));
  float sc  = inv * gma[c];
  scale[c] = sc;
  shift[c] = bta[c] - (float)mu * sc;
}

// ---------- pooled mean (sorted batch, binary search) + MLP head ----------
__global__ __launch_bounds__(256) void pool_mlp(const float* __restrict__ y,
    const int* __restrict__ batch, const float* __restrict__ scale,
    const float* __restrict__ shift, const float* __restrict__ fc1w,
    const float* __restrict__ fc1b, const float* __restrict__ fc2w,
    const float* __restrict__ fc2b, float* __restrict__ out){
  __shared__ float red[256];
  __shared__ float psh[128];
  __shared__ float hid[32];
  const int g = blockIdx.x, t = threadIdx.x;
  // lower_bound on sorted batch
  int lo = 0, hi = NN;
  while (lo < hi){ int mid = (lo+hi)>>1; if (batch[mid] < g) lo = mid+1; else hi = mid; }
  const int beg = lo;
  lo = beg; hi = NN;
  while (lo < hi){ int mid = (lo+hi)>>1; if (batch[mid] < g+1) lo = mid+1; else hi = mid; }
  const int end = lo;
  const int c = t & 127, half = t >> 7;
  const float sc = scale[c], sh = shift[c];
  float acc = 0.f;
  for (int n = beg + half; n < end; n += 2){
    float v = y[(size_t)n*128 + c];
    acc += fmaxf(fmaf(v, sc, sh), 0.f);
  }
  red[t] = acc; __syncthreads();
  if (t < 128){
    float cntf = (float)((end - beg) > 1 ? (end - beg) : 1);
    psh[t] = (red[t] + red[t+128]) / cntf;
  }
  __syncthreads();
  if (t < 32){
    float a = fc1b[t];
    for (int k=0;k<128;k++) a += psh[k]*fc1w[k*32+t];
    a = (a > 0.f) ? a : 0.f;
    hid[t] = a * fc2w[t];
  }
  __syncthreads();
  if (t == 0){
    float sacc = fc2b[0];
    #pragma unroll
    for (int j=0;j<32;j++) sacc += hid[j];
    out[g] = sacc;
  }
}

extern "C" void kernel_launch(void* const* d_in, const int* in_sizes, int n_in,
                              void* d_out, int out_size, void* d_ws, size_t ws_size,
                              hipStream_t stream){
  const float* x     = (const float*)d_in[0];
  const int*   ei    = (const int*)d_in[1];
  const int*   ntype = (const int*)d_in[2];
  const int*   batch = (const int*)d_in[3];
  const float* Wl[3]  = {(const float*)d_in[4],  (const float*)d_in[10], (const float*)d_in[16]};
  const float* asl[3] = {(const float*)d_in[5],  (const float*)d_in[11], (const float*)d_in[17]};
  const float* adl[3] = {(const float*)d_in[6],  (const float*)d_in[12], (const float*)d_in[18]};
  const float* bl[3]  = {(const float*)d_in[7],  (const float*)d_in[13], (const float*)d_in[19]};
  const float* gl[3]  = {(const float*)d_in[8],  (const float*)d_in[14], (const float*)d_in[20]};
  const float* bel[3] = {(const float*)d_in[9],  (const float*)d_in[15], (const float*)d_in[21]};
  const float* fc1w = (const float*)d_in[22];
  const float* fc1b = (const float*)d_in[23];
  const float* fc2w = (const float*)d_in[24];
  const float* fc2b = (const float*)d_in[25];

  char* base = (char*)d_ws;
  size_t off = 0;
  auto alloc = [&](size_t bytes)->char*{
    size_t o = (off + 255) & ~(size_t)255; off = o + bytes; return base + o;
  };
  float* hbuf    = (float*)alloc((size_t)NN*128*4);
  float* y       = (float*)alloc((size_t)NN*128*4);
  float* esrc    = (float*)alloc((size_t)NN*4*4);
  float* edst    = (float*)alloc((size_t)NN*4*4);
  int*   cnt     = (int*)  alloc((size_t)NN*4);
  int*   rowptr  = (int*)  alloc((size_t)(NN+1)*4);
  int*   head    = (int*)  alloc((size_t)NN*4);
  int*   csr_src = (int*)  alloc((size_t)ET_*4);
  double* bnsum  = (double*)alloc(128*8);
  double* bnsumsq= (double*)alloc(128*8);
  float* scale   = (float*)alloc(128*4);
  float* shift   = (float*)alloc(128*4);
  if (off > ws_size) return;

  // ---- CSR build (once; reused by all 3 layers) ----
  hipMemsetAsync(cnt, 0, (size_t)NN*4, stream);
  hist_kernel<<<(ET_+255)/256, 256, 0, stream>>>(ei, cnt);
  scan_kernel<<<1, 1024, 0, stream>>>(cnt, rowptr, head);
  scatter_kernel<<<(ET_+255)/256, 256, 0, stream>>>(ei, head, csr_src);

  const int gemmBlocks = (NN + 63)/64;
  for (int l = 0; l < 3; l++){
    const float* in = (l==0) ? x : y;
    const float* scl = (l==0) ? nullptr : scale;
    const float* shf = (l==0) ? nullptr : shift;
    hipMemsetAsync(bnsum, 0, 128*8*2, stream);   // bnsum + bnsumsq contiguous
    gemm_xw<<<gemmBlocks, 256, 0, stream>>>(in, Wl[l], hbuf, NN, scl, shf);
    attn_prep<<<(NN*4+255)/256, 256, 0, stream>>>(hbuf, asl[l], adl[l], esrc, edst);
    gat_fused<<<(NN+3)/4, 256, 0, stream>>>(rowptr, csr_src, esrc, edst, hbuf, bl[l], ntype, y);
    epi_stats<<<256, 256, 0, stream>>>(y, bnsum, bnsumsq, NN);
    bn_final<<<1, 128, 0, stream>>>(bnsum, bnsumsq, gl[l], bel[l], scale, shift, NN);
  }
  pool_mlp<<<NG, 256, 0, stream>>>(y, batch, scale, shift, fc1w, fc1b, fc2w, fc2b, (float*)d_out);
}

// Round 3
// 869.019 us; speedup vs baseline: 3.2785x; 1.1369x over previous
//
#include <hip/hip_runtime.h>
#include <hip/hip_bf16.h>
#include <math.h>

#define NN 50000
#define EE 800000
#define ET_ 850000
#define NG 64
#define NB 196   // ceil(NN/256)

// ---------- GEMM: H = X @ W  (X:[N,128], W:[128,128]), optional fused BN+ReLU on X ----------
__global__ __launch_bounds__(256) void gemm_xw(const float* __restrict__ X,
    const float* __restrict__ W, float* __restrict__ H, int N,
    const float* __restrict__ scale, const float* __restrict__ shift){
  __shared__ float Ws[64*128];
  __shared__ float Xs[64*128];
  const int t = threadIdx.x;
  const int row0 = blockIdx.x * 64;
  for (int i = t*4; i < 64*128; i += 1024){
    int r = i >> 7, c = i & 127;
    int gr = row0 + r;
    float4 v = make_float4(0.f,0.f,0.f,0.f);
    if (gr < N) v = *(const float4*)(X + (size_t)gr*128 + c);
    if (scale){
      float4 sc = *(const float4*)(scale + c);
      float4 sh = *(const float4*)(shift + c);
      v.x = fmaxf(fmaf(v.x, sc.x, sh.x), 0.f);
      v.y = fmaxf(fmaf(v.y, sc.y, sh.y), 0.f);
      v.z = fmaxf(fmaf(v.z, sc.z, sh.z), 0.f);
      v.w = fmaxf(fmaf(v.w, sc.w, sh.w), 0.f);
    }
    *(float4*)(Xs + i) = v;
  }
  const int col = t & 127;
  const int rg  = (t >> 7) * 32;
  float acc[32];
  #pragma unroll
  for (int r=0;r<32;r++) acc[r]=0.f;
  for (int ko=0; ko<128; ko+=64){
    __syncthreads();
    for (int i = t*4; i < 64*128; i += 1024)
      *(float4*)(Ws + i) = *(const float4*)(W + (size_t)ko*128 + i);
    __syncthreads();
    for (int k=0;k<64;k+=4){
      float w0 = Ws[(k+0)*128+col];
      float w1 = Ws[(k+1)*128+col];
      float w2 = Ws[(k+2)*128+col];
      float w3 = Ws[(k+3)*128+col];
      #pragma unroll
      for (int r=0;r<32;r++){
        float4 xv = *(const float4*)(Xs + (rg+r)*128 + ko + k);
        acc[r] += xv.x*w0 + xv.y*w1 + xv.z*w2 + xv.w*w3;
      }
    }
  }
  for (int r=0;r<32;r++){
    int gr = row0 + rg + r;
    if (gr < N) H[(size_t)gr*128 + col] = acc[r];
  }
}

// ---------- per-(node,head) attention logit prep ----------
__global__ __launch_bounds__(256) void attn_prep(const float* __restrict__ hbuf,
    const float* __restrict__ av, const float* __restrict__ dv,
    float* __restrict__ esrc, float* __restrict__ edst){
  int idx = blockIdx.x*256 + threadIdx.x;
  if (idx >= NN*4) return;
  int n = idx >> 2, hh = idx & 3;
  const float* hp = hbuf + (size_t)n*128 + hh*32;
  const float* ap = av + hh*32;
  const float* dp = dv + hh*32;
  float ss = 0.f, ds = 0.f;
  #pragma unroll
  for (int k=0;k<32;k+=4){
    float4 hv = *(const float4*)(hp + k);
    float4 a4 = *(const float4*)(ap + k);
    float4 d4 = *(const float4*)(dp + k);
    ss += hv.x*a4.x + hv.y*a4.y + hv.z*a4.z + hv.w*a4.w;
    ds += hv.x*d4.x + hv.y*d4.y + hv.z*d4.z + hv.w*d4.w;
  }
  esrc[idx] = ss; edst[idx] = ds;
}

// ---------- CSR build: histogram ----------
__global__ __launch_bounds__(256) void hist_kernel(const int* __restrict__ ei,
    int* __restrict__ cnt){
  int i = blockIdx.x*256 + threadIdx.x;
  if (i >= ET_) return;
  int d = (i < EE) ? ei[EE + i] : (i - EE);
  atomicAdd(cnt + d, 1);
}

// ---------- CSR build: parallel 3-phase scan ----------
__global__ __launch_bounds__(256) void scan_partial(const int* __restrict__ cnt,
    int* __restrict__ rowptr, int* __restrict__ bsum){
  __shared__ int sh[256];
  const int t = threadIdx.x;
  const int i = blockIdx.x*256 + t;
  int v = (i < NN) ? cnt[i] : 0;
  sh[t] = v; __syncthreads();
  for (int o=1;o<256;o<<=1){
    int u = (t>=o) ? sh[t-o] : 0;
    __syncthreads();
    sh[t] += u;
    __syncthreads();
  }
  if (i < NN) rowptr[i] = sh[t] - v;        // exclusive within block
  if (t == 255) bsum[blockIdx.x] = sh[255]; // block total
}

__global__ __launch_bounds__(256) void scan_bsum(int* __restrict__ bsum){
  __shared__ int sh[256];
  const int t = threadIdx.x;
  int v = (t < NB) ? bsum[t] : 0;
  sh[t] = v; __syncthreads();
  for (int o=1;o<256;o<<=1){
    int u = (t>=o) ? sh[t-o] : 0;
    __syncthreads();
    sh[t] += u;
    __syncthreads();
  }
  if (t < NB) bsum[t] = sh[t] - v;          // exclusive block offsets
}

__global__ __launch_bounds__(256) void scan_add(int* __restrict__ rowptr,
    const int* __restrict__ bsum, int* __restrict__ head){
  const int i = blockIdx.x*256 + threadIdx.x;
  if (i < NN){
    int r = rowptr[i] + bsum[blockIdx.x];
    rowptr[i] = r; head[i] = r;
  }
  if (i == NN) rowptr[NN] = ET_;
}

// ---------- CSR build: scatter src ids ----------
__global__ __launch_bounds__(256) void scatter_kernel(const int* __restrict__ ei,
    int* __restrict__ head, int* __restrict__ csr_src){
  int i = blockIdx.x*256 + threadIdx.x;
  if (i >= ET_) return;
  int s, d;
  if (i < EE){ s = ei[i]; d = ei[EE + i]; } else { s = i - EE; d = s; }
  int pos = atomicAdd(head + d, 1);
  csr_src[pos] = s;
}

// ---------- fused GAT aggregate: one wave per destination node ----------
__global__ __launch_bounds__(256) void gat_fused(const int* __restrict__ rowptr,
    const int* __restrict__ csr_src, const float* __restrict__ esrc,
    const float* __restrict__ edst, const float* __restrict__ hbuf,
    const float* __restrict__ bias, const int* __restrict__ ntype,
    float* __restrict__ y){
  const int wid  = blockIdx.x*4 + (threadIdx.x >> 6);
  const int lane = threadIdx.x & 63;
  if (wid >= NN) return;
  const int d = wid;
  const int beg = rowptr[d], end = rowptr[d+1];
  const float4 ed4 = *(const float4*)(edst + (size_t)d*4);

  float dn0=0.f, dn1=0.f, dn2=0.f, dn3=0.f;
  float2 acc = make_float2(0.f, 0.f);
  const int c0 = lane*2;

  for (int j0 = beg; j0 < end; j0 += 64){
    int j = j0 + lane;
    int s = d;
    float ex0=0.f, ex1=0.f, ex2=0.f, ex3=0.f;
    if (j < end){
      s = csr_src[j];
      float4 es = *(const float4*)(esrc + (size_t)s*4);
      float e0 = es.x + ed4.x; e0 = (e0 > 0.f) ? e0 : 0.2f*e0;
      float e1 = es.y + ed4.y; e1 = (e1 > 0.f) ? e1 : 0.2f*e1;
      float e2 = es.z + ed4.z; e2 = (e2 > 0.f) ? e2 : 0.2f*e2;
      float e3 = es.w + ed4.w; e3 = (e3 > 0.f) ? e3 : 0.2f*e3;
      ex0 = expf(e0); ex1 = expf(e1); ex2 = expf(e2); ex3 = expf(e3);
      dn0 += ex0; dn1 += ex1; dn2 += ex2; dn3 += ex3;
    }
    const int cnt2 = (end - j0 < 64) ? (end - j0) : 64;
    for (int jj = 0; jj < cnt2; jj++){
      int   sj = __shfl(s,   jj);
      float p0 = __shfl(ex0, jj);
      float p1 = __shfl(ex1, jj);
      float p2 = __shfl(ex2, jj);
      float p3 = __shfl(ex3, jj);
      float w = (lane < 16) ? p0 : (lane < 32) ? p1 : (lane < 48) ? p2 : p3;
      float2 hv = *(const float2*)(hbuf + (size_t)sj*128 + c0);
      acc.x = fmaf(hv.x, w, acc.x);
      acc.y = fmaf(hv.y, w, acc.y);
    }
  }
  #pragma unroll
  for (int o = 32; o; o >>= 1){
    dn0 += __shfl_xor(dn0, o);
    dn1 += __shfl_xor(dn1, o);
    dn2 += __shfl_xor(dn2, o);
    dn3 += __shfl_xor(dn3, o);
  }
  float dsel = (lane < 16) ? dn0 : (lane < 32) ? dn1 : (lane < 48) ? dn2 : dn3;
  float inv = 1.f / (dsel + 1e-16f);
  float aw = (ntype[d] == 0) ? 1.5f : 1.0f;
  float2 bb = *(const float2*)(bias + c0);
  float2 o2;
  o2.x = (acc.x*inv + bb.x) * aw;
  o2.y = (acc.y*inv + bb.y) * aw;
  *(float2*)(y + (size_t)d*128 + c0) = o2;
}

// ---------- BN stats (read-only) ----------
__global__ __launch_bounds__(256) void epi_stats(const float* __restrict__ y,
    double* __restrict__ bnsum, double* __restrict__ bnsumsq, int N){
  __shared__ float red[256][8];
  const int t = threadIdx.x;
  const int c4 = (t & 31) * 4;
  const int rowInBlk = t >> 5;
  const int stride = gridDim.x * 8;
  float s0=0,s1=0,s2=0,s3=0,q0=0,q1=0,q2=0,q3=0;
  for (int n = blockIdx.x*8 + rowInBlk; n < N; n += stride){
    float4 v = *(const float4*)(y + (size_t)n*128 + c4);
    s0+=v.x; s1+=v.y; s2+=v.z; s3+=v.w;
    q0+=v.x*v.x; q1+=v.y*v.y; q2+=v.z*v.z; q3+=v.w*v.w;
  }
  red[t][0]=s0; red[t][1]=s1; red[t][2]=s2; red[t][3]=s3;
  red[t][4]=q0; red[t][5]=q1; red[t][6]=q2; red[t][7]=q3;
  __syncthreads();
  if (t < 32){
    float a[8] = {0,0,0,0,0,0,0,0};
    for (int j=0;j<8;j++){
      #pragma unroll
      for (int k2=0;k2<8;k2++) a[k2] += red[j*32+t][k2];
    }
    atomicAdd(bnsum   + t*4+0, (double)a[0]);
    atomicAdd(bnsum   + t*4+1, (double)a[1]);
    atomicAdd(bnsum   + t*4+2, (double)a[2]);
    atomicAdd(bnsum   + t*4+3, (double)a[3]);
    atomicAdd(bnsumsq + t*4+0, (double)a[4]);
    atomicAdd(bnsumsq + t*4+1, (double)a[5]);
    atomicAdd(bnsumsq + t*4+2, (double)a[6]);
    atomicAdd(bnsumsq + t*4+3, (double)a[7]);
  }
}

// ---------- BN finalize ----------
__global__ void bn_final(const double* __restrict__ bnsum, const double* __restrict__ bnsumsq,
    const float* __restrict__ gma, const float* __restrict__ bta,
    float* __restrict__ scale, float* __restrict__ shift, int N){
  int c = threadIdx.x;
  double mu  = bnsum[c] / N;
  double var = bnsumsq[c] / N - mu*mu;
  if (var < 0.0) var = 0.0;
  float inv = (float)(1.0 / sqrt(var + 1e-5));
  float sc  = inv * gma[c];
  scale[c] = sc;
  shift[c] = bta[c] - (float)mu * sc;
}

// ---------- pooled mean (sorted batch, binary search) + MLP head ----------
__global__ __launch_bounds__(256) void pool_mlp(const float* __restrict__ y,
    const int* __restrict__ batch, const float* __restrict__ scale,
    const float* __restrict__ shift, const float* __restrict__ fc1w,
    const float* __restrict__ fc1b, const float* __restrict__ fc2w,
    const float* __restrict__ fc2b, float* __restrict__ out){
  __shared__ float red[256];
  __shared__ float psh[128];
  __shared__ float hid[32];
  const int g = blockIdx.x, t = threadIdx.x;
  int lo = 0, hi = NN;
  while (lo < hi){ int mid = (lo+hi)>>1; if (batch[mid] < g) lo = mid+1; else hi = mid; }
  const int beg = lo;
  lo = beg; hi = NN;
  while (lo < hi){ int mid = (lo+hi)>>1; if (batch[mid] < g+1) lo = mid+1; else hi = mid; }
  const int end = lo;
  const int c = t & 127, half = t >> 7;
  const float sc = scale[c], sh = shift[c];
  float acc = 0.f;
  for (int n = beg + half; n < end; n += 2){
    float v = y[(size_t)n*128 + c];
    acc += fmaxf(fmaf(v, sc, sh), 0.f);
  }
  red[t] = acc; __syncthreads();
  if (t < 128){
    float cntf = (float)((end - beg) > 1 ? (end - beg) : 1);
    psh[t] = (red[t] + red[t+128]) / cntf;
  }
  __syncthreads();
  if (t < 32){
    float a = fc1b[t];
    for (int k=0;k<128;k++) a += psh[k]*fc1w[k*32+t];
    a = (a > 0.f) ? a : 0.f;
    hid[t] = a * fc2w[t];
  }
  __syncthreads();
  if (t == 0){
    float sacc = fc2b[0];
    #pragma unroll
    for (int j=0;j<32;j++) sacc += hid[j];
    out[g] = sacc;
  }
}

extern "C" void kernel_launch(void* const* d_in, const int* in_sizes, int n_in,
                              void* d_out, int out_size, void* d_ws, size_t ws_size,
                              hipStream_t stream){
  const float* x     = (const float*)d_in[0];
  const int*   ei    = (const int*)d_in[1];
  const int*   ntype = (const int*)d_in[2];
  const int*   batch = (const int*)d_in[3];
  const float* Wl[3]  = {(const float*)d_in[4],  (const float*)d_in[10], (const float*)d_in[16]};
  const float* asl[3] = {(const float*)d_in[5],  (const float*)d_in[11], (const float*)d_in[17]};
  const float* adl[3] = {(const float*)d_in[6],  (const float*)d_in[12], (const float*)d_in[18]};
  const float* bl[3]  = {(const float*)d_in[7],  (const float*)d_in[13], (const float*)d_in[19]};
  const float* gl[3]  = {(const float*)d_in[8],  (const float*)d_in[14], (const float*)d_in[20]};
  const float* bel[3] = {(const float*)d_in[9],  (const float*)d_in[15], (const float*)d_in[21]};
  const float* fc1w = (const float*)d_in[22];
  const float* fc1b = (const float*)d_in[23];
  const float* fc2w = (const float*)d_in[24];
  const float* fc2b = (const float*)d_in[25];

  char* base = (char*)d_ws;
  size_t off = 0;
  auto alloc = [&](size_t bytes)->char*{
    size_t o = (off + 255) & ~(size_t)255; off = o + bytes; return base + o;
  };
  float* hbuf    = (float*)alloc((size_t)NN*128*4);
  float* y       = (float*)alloc((size_t)NN*128*4);
  float* esrc    = (float*)alloc((size_t)NN*4*4);
  float* edst    = (float*)alloc((size_t)NN*4*4);
  int*   cnt     = (int*)  alloc((size_t)NN*4);
  int*   rowptr  = (int*)  alloc((size_t)(NN+1)*4);
  int*   head    = (int*)  alloc((size_t)NN*4);
  int*   csr_src = (int*)  alloc((size_t)ET_*4);
  int*   bsum    = (int*)  alloc((size_t)NB*4);
  double* bnsum  = (double*)alloc(128*8);
  double* bnsumsq= (double*)alloc(128*8);
  float* scale   = (float*)alloc(128*4);
  float* shift   = (float*)alloc(128*4);
  if (off > ws_size) return;

  // ---- CSR build (once; reused by all 3 layers) ----
  hipMemsetAsync(cnt, 0, (size_t)NN*4, stream);
  hist_kernel<<<(ET_+255)/256, 256, 0, stream>>>(ei, cnt);
  scan_partial<<<NB, 256, 0, stream>>>(cnt, rowptr, bsum);
  scan_bsum<<<1, 256, 0, stream>>>(bsum);
  scan_add<<<NB, 256, 0, stream>>>(rowptr, bsum, head);
  scatter_kernel<<<(ET_+255)/256, 256, 0, stream>>>(ei, head, csr_src);

  const int gemmBlocks = (NN + 63)/64;
  for (int l = 0; l < 3; l++){
    const float* in = (l==0) ? x : y;
    const float* scl = (l==0) ? nullptr : scale;
    const float* shf = (l==0) ? nullptr : shift;
    hipMemsetAsync(bnsum, 0, 128*8*2, stream);
    gemm_xw<<<gemmBlocks, 256, 0, stream>>>(in, Wl[l], hbuf, NN, scl, shf);
    attn_prep<<<(NN*4+255)/256, 256, 0, stream>>>(hbuf, asl[l], adl[l], esrc, edst);
    gat_fused<<<(NN+3)/4, 256, 0, stream>>>(rowptr, csr_src, esrc, edst, hbuf, bl[l], ntype, y);
    epi_stats<<<256, 256, 0, stream>>>(y, bnsum, bnsumsq, NN);
    bn_final<<<1, 128, 0, stream>>>(bnsum, bnsumsq, gl[l], bel[l], scale, shift, NN);
  }
  pool_mlp<<<NG, 256, 0, stream>>>(y, batch, scale, shift, fc1w, fc1b, fc2w, fc2b, (float*)d_out);
}

// Round 4
// 779.868 us; speedup vs baseline: 3.6533x; 1.1143x over previous
//
#include <hip/hip_runtime.h>
#include <hip/hip_bf16.h>
#include <math.h>

#define NN 50000
#define EE 800000
#define ET_ 850000
#define NG 64
#define NB 196   // ceil(NN/256)
#define PB 1024  // pool blocks

// ---------- GEMM: H = X @ W  (X:[N,128], W:[128,128]), optional fused BN+ReLU on X ----------
__global__ __launch_bounds__(256) void gemm_xw(const float* __restrict__ X,
    const float* __restrict__ W, float* __restrict__ H, int N,
    const float* __restrict__ scale, const float* __restrict__ shift){
  __shared__ float Ws[64*128];
  __shared__ float Xs[64*128];
  const int t = threadIdx.x;
  const int row0 = blockIdx.x * 64;
  for (int i = t*4; i < 64*128; i += 1024){
    int r = i >> 7, c = i & 127;
    int gr = row0 + r;
    float4 v = make_float4(0.f,0.f,0.f,0.f);
    if (gr < N) v = *(const float4*)(X + (size_t)gr*128 + c);
    if (scale){
      float4 sc = *(const float4*)(scale + c);
      float4 sh = *(const float4*)(shift + c);
      v.x = fmaxf(fmaf(v.x, sc.x, sh.x), 0.f);
      v.y = fmaxf(fmaf(v.y, sc.y, sh.y), 0.f);
      v.z = fmaxf(fmaf(v.z, sc.z, sh.z), 0.f);
      v.w = fmaxf(fmaf(v.w, sc.w, sh.w), 0.f);
    }
    *(float4*)(Xs + i) = v;
  }
  const int col = t & 127;
  const int rg  = (t >> 7) * 32;
  float acc[32];
  #pragma unroll
  for (int r=0;r<32;r++) acc[r]=0.f;
  for (int ko=0; ko<128; ko+=64){
    __syncthreads();
    for (int i = t*4; i < 64*128; i += 1024)
      *(float4*)(Ws + i) = *(const float4*)(W + (size_t)ko*128 + i);
    __syncthreads();
    for (int k=0;k<64;k+=4){
      float w0 = Ws[(k+0)*128+col];
      float w1 = Ws[(k+1)*128+col];
      float w2 = Ws[(k+2)*128+col];
      float w3 = Ws[(k+3)*128+col];
      #pragma unroll
      for (int r=0;r<32;r++){
        float4 xv = *(const float4*)(Xs + (rg+r)*128 + ko + k);
        acc[r] += xv.x*w0 + xv.y*w1 + xv.z*w2 + xv.w*w3;
      }
    }
  }
  for (int r=0;r<32;r++){
    int gr = row0 + rg + r;
    if (gr < N) H[(size_t)gr*128 + col] = acc[r];
  }
}

// ---------- per-(node,head) attention logit prep ----------
__global__ __launch_bounds__(256) void attn_prep(const float* __restrict__ hbuf,
    const float* __restrict__ av, const float* __restrict__ dv,
    float* __restrict__ esrc, float* __restrict__ edst){
  int idx = blockIdx.x*256 + threadIdx.x;
  if (idx >= NN*4) return;
  int n = idx >> 2, hh = idx & 3;
  const float* hp = hbuf + (size_t)n*128 + hh*32;
  const float* ap = av + hh*32;
  const float* dp = dv + hh*32;
  float ss = 0.f, ds = 0.f;
  #pragma unroll
  for (int k=0;k<32;k+=4){
    float4 hv = *(const float4*)(hp + k);
    float4 a4 = *(const float4*)(ap + k);
    float4 d4 = *(const float4*)(dp + k);
    ss += hv.x*a4.x + hv.y*a4.y + hv.z*a4.z + hv.w*a4.w;
    ds += hv.x*d4.x + hv.y*d4.y + hv.z*d4.z + hv.w*d4.w;
  }
  esrc[idx] = ss; edst[idx] = ds;
}

// ---------- CSR build: histogram ----------
__global__ __launch_bounds__(256) void hist_kernel(const int* __restrict__ ei,
    int* __restrict__ cnt){
  int i = blockIdx.x*256 + threadIdx.x;
  if (i >= ET_) return;
  int d = (i < EE) ? ei[EE + i] : (i - EE);
  atomicAdd(cnt + d, 1);
}

// ---------- CSR build: parallel 3-phase scan ----------
__global__ __launch_bounds__(256) void scan_partial(const int* __restrict__ cnt,
    int* __restrict__ rowptr, int* __restrict__ bsum){
  __shared__ int sh[256];
  const int t = threadIdx.x;
  const int i = blockIdx.x*256 + t;
  int v = (i < NN) ? cnt[i] : 0;
  sh[t] = v; __syncthreads();
  for (int o=1;o<256;o<<=1){
    int u = (t>=o) ? sh[t-o] : 0;
    __syncthreads();
    sh[t] += u;
    __syncthreads();
  }
  if (i < NN) rowptr[i] = sh[t] - v;
  if (t == 255) bsum[blockIdx.x] = sh[255];
}

__global__ __launch_bounds__(256) void scan_bsum(int* __restrict__ bsum){
  __shared__ int sh[256];
  const int t = threadIdx.x;
  int v = (t < NB) ? bsum[t] : 0;
  sh[t] = v; __syncthreads();
  for (int o=1;o<256;o<<=1){
    int u = (t>=o) ? sh[t-o] : 0;
    __syncthreads();
    sh[t] += u;
    __syncthreads();
  }
  if (t < NB) bsum[t] = sh[t] - v;
}

__global__ __launch_bounds__(256) void scan_add(int* __restrict__ rowptr,
    const int* __restrict__ bsum, int* __restrict__ head){
  const int i = blockIdx.x*256 + threadIdx.x;
  if (i < NN){
    int r = rowptr[i] + bsum[blockIdx.x];
    rowptr[i] = r; head[i] = r;
  }
  if (i == NN) rowptr[NN] = ET_;
}

// ---------- CSR build: scatter src ids ----------
__global__ __launch_bounds__(256) void scatter_kernel(const int* __restrict__ ei,
    int* __restrict__ head, int* __restrict__ csr_src){
  int i = blockIdx.x*256 + threadIdx.x;
  if (i >= ET_) return;
  int s, d;
  if (i < EE){ s = ei[i]; d = ei[EE + i]; } else { s = i - EE; d = s; }
  int pos = atomicAdd(head + d, 1);
  csr_src[pos] = s;
}

// ---------- fused GAT aggregate: one wave per destination node ----------
__global__ __launch_bounds__(256) void gat_fused(const int* __restrict__ rowptr,
    const int* __restrict__ csr_src, const float* __restrict__ esrc,
    const float* __restrict__ edst, const float* __restrict__ hbuf,
    const float* __restrict__ bias, const int* __restrict__ ntype,
    float* __restrict__ y){
  const int wid  = blockIdx.x*4 + (threadIdx.x >> 6);
  const int lane = threadIdx.x & 63;
  if (wid >= NN) return;
  const int d = wid;
  const int beg = rowptr[d], end = rowptr[d+1];
  const float4 ed4 = *(const float4*)(edst + (size_t)d*4);

  float dn0=0.f, dn1=0.f, dn2=0.f, dn3=0.f;
  float2 acc = make_float2(0.f, 0.f);
  const int c0 = lane*2;

  for (int j0 = beg; j0 < end; j0 += 64){
    int j = j0 + lane;
    int s = d;
    float ex0=0.f, ex1=0.f, ex2=0.f, ex3=0.f;
    if (j < end){
      s = csr_src[j];
      float4 es = *(const float4*)(esrc + (size_t)s*4);
      float e0 = es.x + ed4.x; e0 = (e0 > 0.f) ? e0 : 0.2f*e0;
      float e1 = es.y + ed4.y; e1 = (e1 > 0.f) ? e1 : 0.2f*e1;
      float e2 = es.z + ed4.z; e2 = (e2 > 0.f) ? e2 : 0.2f*e2;
      float e3 = es.w + ed4.w; e3 = (e3 > 0.f) ? e3 : 0.2f*e3;
      ex0 = expf(e0); ex1 = expf(e1); ex2 = expf(e2); ex3 = expf(e3);
      dn0 += ex0; dn1 += ex1; dn2 += ex2; dn3 += ex3;
    }
    const int cnt2 = (end - j0 < 64) ? (end - j0) : 64;
    for (int jj = 0; jj < cnt2; jj++){
      int   sj = __shfl(s,   jj);
      float p0 = __shfl(ex0, jj);
      float p1 = __shfl(ex1, jj);
      float p2 = __shfl(ex2, jj);
      float p3 = __shfl(ex3, jj);
      float w = (lane < 16) ? p0 : (lane < 32) ? p1 : (lane < 48) ? p2 : p3;
      float2 hv = *(const float2*)(hbuf + (size_t)sj*128 + c0);
      acc.x = fmaf(hv.x, w, acc.x);
      acc.y = fmaf(hv.y, w, acc.y);
    }
  }
  #pragma unroll
  for (int o = 32; o; o >>= 1){
    dn0 += __shfl_xor(dn0, o);
    dn1 += __shfl_xor(dn1, o);
    dn2 += __shfl_xor(dn2, o);
    dn3 += __shfl_xor(dn3, o);
  }
  float dsel = (lane < 16) ? dn0 : (lane < 32) ? dn1 : (lane < 48) ? dn2 : dn3;
  float inv = 1.f / (dsel + 1e-16f);
  float aw = (ntype[d] == 0) ? 1.5f : 1.0f;
  float2 bb = *(const float2*)(bias + c0);
  float2 o2;
  o2.x = (acc.x*inv + bb.x) * aw;
  o2.y = (acc.y*inv + bb.y) * aw;
  *(float2*)(y + (size_t)d*128 + c0) = o2;
}

// ---------- BN stats (read-only) ----------
__global__ __launch_bounds__(256) void epi_stats(const float* __restrict__ y,
    double* __restrict__ bnsum, double* __restrict__ bnsumsq, int N){
  __shared__ float red[256][8];
  const int t = threadIdx.x;
  const int c4 = (t & 31) * 4;
  const int rowInBlk = t >> 5;
  const int stride = gridDim.x * 8;
  float s0=0,s1=0,s2=0,s3=0,q0=0,q1=0,q2=0,q3=0;
  for (int n = blockIdx.x*8 + rowInBlk; n < N; n += stride){
    float4 v = *(const float4*)(y + (size_t)n*128 + c4);
    s0+=v.x; s1+=v.y; s2+=v.z; s3+=v.w;
    q0+=v.x*v.x; q1+=v.y*v.y; q2+=v.z*v.z; q3+=v.w*v.w;
  }
  red[t][0]=s0; red[t][1]=s1; red[t][2]=s2; red[t][3]=s3;
  red[t][4]=q0; red[t][5]=q1; red[t][6]=q2; red[t][7]=q3;
  __syncthreads();
  if (t < 32){
    float a[8] = {0,0,0,0,0,0,0,0};
    for (int j=0;j<8;j++){
      #pragma unroll
      for (int k2=0;k2<8;k2++) a[k2] += red[j*32+t][k2];
    }
    atomicAdd(bnsum   + t*4+0, (double)a[0]);
    atomicAdd(bnsum   + t*4+1, (double)a[1]);
    atomicAdd(bnsum   + t*4+2, (double)a[2]);
    atomicAdd(bnsum   + t*4+3, (double)a[3]);
    atomicAdd(bnsumsq + t*4+0, (double)a[4]);
    atomicAdd(bnsumsq + t*4+1, (double)a[5]);
    atomicAdd(bnsumsq + t*4+2, (double)a[6]);
    atomicAdd(bnsumsq + t*4+3, (double)a[7]);
  }
}

// ---------- BN finalize ----------
__global__ void bn_final(const double* __restrict__ bnsum, const double* __restrict__ bnsumsq,
    const float* __restrict__ gma, const float* __restrict__ bta,
    float* __restrict__ scale, float* __restrict__ shift, int N){
  int c = threadIdx.x;
  double mu  = bnsum[c] / N;
  double var = bnsumsq[c] / N - mu*mu;
  if (var < 0.0) var = 0.0;
  float inv = (float)(1.0 / sqrt(var + 1e-5));
  float sc  = inv * gma[c];
  scale[c] = sc;
  shift[c] = bta[c] - (float)mu * sc;
}

// ---------- pool phase 1: BN+ReLU+partial per-graph sums (sorted batch) ----------
__global__ __launch_bounds__(256) void pool_partial(const float* __restrict__ y,
    const int* __restrict__ batch, const float* __restrict__ scale,
    const float* __restrict__ shift, float* __restrict__ pooled){
  const int t = threadIdx.x;
  const int c = t & 127;
  const int sub = t >> 7;             // 0/1
  const int per = (NN + PB - 1) / PB; // 49
  const int n0 = blockIdx.x * per;
  int n1 = n0 + per; if (n1 > NN) n1 = NN;
  const float sc = scale[c], sh = shift[c];
  float acc = 0.f;
  int curg = -1;
  for (int n = n0 + sub; n < n1; n += 2){
    int g = batch[n];
    if (g != curg){
      if (curg >= 0) unsafeAtomicAdd(pooled + (size_t)curg*128 + c, acc);
      curg = g; acc = 0.f;
    }
    float v = y[(size_t)n*128 + c];
    acc += fmaxf(fmaf(v, sc, sh), 0.f);
  }
  if (curg >= 0) unsafeAtomicAdd(pooled + (size_t)curg*128 + c, acc);
}

// ---------- pool phase 2: mean + MLP head ----------
__global__ __launch_bounds__(128) void mlp_head(const float* __restrict__ pooled,
    const int* __restrict__ batch, const float* __restrict__ fc1w,
    const float* __restrict__ fc1b, const float* __restrict__ fc2w,
    const float* __restrict__ fc2b, float* __restrict__ out){
  __shared__ float psh[128];
  __shared__ float hid[32];
  const int g = blockIdx.x, t = threadIdx.x;
  int lo = 0, hi = NN;
  while (lo < hi){ int mid = (lo+hi)>>1; if (batch[mid] < g) lo = mid+1; else hi = mid; }
  const int beg = lo;
  lo = beg; hi = NN;
  while (lo < hi){ int mid = (lo+hi)>>1; if (batch[mid] < g+1) lo = mid+1; else hi = mid; }
  int cntn = lo - beg; if (cntn < 1) cntn = 1;
  psh[t] = pooled[(size_t)g*128 + t] / (float)cntn;
  __syncthreads();
  if (t < 32){
    float a = fc1b[t];
    for (int k=0;k<128;k++) a += psh[k]*fc1w[k*32+t];
    a = (a > 0.f) ? a : 0.f;
    hid[t] = a * fc2w[t];
  }
  __syncthreads();
  if (t == 0){
    float sacc = fc2b[0];
    #pragma unroll
    for (int j=0;j<32;j++) sacc += hid[j];
    out[g] = sacc;
  }
}

extern "C" void kernel_launch(void* const* d_in, const int* in_sizes, int n_in,
                              void* d_out, int out_size, void* d_ws, size_t ws_size,
                              hipStream_t stream){
  const float* x     = (const float*)d_in[0];
  const int*   ei    = (const int*)d_in[1];
  const int*   ntype = (const int*)d_in[2];
  const int*   batch = (const int*)d_in[3];
  const float* Wl[3]  = {(const float*)d_in[4],  (const float*)d_in[10], (const float*)d_in[16]};
  const float* asl[3] = {(const float*)d_in[5],  (const float*)d_in[11], (const float*)d_in[17]};
  const float* adl[3] = {(const float*)d_in[6],  (const float*)d_in[12], (const float*)d_in[18]};
  const float* bl[3]  = {(const float*)d_in[7],  (const float*)d_in[13], (const float*)d_in[19]};
  const float* gl[3]  = {(const float*)d_in[8],  (const float*)d_in[14], (const float*)d_in[20]};
  const float* bel[3] = {(const float*)d_in[9],  (const float*)d_in[15], (const float*)d_in[21]};
  const float* fc1w = (const float*)d_in[22];
  const float* fc1b = (const float*)d_in[23];
  const float* fc2w = (const float*)d_in[24];
  const float* fc2b = (const float*)d_in[25];

  char* base = (char*)d_ws;
  size_t off = 0;
  auto alloc = [&](size_t bytes)->char*{
    size_t o = (off + 255) & ~(size_t)255; off = o + bytes; return base + o;
  };
  float* hbuf    = (float*)alloc((size_t)NN*128*4);
  float* y       = (float*)alloc((size_t)NN*128*4);
  float* esrc    = (float*)alloc((size_t)NN*4*4);
  float* edst    = (float*)alloc((size_t)NN*4*4);
  int*   cnt     = (int*)  alloc((size_t)NN*4);
  int*   rowptr  = (int*)  alloc((size_t)(NN+1)*4);
  int*   head    = (int*)  alloc((size_t)NN*4);
  int*   csr_src = (int*)  alloc((size_t)ET_*4);
  int*   bsum    = (int*)  alloc((size_t)NB*4);
  double* bnsum  = (double*)alloc(128*8);
  double* bnsumsq= (double*)alloc(128*8);
  float* scale   = (float*)alloc(128*4);
  float* shift   = (float*)alloc(128*4);
  float* pooled  = (float*)alloc((size_t)NG*128*4);
  if (off > ws_size) return;

  // ---- CSR build (once; reused by all 3 layers) ----
  hipMemsetAsync(cnt, 0, (size_t)NN*4, stream);
  hipMemsetAsync(pooled, 0, (size_t)NG*128*4, stream);
  hist_kernel<<<(ET_+255)/256, 256, 0, stream>>>(ei, cnt);
  scan_partial<<<NB, 256, 0, stream>>>(cnt, rowptr, bsum);
  scan_bsum<<<1, 256, 0, stream>>>(bsum);
  scan_add<<<NB, 256, 0, stream>>>(rowptr, bsum, head);
  scatter_kernel<<<(ET_+255)/256, 256, 0, stream>>>(ei, head, csr_src);

  const int gemmBlocks = (NN + 63)/64;
  for (int l = 0; l < 3; l++){
    const float* in = (l==0) ? x : y;
    const float* scl = (l==0) ? nullptr : scale;
    const float* shf = (l==0) ? nullptr : shift;
    hipMemsetAsync(bnsum, 0, 128*8*2, stream);
    gemm_xw<<<gemmBlocks, 256, 0, stream>>>(in, Wl[l], hbuf, NN, scl, shf);
    attn_prep<<<(NN*4+255)/256, 256, 0, stream>>>(hbuf, asl[l], adl[l], esrc, edst);
    gat_fused<<<(NN+3)/4, 256, 0, stream>>>(rowptr, csr_src, esrc, edst, hbuf, bl[l], ntype, y);
    epi_stats<<<256, 256, 0, stream>>>(y, bnsum, bnsumsq, NN);
    bn_final<<<1, 128, 0, stream>>>(bnsum, bnsumsq, gl[l], bel[l], scale, shift, NN);
  }
  pool_partial<<<PB, 256, 0, stream>>>(y, batch, scale, shift, pooled);
  mlp_head<<<NG, 128, 0, stream>>>(pooled, batch, fc1w, fc1b, fc2w, fc2b, (float*)d_out);
}

// Round 5
// 747.584 us; speedup vs baseline: 3.8110x; 1.0432x over previous
//
#include <hip/hip_runtime.h>
#include <hip/hip_bf16.h>
#include <math.h>

#define NN 50000
#define EE 800000
#define ET_ 850000
#define NG 64
#define NB 196   // ceil(NN/256)
#define PB 1024  // pool blocks

// ---------- GEMM: H = X @ W  (X:[N,128], W:[128,128]), optional fused BN+ReLU on X ----------
__global__ __launch_bounds__(256) void gemm_xw(const float* __restrict__ X,
    const float* __restrict__ W, float* __restrict__ H, int N,
    const float* __restrict__ scale, const float* __restrict__ shift){
  __shared__ float Ws[64*128];
  __shared__ float Xs[64*128];
  const int t = threadIdx.x;
  const int row0 = blockIdx.x * 64;
  for (int i = t*4; i < 64*128; i += 1024){
    int r = i >> 7, c = i & 127;
    int gr = row0 + r;
    float4 v = make_float4(0.f,0.f,0.f,0.f);
    if (gr < N) v = *(const float4*)(X + (size_t)gr*128 + c);
    if (scale){
      float4 sc = *(const float4*)(scale + c);
      float4 sh = *(const float4*)(shift + c);
      v.x = fmaxf(fmaf(v.x, sc.x, sh.x), 0.f);
      v.y = fmaxf(fmaf(v.y, sc.y, sh.y), 0.f);
      v.z = fmaxf(fmaf(v.z, sc.z, sh.z), 0.f);
      v.w = fmaxf(fmaf(v.w, sc.w, sh.w), 0.f);
    }
    *(float4*)(Xs + i) = v;
  }
  const int col = t & 127;
  const int rg  = (t >> 7) * 32;
  float acc[32];
  #pragma unroll
  for (int r=0;r<32;r++) acc[r]=0.f;
  for (int ko=0; ko<128; ko+=64){
    __syncthreads();
    for (int i = t*4; i < 64*128; i += 1024)
      *(float4*)(Ws + i) = *(const float4*)(W + (size_t)ko*128 + i);
    __syncthreads();
    for (int k=0;k<64;k+=4){
      float w0 = Ws[(k+0)*128+col];
      float w1 = Ws[(k+1)*128+col];
      float w2 = Ws[(k+2)*128+col];
      float w3 = Ws[(k+3)*128+col];
      #pragma unroll
      for (int r=0;r<32;r++){
        float4 xv = *(const float4*)(Xs + (rg+r)*128 + ko + k);
        acc[r] += xv.x*w0 + xv.y*w1 + xv.z*w2 + xv.w*w3;
      }
    }
  }
  for (int r=0;r<32;r++){
    int gr = row0 + rg + r;
    if (gr < N) H[(size_t)gr*128 + col] = acc[r];
  }
}

// ---------- per-(node,head) attention logit prep ----------
__global__ __launch_bounds__(256) void attn_prep(const float* __restrict__ hbuf,
    const float* __restrict__ av, const float* __restrict__ dv,
    float* __restrict__ esrc, float* __restrict__ edst){
  int idx = blockIdx.x*256 + threadIdx.x;
  if (idx >= NN*4) return;
  int n = idx >> 2, hh = idx & 3;
  const float* hp = hbuf + (size_t)n*128 + hh*32;
  const float* ap = av + hh*32;
  const float* dp = dv + hh*32;
  float ss = 0.f, ds = 0.f;
  #pragma unroll
  for (int k=0;k<32;k+=4){
    float4 hv = *(const float4*)(hp + k);
    float4 a4 = *(const float4*)(ap + k);
    float4 d4 = *(const float4*)(dp + k);
    ss += hv.x*a4.x + hv.y*a4.y + hv.z*a4.z + hv.w*a4.w;
    ds += hv.x*d4.x + hv.y*d4.y + hv.z*d4.z + hv.w*d4.w;
  }
  esrc[idx] = ss; edst[idx] = ds;
}

// ---------- CSR build: histogram ----------
__global__ __launch_bounds__(256) void hist_kernel(const int* __restrict__ ei,
    int* __restrict__ cnt){
  int i = blockIdx.x*256 + threadIdx.x;
  if (i >= ET_) return;
  int d = (i < EE) ? ei[EE + i] : (i - EE);
  atomicAdd(cnt + d, 1);
}

// ---------- CSR build: parallel 3-phase scan ----------
__global__ __launch_bounds__(256) void scan_partial(const int* __restrict__ cnt,
    int* __restrict__ rowptr, int* __restrict__ bsum){
  __shared__ int sh[256];
  const int t = threadIdx.x;
  const int i = blockIdx.x*256 + t;
  int v = (i < NN) ? cnt[i] : 0;
  sh[t] = v; __syncthreads();
  for (int o=1;o<256;o<<=1){
    int u = (t>=o) ? sh[t-o] : 0;
    __syncthreads();
    sh[t] += u;
    __syncthreads();
  }
  if (i < NN) rowptr[i] = sh[t] - v;
  if (t == 255) bsum[blockIdx.x] = sh[255];
}

__global__ __launch_bounds__(256) void scan_bsum(int* __restrict__ bsum){
  __shared__ int sh[256];
  const int t = threadIdx.x;
  int v = (t < NB) ? bsum[t] : 0;
  sh[t] = v; __syncthreads();
  for (int o=1;o<256;o<<=1){
    int u = (t>=o) ? sh[t-o] : 0;
    __syncthreads();
    sh[t] += u;
    __syncthreads();
  }
  if (t < NB) bsum[t] = sh[t] - v;
}

__global__ __launch_bounds__(256) void scan_add(int* __restrict__ rowptr,
    const int* __restrict__ bsum, int* __restrict__ head){
  const int i = blockIdx.x*256 + threadIdx.x;
  if (i < NN){
    int r = rowptr[i] + bsum[blockIdx.x];
    rowptr[i] = r; head[i] = r;
  }
  if (i == NN) rowptr[NN] = ET_;
}

// ---------- CSR build: scatter src ids ----------
__global__ __launch_bounds__(256) void scatter_kernel(const int* __restrict__ ei,
    int* __restrict__ head, int* __restrict__ csr_src){
  int i = blockIdx.x*256 + threadIdx.x;
  if (i >= ET_) return;
  int s, d;
  if (i < EE){ s = ei[i]; d = ei[EE + i]; } else { s = i - EE; d = s; }
  int pos = atomicAdd(head + d, 1);
  csr_src[pos] = s;
}

// ---------- fused GAT aggregate: one wave per destination node ----------
// LDS-staged edge chunks; 2 edges/iter (lanes 0-31 edge A, 32-63 edge B, float4 channels).
__global__ __launch_bounds__(256) void gat_fused(const int* __restrict__ rowptr,
    const int* __restrict__ csr_src, const float* __restrict__ esrc,
    const float* __restrict__ edst, const float* __restrict__ hbuf,
    const float* __restrict__ bias, const int* __restrict__ ntype,
    float* __restrict__ y){
  __shared__ int   srcs[4][64];
  __shared__ float wts[4][64][4];
  const int w    = threadIdx.x >> 6;
  const int lane = threadIdx.x & 63;
  const int wid  = blockIdx.x*4 + w;
  if (wid >= NN) return;
  const int d = wid;
  const int beg = rowptr[d], end = rowptr[d+1];
  const float4 ed4 = *(const float4*)(edst + (size_t)d*4);

  const int c4   = (lane & 31) * 4;    // this lane's 4 channels
  const int eh   = lane >> 5;          // which edge of the pair (0/1)
  const int head = (lane & 31) >> 3;   // c4 >> 5

  float dn0=0.f, dn1=0.f, dn2=0.f, dn3=0.f;
  float4 acc = make_float4(0.f,0.f,0.f,0.f);

  const int*   sp = &srcs[w][eh];          // stride 2 ints per pair
  const float* wp = &wts[w][eh][head];     // stride 8 floats per pair

  for (int j0 = beg; j0 < end; j0 += 64){
    int j = j0 + lane;
    int s = d;
    float ex0=0.f, ex1=0.f, ex2=0.f, ex3=0.f;
    if (j < end){
      s = csr_src[j];
      float4 es = *(const float4*)(esrc + (size_t)s*4);
      float e0 = es.x + ed4.x; e0 = (e0 > 0.f) ? e0 : 0.2f*e0;
      float e1 = es.y + ed4.y; e1 = (e1 > 0.f) ? e1 : 0.2f*e1;
      float e2 = es.z + ed4.z; e2 = (e2 > 0.f) ? e2 : 0.2f*e2;
      float e3 = es.w + ed4.w; e3 = (e3 > 0.f) ? e3 : 0.2f*e3;
      ex0 = expf(e0); ex1 = expf(e1); ex2 = expf(e2); ex3 = expf(e3);
      dn0 += ex0; dn1 += ex1; dn2 += ex2; dn3 += ex3;
    }
    srcs[w][lane] = s;           // wave-private LDS; in-wave lgkmcnt ordering
    wts[w][lane][0] = ex0;
    wts[w][lane][1] = ex1;
    wts[w][lane][2] = ex2;
    wts[w][lane][3] = ex3;
    int cnt2 = end - j0; if (cnt2 > 64) cnt2 = 64;
    const int npair = (cnt2 + 1) >> 1;
    #pragma unroll 4
    for (int p = 0; p < npair; p++){
      int   s2 = sp[p*2];
      float wg = wp[p*8];
      float4 hv = *(const float4*)(hbuf + (size_t)s2*128 + c4);
      acc.x = fmaf(hv.x, wg, acc.x);
      acc.y = fmaf(hv.y, wg, acc.y);
      acc.z = fmaf(hv.z, wg, acc.z);
      acc.w = fmaf(hv.w, wg, acc.w);
    }
  }
  // reduce denominators across all 64 lanes
  #pragma unroll
  for (int o = 32; o; o >>= 1){
    dn0 += __shfl_xor(dn0, o);
    dn1 += __shfl_xor(dn1, o);
    dn2 += __shfl_xor(dn2, o);
    dn3 += __shfl_xor(dn3, o);
  }
  float dsel = (head==0) ? dn0 : (head==1) ? dn1 : (head==2) ? dn2 : dn3;
  float inv = 1.f / (dsel + 1e-16f);
  // combine the two edge-halves
  acc.x += __shfl_xor(acc.x, 32);
  acc.y += __shfl_xor(acc.y, 32);
  acc.z += __shfl_xor(acc.z, 32);
  acc.w += __shfl_xor(acc.w, 32);
  if (eh == 0){
    float aw = (ntype[d] == 0) ? 1.5f : 1.0f;
    float4 bb = *(const float4*)(bias + c4);
    float4 o4;
    o4.x = (acc.x*inv + bb.x) * aw;
    o4.y = (acc.y*inv + bb.y) * aw;
    o4.z = (acc.z*inv + bb.z) * aw;
    o4.w = (acc.w*inv + bb.w) * aw;
    *(float4*)(y + (size_t)d*128 + c4) = o4;
  }
}

// ---------- BN stats (read-only) ----------
__global__ __launch_bounds__(256) void epi_stats(const float* __restrict__ y,
    double* __restrict__ bnsum, double* __restrict__ bnsumsq, int N){
  __shared__ float red[256][8];
  const int t = threadIdx.x;
  const int c4 = (t & 31) * 4;
  const int rowInBlk = t >> 5;
  const int stride = gridDim.x * 8;
  float s0=0,s1=0,s2=0,s3=0,q0=0,q1=0,q2=0,q3=0;
  for (int n = blockIdx.x*8 + rowInBlk; n < N; n += stride){
    float4 v = *(const float4*)(y + (size_t)n*128 + c4);
    s0+=v.x; s1+=v.y; s2+=v.z; s3+=v.w;
    q0+=v.x*v.x; q1+=v.y*v.y; q2+=v.z*v.z; q3+=v.w*v.w;
  }
  red[t][0]=s0; red[t][1]=s1; red[t][2]=s2; red[t][3]=s3;
  red[t][4]=q0; red[t][5]=q1; red[t][6]=q2; red[t][7]=q3;
  __syncthreads();
  if (t < 32){
    float a[8] = {0,0,0,0,0,0,0,0};
    for (int j=0;j<8;j++){
      #pragma unroll
      for (int k2=0;k2<8;k2++) a[k2] += red[j*32+t][k2];
    }
    atomicAdd(bnsum   + t*4+0, (double)a[0]);
    atomicAdd(bnsum   + t*4+1, (double)a[1]);
    atomicAdd(bnsum   + t*4+2, (double)a[2]);
    atomicAdd(bnsum   + t*4+3, (double)a[3]);
    atomicAdd(bnsumsq + t*4+0, (double)a[4]);
    atomicAdd(bnsumsq + t*4+1, (double)a[5]);
    atomicAdd(bnsumsq + t*4+2, (double)a[6]);
    atomicAdd(bnsumsq + t*4+3, (double)a[7]);
  }
}

// ---------- BN finalize ----------
__global__ void bn_final(const double* __restrict__ bnsum, const double* __restrict__ bnsumsq,
    const float* __restrict__ gma, const float* __restrict__ bta,
    float* __restrict__ scale, float* __restrict__ shift, int N){
  int c = threadIdx.x;
  double mu  = bnsum[c] / N;
  double var = bnsumsq[c] / N - mu*mu;
  if (var < 0.0) var = 0.0;
  float inv = (float)(1.0 / sqrt(var + 1e-5));
  float sc  = inv * gma[c];
  scale[c] = sc;
  shift[c] = bta[c] - (float)mu * sc;
}

// ---------- pool phase 1: BN+ReLU+partial per-graph sums (sorted batch) ----------
__global__ __launch_bounds__(256) void pool_partial(const float* __restrict__ y,
    const int* __restrict__ batch, const float* __restrict__ scale,
    const float* __restrict__ shift, float* __restrict__ pooled){
  const int t = threadIdx.x;
  const int c = t & 127;
  const int sub = t >> 7;
  const int per = (NN + PB - 1) / PB;
  const int n0 = blockIdx.x * per;
  int n1 = n0 + per; if (n1 > NN) n1 = NN;
  const float sc = scale[c], sh = shift[c];
  float acc = 0.f;
  int curg = -1;
  for (int n = n0 + sub; n < n1; n += 2){
    int g = batch[n];
    if (g != curg){
      if (curg >= 0) unsafeAtomicAdd(pooled + (size_t)curg*128 + c, acc);
      curg = g; acc = 0.f;
    }
    float v = y[(size_t)n*128 + c];
    acc += fmaxf(fmaf(v, sc, sh), 0.f);
  }
  if (curg >= 0) unsafeAtomicAdd(pooled + (size_t)curg*128 + c, acc);
}

// ---------- pool phase 2: mean + MLP head ----------
__global__ __launch_bounds__(128) void mlp_head(const float* __restrict__ pooled,
    const int* __restrict__ batch, const float* __restrict__ fc1w,
    const float* __restrict__ fc1b, const float* __restrict__ fc2w,
    const float* __restrict__ fc2b, float* __restrict__ out){
  __shared__ float psh[128];
  __shared__ float hid[32];
  const int g = blockIdx.x, t = threadIdx.x;
  int lo = 0, hi = NN;
  while (lo < hi){ int mid = (lo+hi)>>1; if (batch[mid] < g) lo = mid+1; else hi = mid; }
  const int beg = lo;
  lo = beg; hi = NN;
  while (lo < hi){ int mid = (lo+hi)>>1; if (batch[mid] < g+1) lo = mid+1; else hi = mid; }
  int cntn = lo - beg; if (cntn < 1) cntn = 1;
  psh[t] = pooled[(size_t)g*128 + t] / (float)cntn;
  __syncthreads();
  if (t < 32){
    float a = fc1b[t];
    for (int k=0;k<128;k++) a += psh[k]*fc1w[k*32+t];
    a = (a > 0.f) ? a : 0.f;
    hid[t] = a * fc2w[t];
  }
  __syncthreads();
  if (t == 0){
    float sacc = fc2b[0];
    #pragma unroll
    for (int j=0;j<32;j++) sacc += hid[j];
    out[g] = sacc;
  }
}

extern "C" void kernel_launch(void* const* d_in, const int* in_sizes, int n_in,
                              void* d_out, int out_size, void* d_ws, size_t ws_size,
                              hipStream_t stream){
  const float* x     = (const float*)d_in[0];
  const int*   ei    = (const int*)d_in[1];
  const int*   ntype = (const int*)d_in[2];
  const int*   batch = (const int*)d_in[3];
  const float* Wl[3]  = {(const float*)d_in[4],  (const float*)d_in[10], (const float*)d_in[16]};
  const float* asl[3] = {(const float*)d_in[5],  (const float*)d_in[11], (const float*)d_in[17]};
  const float* adl[3] = {(const float*)d_in[6],  (const float*)d_in[12], (const float*)d_in[18]};
  const float* bl[3]  = {(const float*)d_in[7],  (const float*)d_in[13], (const float*)d_in[19]};
  const float* gl[3]  = {(const float*)d_in[8],  (const float*)d_in[14], (const float*)d_in[20]};
  const float* bel[3] = {(const float*)d_in[9],  (const float*)d_in[15], (const float*)d_in[21]};
  const float* fc1w = (const float*)d_in[22];
  const float* fc1b = (const float*)d_in[23];
  const float* fc2w = (const float*)d_in[24];
  const float* fc2b = (const float*)d_in[25];

  char* base = (char*)d_ws;
  size_t off = 0;
  auto alloc = [&](size_t bytes)->char*{
    size_t o = (off + 255) & ~(size_t)255; off = o + bytes; return base + o;
  };
  float* hbuf    = (float*)alloc((size_t)NN*128*4);
  float* y       = (float*)alloc((size_t)NN*128*4);
  float* esrc    = (float*)alloc((size_t)NN*4*4);
  float* edst    = (float*)alloc((size_t)NN*4*4);
  int*   cnt     = (int*)  alloc((size_t)NN*4);
  int*   rowptr  = (int*)  alloc((size_t)(NN+1)*4);
  int*   head    = (int*)  alloc((size_t)NN*4);
  int*   csr_src = (int*)  alloc((size_t)ET_*4);
  int*   bsum    = (int*)  alloc((size_t)NB*4);
  double* bnsum  = (double*)alloc(128*8);
  double* bnsumsq= (double*)alloc(128*8);
  float* scale   = (float*)alloc(128*4);
  float* shift   = (float*)alloc(128*4);
  float* pooled  = (float*)alloc((size_t)NG*128*4);
  if (off > ws_size) return;

  // ---- CSR build (once; reused by all 3 layers) ----
  hipMemsetAsync(cnt, 0, (size_t)NN*4, stream);
  hipMemsetAsync(pooled, 0, (size_t)NG*128*4, stream);
  hist_kernel<<<(ET_+255)/256, 256, 0, stream>>>(ei, cnt);
  scan_partial<<<NB, 256, 0, stream>>>(cnt, rowptr, bsum);
  scan_bsum<<<1, 256, 0, stream>>>(bsum);
  scan_add<<<NB, 256, 0, stream>>>(rowptr, bsum, head);
  scatter_kernel<<<(ET_+255)/256, 256, 0, stream>>>(ei, head, csr_src);

  const int gemmBlocks = (NN + 63)/64;
  for (int l = 0; l < 3; l++){
    const float* in = (l==0) ? x : y;
    const float* scl = (l==0) ? nullptr : scale;
    const float* shf = (l==0) ? nullptr : shift;
    hipMemsetAsync(bnsum, 0, 128*8*2, stream);
    gemm_xw<<<gemmBlocks, 256, 0, stream>>>(in, Wl[l], hbuf, NN, scl, shf);
    attn_prep<<<(NN*4+255)/256, 256, 0, stream>>>(hbuf, asl[l], adl[l], esrc, edst);
    gat_fused<<<(NN+3)/4, 256, 0, stream>>>(rowptr, csr_src, esrc, edst, hbuf, bl[l], ntype, y);
    epi_stats<<<256, 256, 0, stream>>>(y, bnsum, bnsumsq, NN);
    bn_final<<<1, 128, 0, stream>>>(bnsum, bnsumsq, gl[l], bel[l], scale, shift, NN);
  }
  pool_partial<<<PB, 256, 0, stream>>>(y, batch, scale, shift, pooled);
  mlp_head<<<NG, 128, 0, stream>>>(pooled, batch, fc1w, fc1b, fc2w, fc2b, (float*)d_out);
}

// Round 6
// 694.549 us; speedup vs baseline: 4.1020x; 1.0764x over previous
//
#include <hip/hip_runtime.h>
#include <hip/hip_bf16.h>
#include <math.h>

#define NN 50000
#define EE 800000
#define ET_ 850000
#define NG 64
#define NB 196   // ceil(NN/256)
#define PB 1024  // pool blocks

typedef __attribute__((ext_vector_type(8))) short bf16x8;
typedef __attribute__((ext_vector_type(4))) float f32x4;

// ---- split f32 -> bf16 hi + bf16 lo (RNE both) ----
__device__ __forceinline__ void bsplit(float v, ushort& h, ushort& l){
  unsigned u = __float_as_uint(v);
  unsigned hb = (u + 0x7fffu + ((u >> 16) & 1u)) >> 16;
  h = (ushort)hb;
  float hf = __uint_as_float(hb << 16);
  float r = v - hf;
  unsigned ur = __float_as_uint(r);
  l = (ushort)((ur + 0x7fffu + ((ur >> 16) & 1u)) >> 16);
}

// ---------- convert input (optionally BN+ReLU) to bf16 hi/lo ----------
__global__ __launch_bounds__(256) void convx(const float* __restrict__ in,
    ushort* __restrict__ hi, ushort* __restrict__ lo,
    const float* __restrict__ scale, const float* __restrict__ shift){
  int i4 = blockIdx.x*256 + threadIdx.x;
  if (i4 >= NN*32) return;
  size_t i = (size_t)i4*4;
  int c = (int)(i & 127);
  float4 v = *(const float4*)(in + i);
  if (scale){
    float4 sc = *(const float4*)(scale + c);
    float4 sh = *(const float4*)(shift + c);
    v.x = fmaxf(fmaf(v.x, sc.x, sh.x), 0.f);
    v.y = fmaxf(fmaf(v.y, sc.y, sh.y), 0.f);
    v.z = fmaxf(fmaf(v.z, sc.z, sh.z), 0.f);
    v.w = fmaxf(fmaf(v.w, sc.w, sh.w), 0.f);
  }
  ushort4 h, l2;
  bsplit(v.x, h.x, l2.x);
  bsplit(v.y, h.y, l2.y);
  bsplit(v.z, h.z, l2.z);
  bsplit(v.w, h.w, l2.w);
  *(ushort4*)(hi + i) = h;
  *(ushort4*)(lo + i) = l2;
}

// ---------- convert W -> W^T bf16 hi/lo ----------
__global__ __launch_bounds__(256) void convw(const float* __restrict__ W,
    ushort* __restrict__ whi, ushort* __restrict__ wlo){
  int idx = blockIdx.x*256 + threadIdx.x;
  if (idx >= 128*128) return;
  int c = idx & 127, k = idx >> 7;
  float v = W[(size_t)k*128 + c];
  ushort h, l;
  bsplit(v, h, l);
  whi[(size_t)c*128 + k] = h;
  wlo[(size_t)c*128 + k] = l;
}

// ---------- MFMA GEMM: H = X @ W via split-bf16 (3-term) ----------
// block = 4 waves; wave w: rows bid*64 + w*16 .. +15, all 128 cols. No LDS.
__global__ __launch_bounds__(256) void gemm_mfma(const ushort* __restrict__ xhi,
    const ushort* __restrict__ xlo, const ushort* __restrict__ wthi,
    const ushort* __restrict__ wtlo, float* __restrict__ H, int N){
  const int w  = threadIdx.x >> 6;
  const int l  = threadIdx.x & 63;
  const int lr = l & 15;
  const int lk = (l >> 4) * 8;
  const int arow = blockIdx.x*64 + w*16 + lr;
  const bool av = (arow < N);
  const size_t abase = (size_t)(av ? arow : 0) * 128;
  const bf16x8 zz = {0,0,0,0,0,0,0,0};
  bf16x8 ahi[4], alo[4];
  #pragma unroll
  for (int kb = 0; kb < 4; kb++){
    ahi[kb] = av ? *(const bf16x8*)(xhi + abase + kb*32 + lk) : zz;
    alo[kb] = av ? *(const bf16x8*)(xlo + abase + kb*32 + lk) : zz;
  }
  const int crow0 = blockIdx.x*64 + w*16 + (l >> 4)*4;
  #pragma unroll 2
  for (int ct = 0; ct < 8; ct++){
    f32x4 acc = {0.f, 0.f, 0.f, 0.f};
    const ushort* bh = wthi + (size_t)(ct*16 + lr)*128 + lk;
    const ushort* bl = wtlo + (size_t)(ct*16 + lr)*128 + lk;
    #pragma unroll
    for (int kb = 0; kb < 4; kb++){
      bf16x8 bhf = *(const bf16x8*)(bh + kb*32);
      bf16x8 blf = *(const bf16x8*)(bl + kb*32);
      acc = __builtin_amdgcn_mfma_f32_16x16x32_bf16(ahi[kb], bhf, acc, 0, 0, 0);
      acc = __builtin_amdgcn_mfma_f32_16x16x32_bf16(ahi[kb], blf, acc, 0, 0, 0);
      acc = __builtin_amdgcn_mfma_f32_16x16x32_bf16(alo[kb], bhf, acc, 0, 0, 0);
    }
    #pragma unroll
    for (int j = 0; j < 4; j++){
      int r = crow0 + j;
      if (r < N) H[(size_t)r*128 + ct*16 + lr] = acc[j];
    }
  }
}

// ---------- per-(node,head) attention logit prep ----------
__global__ __launch_bounds__(256) void attn_prep(const float* __restrict__ hbuf,
    const float* __restrict__ av, const float* __restrict__ dv,
    float* __restrict__ esrc, float* __restrict__ edst){
  int idx = blockIdx.x*256 + threadIdx.x;
  if (idx >= NN*4) return;
  int n = idx >> 2, hh = idx & 3;
  const float* hp = hbuf + (size_t)n*128 + hh*32;
  const float* ap = av + hh*32;
  const float* dp = dv + hh*32;
  float ss = 0.f, ds = 0.f;
  #pragma unroll
  for (int k=0;k<32;k+=4){
    float4 hv = *(const float4*)(hp + k);
    float4 a4 = *(const float4*)(ap + k);
    float4 d4 = *(const float4*)(dp + k);
    ss += hv.x*a4.x + hv.y*a4.y + hv.z*a4.z + hv.w*a4.w;
    ds += hv.x*d4.x + hv.y*d4.y + hv.z*d4.z + hv.w*d4.w;
  }
  esrc[idx] = ss; edst[idx] = ds;
}

// ---------- CSR build: histogram ----------
__global__ __launch_bounds__(256) void hist_kernel(const int* __restrict__ ei,
    int* __restrict__ cnt){
  int i = blockIdx.x*256 + threadIdx.x;
  if (i >= ET_) return;
  int d = (i < EE) ? ei[EE + i] : (i - EE);
  atomicAdd(cnt + d, 1);
}

// ---------- CSR build: parallel 3-phase scan ----------
__global__ __launch_bounds__(256) void scan_partial(const int* __restrict__ cnt,
    int* __restrict__ rowptr, int* __restrict__ bsum){
  __shared__ int sh[256];
  const int t = threadIdx.x;
  const int i = blockIdx.x*256 + t;
  int v = (i < NN) ? cnt[i] : 0;
  sh[t] = v; __syncthreads();
  for (int o=1;o<256;o<<=1){
    int u = (t>=o) ? sh[t-o] : 0;
    __syncthreads();
    sh[t] += u;
    __syncthreads();
  }
  if (i < NN) rowptr[i] = sh[t] - v;
  if (t == 255) bsum[blockIdx.x] = sh[255];
}

__global__ __launch_bounds__(256) void scan_bsum(int* __restrict__ bsum){
  __shared__ int sh[256];
  const int t = threadIdx.x;
  int v = (t < NB) ? bsum[t] : 0;
  sh[t] = v; __syncthreads();
  for (int o=1;o<256;o<<=1){
    int u = (t>=o) ? sh[t-o] : 0;
    __syncthreads();
    sh[t] += u;
    __syncthreads();
  }
  if (t < NB) bsum[t] = sh[t] - v;
}

__global__ __launch_bounds__(256) void scan_add(int* __restrict__ rowptr,
    const int* __restrict__ bsum, int* __restrict__ head){
  const int i = blockIdx.x*256 + threadIdx.x;
  if (i < NN){
    int r = rowptr[i] + bsum[blockIdx.x];
    rowptr[i] = r; head[i] = r;
  }
  if (i == NN) rowptr[NN] = ET_;
}

// ---------- CSR build: scatter src ids ----------
__global__ __launch_bounds__(256) void scatter_kernel(const int* __restrict__ ei,
    int* __restrict__ head, int* __restrict__ csr_src){
  int i = blockIdx.x*256 + threadIdx.x;
  if (i >= ET_) return;
  int s, d;
  if (i < EE){ s = ei[i]; d = ei[EE + i]; } else { s = i - EE; d = s; }
  int pos = atomicAdd(head + d, 1);
  csr_src[pos] = s;
}

// ---------- fused GAT aggregate: one wave per destination node ----------
__global__ __launch_bounds__(256) void gat_fused(const int* __restrict__ rowptr,
    const int* __restrict__ csr_src, const float* __restrict__ esrc,
    const float* __restrict__ edst, const float* __restrict__ hbuf,
    const float* __restrict__ bias, const int* __restrict__ ntype,
    float* __restrict__ y){
  __shared__ int   srcs[4][64];
  __shared__ float wts[4][64][4];
  const int w    = threadIdx.x >> 6;
  const int lane = threadIdx.x & 63;
  const int wid  = blockIdx.x*4 + w;
  if (wid >= NN) return;
  const int d = wid;
  const int beg = rowptr[d], end = rowptr[d+1];
  const float4 ed4 = *(const float4*)(edst + (size_t)d*4);

  const int c4   = (lane & 31) * 4;
  const int eh   = lane >> 5;
  const int head = (lane & 31) >> 3;

  float dn0=0.f, dn1=0.f, dn2=0.f, dn3=0.f;
  float4 acc = make_float4(0.f,0.f,0.f,0.f);

  const int*   sp = &srcs[w][eh];
  const float* wp = &wts[w][eh][head];

  for (int j0 = beg; j0 < end; j0 += 64){
    int j = j0 + lane;
    int s = d;
    float ex0=0.f, ex1=0.f, ex2=0.f, ex3=0.f;
    if (j < end){
      s = csr_src[j];
      float4 es = *(const float4*)(esrc + (size_t)s*4);
      float e0 = es.x + ed4.x; e0 = (e0 > 0.f) ? e0 : 0.2f*e0;
      float e1 = es.y + ed4.y; e1 = (e1 > 0.f) ? e1 : 0.2f*e1;
      float e2 = es.z + ed4.z; e2 = (e2 > 0.f) ? e2 : 0.2f*e2;
      float e3 = es.w + ed4.w; e3 = (e3 > 0.f) ? e3 : 0.2f*e3;
      ex0 = expf(e0); ex1 = expf(e1); ex2 = expf(e2); ex3 = expf(e3);
      dn0 += ex0; dn1 += ex1; dn2 += ex2; dn3 += ex3;
    }
    srcs[w][lane] = s;
    wts[w][lane][0] = ex0;
    wts[w][lane][1] = ex1;
    wts[w][lane][2] = ex2;
    wts[w][lane][3] = ex3;
    int cnt2 = end - j0; if (cnt2 > 64) cnt2 = 64;
    const int npair = (cnt2 + 1) >> 1;
    #pragma unroll 4
    for (int p = 0; p < npair; p++){
      int   s2 = sp[p*2];
      float wg = wp[p*8];
      float4 hv = *(const float4*)(hbuf + (size_t)s2*128 + c4);
      acc.x = fmaf(hv.x, wg, acc.x);
      acc.y = fmaf(hv.y, wg, acc.y);
      acc.z = fmaf(hv.z, wg, acc.z);
      acc.w = fmaf(hv.w, wg, acc.w);
    }
  }
  #pragma unroll
  for (int o = 32; o; o >>= 1){
    dn0 += __shfl_xor(dn0, o);
    dn1 += __shfl_xor(dn1, o);
    dn2 += __shfl_xor(dn2, o);
    dn3 += __shfl_xor(dn3, o);
  }
  float dsel = (head==0) ? dn0 : (head==1) ? dn1 : (head==2) ? dn2 : dn3;
  float inv = 1.f / (dsel + 1e-16f);
  acc.x += __shfl_xor(acc.x, 32);
  acc.y += __shfl_xor(acc.y, 32);
  acc.z += __shfl_xor(acc.z, 32);
  acc.w += __shfl_xor(acc.w, 32);
  if (eh == 0){
    float aw = (ntype[d] == 0) ? 1.5f : 1.0f;
    float4 bb = *(const float4*)(bias + c4);
    float4 o4;
    o4.x = (acc.x*inv + bb.x) * aw;
    o4.y = (acc.y*inv + bb.y) * aw;
    o4.z = (acc.z*inv + bb.z) * aw;
    o4.w = (acc.w*inv + bb.w) * aw;
    *(float4*)(y + (size_t)d*128 + c4) = o4;
  }
}

// ---------- BN stats (read-only) ----------
__global__ __launch_bounds__(256) void epi_stats(const float* __restrict__ y,
    double* __restrict__ bnsum, double* __restrict__ bnsumsq, int N){
  __shared__ float red[256][8];
  const int t = threadIdx.x;
  const int c4 = (t & 31) * 4;
  const int rowInBlk = t >> 5;
  const int stride = gridDim.x * 8;
  float s0=0,s1=0,s2=0,s3=0,q0=0,q1=0,q2=0,q3=0;
  for (int n = blockIdx.x*8 + rowInBlk; n < N; n += stride){
    float4 v = *(const float4*)(y + (size_t)n*128 + c4);
    s0+=v.x; s1+=v.y; s2+=v.z; s3+=v.w;
    q0+=v.x*v.x; q1+=v.y*v.y; q2+=v.z*v.z; q3+=v.w*v.w;
  }
  red[t][0]=s0; red[t][1]=s1; red[t][2]=s2; red[t][3]=s3;
  red[t][4]=q0; red[t][5]=q1; red[t][6]=q2; red[t][7]=q3;
  __syncthreads();
  if (t < 32){
    float a[8] = {0,0,0,0,0,0,0,0};
    for (int j=0;j<8;j++){
      #pragma unroll
      for (int k2=0;k2<8;k2++) a[k2] += red[j*32+t][k2];
    }
    atomicAdd(bnsum   + t*4+0, (double)a[0]);
    atomicAdd(bnsum   + t*4+1, (double)a[1]);
    atomicAdd(bnsum   + t*4+2, (double)a[2]);
    atomicAdd(bnsum   + t*4+3, (double)a[3]);
    atomicAdd(bnsumsq + t*4+0, (double)a[4]);
    atomicAdd(bnsumsq + t*4+1, (double)a[5]);
    atomicAdd(bnsumsq + t*4+2, (double)a[6]);
    atomicAdd(bnsumsq + t*4+3, (double)a[7]);
  }
}

// ---------- BN finalize ----------
__global__ void bn_final(const double* __restrict__ bnsum, const double* __restrict__ bnsumsq,
    const float* __restrict__ gma, const float* __restrict__ bta,
    float* __restrict__ scale, float* __restrict__ shift, int N){
  int c = threadIdx.x;
  double mu  = bnsum[c] / N;
  double var = bnsumsq[c] / N - mu*mu;
  if (var < 0.0) var = 0.0;
  float inv = (float)(1.0 / sqrt(var + 1e-5));
  float sc  = inv * gma[c];
  scale[c] = sc;
  shift[c] = bta[c] - (float)mu * sc;
}

// ---------- pool phase 1: BN+ReLU+partial per-graph sums (sorted batch) ----------
__global__ __launch_bounds__(256) void pool_partial(const float* __restrict__ y,
    const int* __restrict__ batch, const float* __restrict__ scale,
    const float* __restrict__ shift, float* __restrict__ pooled){
  const int t = threadIdx.x;
  const int c = t & 127;
  const int sub = t >> 7;
  const int per = (NN + PB - 1) / PB;
  const int n0 = blockIdx.x * per;
  int n1 = n0 + per; if (n1 > NN) n1 = NN;
  const float sc = scale[c], sh = shift[c];
  float acc = 0.f;
  int curg = -1;
  for (int n = n0 + sub; n < n1; n += 2){
    int g = batch[n];
    if (g != curg){
      if (curg >= 0) unsafeAtomicAdd(pooled + (size_t)curg*128 + c, acc);
      curg = g; acc = 0.f;
    }
    float v = y[(size_t)n*128 + c];
    acc += fmaxf(fmaf(v, sc, sh), 0.f);
  }
  if (curg >= 0) unsafeAtomicAdd(pooled + (size_t)curg*128 + c, acc);
}

// ---------- pool phase 2: mean + MLP head ----------
__global__ __launch_bounds__(128) void mlp_head(const float* __restrict__ pooled,
    const int* __restrict__ batch, const float* __restrict__ fc1w,
    const float* __restrict__ fc1b, const float* __restrict__ fc2w,
    const float* __restrict__ fc2b, float* __restrict__ out){
  __shared__ float psh[128];
  __shared__ float hid[32];
  const int g = blockIdx.x, t = threadIdx.x;
  int lo = 0, hi = NN;
  while (lo < hi){ int mid = (lo+hi)>>1; if (batch[mid] < g) lo = mid+1; else hi = mid; }
  const int beg = lo;
  lo = beg; hi = NN;
  while (lo < hi){ int mid = (lo+hi)>>1; if (batch[mid] < g+1) lo = mid+1; else hi = mid; }
  int cntn = lo - beg; if (cntn < 1) cntn = 1;
  psh[t] = pooled[(size_t)g*128 + t] / (float)cntn;
  __syncthreads();
  if (t < 32){
    float a = fc1b[t];
    for (int k=0;k<128;k++) a += psh[k]*fc1w[k*32+t];
    a = (a > 0.f) ? a : 0.f;
    hid[t] = a * fc2w[t];
  }
  __syncthreads();
  if (t == 0){
    float sacc = fc2b[0];
    #pragma unroll
    for (int j=0;j<32;j++) sacc += hid[j];
    out[g] = sacc;
  }
}

extern "C" void kernel_launch(void* const* d_in, const int* in_sizes, int n_in,
                              void* d_out, int out_size, void* d_ws, size_t ws_size,
                              hipStream_t stream){
  const float* x     = (const float*)d_in[0];
  const int*   ei    = (const int*)d_in[1];
  const int*   ntype = (const int*)d_in[2];
  const int*   batch = (const int*)d_in[3];
  const float* Wl[3]  = {(const float*)d_in[4],  (const float*)d_in[10], (const float*)d_in[16]};
  const float* asl[3] = {(const float*)d_in[5],  (const float*)d_in[11], (const float*)d_in[17]};
  const float* adl[3] = {(const float*)d_in[6],  (const float*)d_in[12], (const float*)d_in[18]};
  const float* bl[3]  = {(const float*)d_in[7],  (const float*)d_in[13], (const float*)d_in[19]};
  const float* gl[3]  = {(const float*)d_in[8],  (const float*)d_in[14], (const float*)d_in[20]};
  const float* bel[3] = {(const float*)d_in[9],  (const float*)d_in[15], (const float*)d_in[21]};
  const float* fc1w = (const float*)d_in[22];
  const float* fc1b = (const float*)d_in[23];
  const float* fc2w = (const float*)d_in[24];
  const float* fc2b = (const float*)d_in[25];

  char* base = (char*)d_ws;
  size_t off = 0;
  auto alloc = [&](size_t bytes)->char*{
    size_t o = (off + 255) & ~(size_t)255; off = o + bytes; return base + o;
  };
  float* hbuf    = (float*)alloc((size_t)NN*128*4);
  float* y       = (float*)alloc((size_t)NN*128*4);
  ushort* xhi    = (ushort*)alloc((size_t)NN*128*2);
  ushort* xlo    = (ushort*)alloc((size_t)NN*128*2);
  ushort* wthi   = (ushort*)alloc((size_t)128*128*2);
  ushort* wtlo   = (ushort*)alloc((size_t)128*128*2);
  float* esrc    = (float*)alloc((size_t)NN*4*4);
  float* edst    = (float*)alloc((size_t)NN*4*4);
  int*   cnt     = (int*)  alloc((size_t)NN*4);
  int*   rowptr  = (int*)  alloc((size_t)(NN+1)*4);
  int*   head    = (int*)  alloc((size_t)NN*4);
  int*   csr_src = (int*)  alloc((size_t)ET_*4);
  int*   bsum    = (int*)  alloc((size_t)NB*4);
  double* bnsum  = (double*)alloc(128*8);
  double* bnsumsq= (double*)alloc(128*8);
  float* scale   = (float*)alloc(128*4);
  float* shift   = (float*)alloc(128*4);
  float* pooled  = (float*)alloc((size_t)NG*128*4);
  if (off > ws_size) return;

  // ---- CSR build (once; reused by all 3 layers) ----
  hipMemsetAsync(cnt, 0, (size_t)NN*4, stream);
  hipMemsetAsync(pooled, 0, (size_t)NG*128*4, stream);
  hist_kernel<<<(ET_+255)/256, 256, 0, stream>>>(ei, cnt);
  scan_partial<<<NB, 256, 0, stream>>>(cnt, rowptr, bsum);
  scan_bsum<<<1, 256, 0, stream>>>(bsum);
  scan_add<<<NB, 256, 0, stream>>>(rowptr, bsum, head);
  scatter_kernel<<<(ET_+255)/256, 256, 0, stream>>>(ei, head, csr_src);

  const int gemmBlocks = (NN + 63)/64;
  for (int l = 0; l < 3; l++){
    const float* in = (l==0) ? x : y;
    const float* scl = (l==0) ? nullptr : scale;
    const float* shf = (l==0) ? nullptr : shift;
    hipMemsetAsync(bnsum, 0, 128*8*2, stream);
    convw<<<64, 256, 0, stream>>>(Wl[l], wthi, wtlo);
    convx<<<(NN*32+255)/256, 256, 0, stream>>>(in, xhi, xlo, scl, shf);
    gemm_mfma<<<gemmBlocks, 256, 0, stream>>>(xhi, xlo, wthi, wtlo, hbuf, NN);
    attn_prep<<<(NN*4+255)/256, 256, 0, stream>>>(hbuf, asl[l], adl[l], esrc, edst);
    gat_fused<<<(NN+3)/4, 256, 0, stream>>>(rowptr, csr_src, esrc, edst, hbuf, bl[l], ntype, y);
    epi_stats<<<256, 256, 0, stream>>>(y, bnsum, bnsumsq, NN);
    bn_final<<<1, 128, 0, stream>>>(bnsum, bnsumsq, gl[l], bel[l], scale, shift, NN);
  }
  pool_partial<<<PB, 256, 0, stream>>>(y, batch, scale, shift, pooled);
  mlp_head<<<NG, 128, 0, stream>>>(pooled, batch, fc1w, fc1b, fc2w, fc2b, (float*)d_out);
}

// Round 7
// 583.337 us; speedup vs baseline: 4.8841x; 1.1906x over previous
//
#include <hip/hip_runtime.h>
#include <hip/hip_bf16.h>
#include <math.h>

#define NN 50000
#define EE 800000
#define ET_ 850000
#define NG 64
#define NB 196   // ceil(NN/256)
#define PB 1024  // pool blocks
#define GB 391   // ceil(NN/128) gemm blocks

typedef __attribute__((ext_vector_type(8))) short bf16x8;
typedef __attribute__((ext_vector_type(4))) float f32x4;

// ---- split f32 -> bf16 hi + bf16 lo (RNE both) ----
__device__ __forceinline__ void bsplit(float v, ushort& h, ushort& l){
  unsigned u = __float_as_uint(v);
  unsigned hb = (u + 0x7fffu + ((u >> 16) & 1u)) >> 16;
  h = (ushort)hb;
  float hf = __uint_as_float(hb << 16);
  float r = v - hf;
  unsigned ur = __float_as_uint(r);
  l = (ushort)((ur + 0x7fffu + ((ur >> 16) & 1u)) >> 16);
}

// ---------- convert W -> fragment-packed W^T bf16 hi/lo ----------
// element (k,c) of W goes to frag slot: ct=c>>4, kb=k>>5, l=((k&31)>>3)<<4 | (c&15), j=k&7
__global__ __launch_bounds__(256) void convw(const float* __restrict__ W,
    ushort* __restrict__ wfrag){
  int idx = blockIdx.x*256 + threadIdx.x;   // idx = k*128 + c
  if (idx >= 128*128) return;
  int c = idx & 127, k = idx >> 7;
  float v = W[idx];
  ushort h, lo;
  bsplit(v, h, lo);
  int dest = (((c>>4)*4 + (k>>5))*64 + (((k&31)>>3)<<4 | (c&15)))*8 + (k&7);
  wfrag[dest] = h;
  wfrag[16384 + dest] = lo;
}

// ---------- fused: [BN+ReLU] -> split-bf16 MFMA GEMM -> H + attention logits ----------
// 512 threads = 8 waves; wave w handles rows bid*128 + w*16 .. +15, all 128 cols.
__global__ __launch_bounds__(512) void gemm_fused(const float* __restrict__ X,
    const ushort* __restrict__ wfrag,
    const float* __restrict__ scale, const float* __restrict__ shift,
    const float* __restrict__ av, const float* __restrict__ dv,
    float* __restrict__ H, float* __restrict__ esrc, float* __restrict__ edst, int N){
  __shared__ ushort wl[32768];   // 64 KB: hi [0..16383], lo [16384..]
  const int tid = threadIdx.x;
  #pragma unroll
  for (int i = 0; i < 8; i++){
    int e = (i*512 + tid) * 8;
    *(bf16x8*)(wl + e) = *(const bf16x8*)(wfrag + e);
  }
  const int w  = tid >> 6;
  const int l  = tid & 63;
  const int lr = l & 15;
  const int lg = l >> 4;
  const int lk = lg * 8;
  const int arow = blockIdx.x*128 + w*16 + lr;
  const bool avl = (arow < N);
  const size_t abase = (size_t)(avl ? arow : 0) * 128;
  bf16x8 ahi[4], alo[4];
  #pragma unroll
  for (int kb = 0; kb < 4; kb++){
    float a[8];
    if (avl){
      *(float4*)(a)   = *(const float4*)(X + abase + kb*32 + lk);
      *(float4*)(a+4) = *(const float4*)(X + abase + kb*32 + lk + 4);
    } else {
      #pragma unroll
      for (int j=0;j<8;j++) a[j] = 0.f;
    }
    if (scale){
      float s[8], b[8];
      *(float4*)(s)   = *(const float4*)(scale + kb*32 + lk);
      *(float4*)(s+4) = *(const float4*)(scale + kb*32 + lk + 4);
      *(float4*)(b)   = *(const float4*)(shift + kb*32 + lk);
      *(float4*)(b+4) = *(const float4*)(shift + kb*32 + lk + 4);
      #pragma unroll
      for (int j=0;j<8;j++) a[j] = fmaxf(fmaf(a[j], s[j], b[j]), 0.f);
    }
    #pragma unroll
    for (int j=0;j<8;j++){
      ushort hh2, ll2;
      bsplit(a[j], hh2, ll2);
      ahi[kb][j] = (short)hh2;
      alo[kb][j] = (short)ll2;
    }
  }
  __syncthreads();
  float esp[4][4], edp[4][4];   // [j][h], all indices compile-time (full unroll)
  #pragma unroll
  for (int j=0;j<4;j++)
    #pragma unroll
    for (int h=0;h<4;h++){ esp[j][h]=0.f; edp[j][h]=0.f; }
  const int crowb = blockIdx.x*128 + w*16 + lg*4;
  #pragma unroll
  for (int ct = 0; ct < 8; ct++){
    f32x4 acc = {0.f,0.f,0.f,0.f};
    #pragma unroll
    for (int kb = 0; kb < 4; kb++){
      const int fi = ((ct*4 + kb)*64 + l) * 8;
      bf16x8 bhf = *(const bf16x8*)(wl + fi);
      bf16x8 blf = *(const bf16x8*)(wl + 16384 + fi);
      acc = __builtin_amdgcn_mfma_f32_16x16x32_bf16(ahi[kb], bhf, acc, 0, 0, 0);
      acc = __builtin_amdgcn_mfma_f32_16x16x32_bf16(ahi[kb], blf, acc, 0, 0, 0);
      acc = __builtin_amdgcn_mfma_f32_16x16x32_bf16(alo[kb], bhf, acc, 0, 0, 0);
    }
    const int h = ct >> 1;
    const float asv = av[h*32 + (ct&1)*16 + lr];
    const float adv = dv[h*32 + (ct&1)*16 + lr];
    #pragma unroll
    for (int j = 0; j < 4; j++){
      esp[j][h] = fmaf(acc[j], asv, esp[j][h]);
      edp[j][h] = fmaf(acc[j], adv, edp[j][h]);
      int r = crowb + j;
      if (r < N) H[(size_t)r*128 + ct*16 + lr] = acc[j];
    }
  }
  #pragma unroll
  for (int o = 1; o < 16; o <<= 1){
    #pragma unroll
    for (int j=0;j<4;j++)
      #pragma unroll
      for (int h=0;h<4;h++){
        esp[j][h] += __shfl_xor(esp[j][h], o);
        edp[j][h] += __shfl_xor(edp[j][h], o);
      }
  }
  const int jj = lr >> 2, hh = lr & 3;
  float eo = 0.f, dd = 0.f;
  #pragma unroll
  for (int j=0;j<4;j++)
    #pragma unroll
    for (int h=0;h<4;h++){
      bool m = (jj==j) & (hh==h);
      eo = m ? esp[j][h] : eo;
      dd = m ? edp[j][h] : dd;
    }
  const int rw = crowb + jj;
  if (rw < N){
    esrc[rw*4 + hh] = eo;
    edst[rw*4 + hh] = dd;
  }
}

// ---------- CSR build: histogram ----------
__global__ __launch_bounds__(256) void hist_kernel(const int* __restrict__ ei,
    int* __restrict__ cnt){
  int i = blockIdx.x*256 + threadIdx.x;
  if (i >= ET_) return;
  int d = (i < EE) ? ei[EE + i] : (i - EE);
  atomicAdd(cnt + d, 1);
}

// ---------- CSR build: parallel 3-phase scan ----------
__global__ __launch_bounds__(256) void scan_partial(const int* __restrict__ cnt,
    int* __restrict__ rowptr, int* __restrict__ bsum){
  __shared__ int sh[256];
  const int t = threadIdx.x;
  const int i = blockIdx.x*256 + t;
  int v = (i < NN) ? cnt[i] : 0;
  sh[t] = v; __syncthreads();
  for (int o=1;o<256;o<<=1){
    int u = (t>=o) ? sh[t-o] : 0;
    __syncthreads();
    sh[t] += u;
    __syncthreads();
  }
  if (i < NN) rowptr[i] = sh[t] - v;
  if (t == 255) bsum[blockIdx.x] = sh[255];
}

__global__ __launch_bounds__(256) void scan_bsum(int* __restrict__ bsum){
  __shared__ int sh[256];
  const int t = threadIdx.x;
  int v = (t < NB) ? bsum[t] : 0;
  sh[t] = v; __syncthreads();
  for (int o=1;o<256;o<<=1){
    int u = (t>=o) ? sh[t-o] : 0;
    __syncthreads();
    sh[t] += u;
    __syncthreads();
  }
  if (t < NB) bsum[t] = sh[t] - v;
}

__global__ __launch_bounds__(256) void scan_add(int* __restrict__ rowptr,
    const int* __restrict__ bsum, int* __restrict__ head){
  const int i = blockIdx.x*256 + threadIdx.x;
  if (i < NN){
    int r = rowptr[i] + bsum[blockIdx.x];
    rowptr[i] = r; head[i] = r;
  }
  if (i == NN) rowptr[NN] = ET_;
}

// ---------- CSR build: scatter src ids ----------
__global__ __launch_bounds__(256) void scatter_kernel(const int* __restrict__ ei,
    int* __restrict__ head, int* __restrict__ csr_src){
  int i = blockIdx.x*256 + threadIdx.x;
  if (i >= ET_) return;
  int s, d;
  if (i < EE){ s = ei[i]; d = ei[EE + i]; } else { s = i - EE; d = s; }
  int pos = atomicAdd(head + d, 1);
  csr_src[pos] = s;
}

// ---------- fused GAT aggregate: one wave per destination node ----------
__global__ __launch_bounds__(256) void gat_fused(const int* __restrict__ rowptr,
    const int* __restrict__ csr_src, const float* __restrict__ esrc,
    const float* __restrict__ edst, const float* __restrict__ hbuf,
    const float* __restrict__ bias, const int* __restrict__ ntype,
    float* __restrict__ y){
  __shared__ int   srcs[4][64];
  __shared__ float wts[4][64][4];
  const int w    = threadIdx.x >> 6;
  const int lane = threadIdx.x & 63;
  const int wid  = blockIdx.x*4 + w;
  if (wid >= NN) return;
  const int d = wid;
  const int beg = rowptr[d], end = rowptr[d+1];
  const float4 ed4 = *(const float4*)(edst + (size_t)d*4);

  const int c4   = (lane & 31) * 4;
  const int eh   = lane >> 5;
  const int head = (lane & 31) >> 3;

  float dn0=0.f, dn1=0.f, dn2=0.f, dn3=0.f;
  float4 acc0 = make_float4(0.f,0.f,0.f,0.f);
  float4 acc1 = make_float4(0.f,0.f,0.f,0.f);

  const int*   sp = &srcs[w][eh];
  const float* wp = &wts[w][eh][head];

  for (int j0 = beg; j0 < end; j0 += 64){
    int j = j0 + lane;
    int s = d;
    float ex0=0.f, ex1=0.f, ex2=0.f, ex3=0.f;
    if (j < end){
      s = csr_src[j];
      float4 es = *(const float4*)(esrc + (size_t)s*4);
      float e0 = es.x + ed4.x; e0 = (e0 > 0.f) ? e0 : 0.2f*e0;
      float e1 = es.y + ed4.y; e1 = (e1 > 0.f) ? e1 : 0.2f*e1;
      float e2 = es.z + ed4.z; e2 = (e2 > 0.f) ? e2 : 0.2f*e2;
      float e3 = es.w + ed4.w; e3 = (e3 > 0.f) ? e3 : 0.2f*e3;
      ex0 = expf(e0); ex1 = expf(e1); ex2 = expf(e2); ex3 = expf(e3);
      dn0 += ex0; dn1 += ex1; dn2 += ex2; dn3 += ex3;
    }
    srcs[w][lane] = s;
    wts[w][lane][0] = ex0;
    wts[w][lane][1] = ex1;
    wts[w][lane][2] = ex2;
    wts[w][lane][3] = ex3;
    int cnt2 = end - j0; if (cnt2 > 64) cnt2 = 64;
    const int npair = (cnt2 + 1) >> 1;
    int p = 0;
    #pragma unroll 2
    for (; p + 2 <= npair; p += 2){
      int   sa = sp[p*2];
      int   sb = sp[p*2 + 2];
      float wa = wp[p*8];
      float wb = wp[p*8 + 8];
      float4 ha = *(const float4*)(hbuf + (size_t)sa*128 + c4);
      float4 hb = *(const float4*)(hbuf + (size_t)sb*128 + c4);
      acc0.x = fmaf(ha.x, wa, acc0.x);
      acc0.y = fmaf(ha.y, wa, acc0.y);
      acc0.z = fmaf(ha.z, wa, acc0.z);
      acc0.w = fmaf(ha.w, wa, acc0.w);
      acc1.x = fmaf(hb.x, wb, acc1.x);
      acc1.y = fmaf(hb.y, wb, acc1.y);
      acc1.z = fmaf(hb.z, wb, acc1.z);
      acc1.w = fmaf(hb.w, wb, acc1.w);
    }
    if (p < npair){
      int   sa = sp[p*2];
      float wa = wp[p*8];
      float4 ha = *(const float4*)(hbuf + (size_t)sa*128 + c4);
      acc0.x = fmaf(ha.x, wa, acc0.x);
      acc0.y = fmaf(ha.y, wa, acc0.y);
      acc0.z = fmaf(ha.z, wa, acc0.z);
      acc0.w = fmaf(ha.w, wa, acc0.w);
    }
  }
  #pragma unroll
  for (int o = 32; o; o >>= 1){
    dn0 += __shfl_xor(dn0, o);
    dn1 += __shfl_xor(dn1, o);
    dn2 += __shfl_xor(dn2, o);
    dn3 += __shfl_xor(dn3, o);
  }
  float dsel = (head==0) ? dn0 : (head==1) ? dn1 : (head==2) ? dn2 : dn3;
  float inv = 1.f / (dsel + 1e-16f);
  float4 acc;
  acc.x = acc0.x + acc1.x;
  acc.y = acc0.y + acc1.y;
  acc.z = acc0.z + acc1.z;
  acc.w = acc0.w + acc1.w;
  acc.x += __shfl_xor(acc.x, 32);
  acc.y += __shfl_xor(acc.y, 32);
  acc.z += __shfl_xor(acc.z, 32);
  acc.w += __shfl_xor(acc.w, 32);
  if (eh == 0){
    float aw = (ntype[d] == 0) ? 1.5f : 1.0f;
    float4 bb = *(const float4*)(bias + c4);
    float4 o4;
    o4.x = (acc.x*inv + bb.x) * aw;
    o4.y = (acc.y*inv + bb.y) * aw;
    o4.z = (acc.z*inv + bb.z) * aw;
    o4.w = (acc.w*inv + bb.w) * aw;
    *(float4*)(y + (size_t)d*128 + c4) = o4;
  }
}

// ---------- BN stats (read-only) ----------
__global__ __launch_bounds__(256) void epi_stats(const float* __restrict__ y,
    double* __restrict__ bnsum, double* __restrict__ bnsumsq, int N){
  __shared__ float red[256][8];
  const int t = threadIdx.x;
  const int c4 = (t & 31) * 4;
  const int rowInBlk = t >> 5;
  const int stride = gridDim.x * 8;
  float s0=0,s1=0,s2=0,s3=0,q0=0,q1=0,q2=0,q3=0;
  for (int n = blockIdx.x*8 + rowInBlk; n < N; n += stride){
    float4 v = *(const float4*)(y + (size_t)n*128 + c4);
    s0+=v.x; s1+=v.y; s2+=v.z; s3+=v.w;
    q0+=v.x*v.x; q1+=v.y*v.y; q2+=v.z*v.z; q3+=v.w*v.w;
  }
  red[t][0]=s0; red[t][1]=s1; red[t][2]=s2; red[t][3]=s3;
  red[t][4]=q0; red[t][5]=q1; red[t][6]=q2; red[t][7]=q3;
  __syncthreads();
  if (t < 32){
    float a[8] = {0,0,0,0,0,0,0,0};
    for (int j=0;j<8;j++){
      #pragma unroll
      for (int k2=0;k2<8;k2++) a[k2] += red[j*32+t][k2];
    }
    atomicAdd(bnsum   + t*4+0, (double)a[0]);
    atomicAdd(bnsum   + t*4+1, (double)a[1]);
    atomicAdd(bnsum   + t*4+2, (double)a[2]);
    atomicAdd(bnsum   + t*4+3, (double)a[3]);
    atomicAdd(bnsumsq + t*4+0, (double)a[4]);
    atomicAdd(bnsumsq + t*4+1, (double)a[5]);
    atomicAdd(bnsumsq + t*4+2, (double)a[6]);
    atomicAdd(bnsumsq + t*4+3, (double)a[7]);
  }
}

// ---------- BN finalize ----------
__global__ void bn_final(const double* __restrict__ bnsum, const double* __restrict__ bnsumsq,
    const float* __restrict__ gma, const float* __restrict__ bta,
    float* __restrict__ scale, float* __restrict__ shift, int N){
  int c = threadIdx.x;
  double mu  = bnsum[c] / N;
  double var = bnsumsq[c] / N - mu*mu;
  if (var < 0.0) var = 0.0;
  float inv = (float)(1.0 / sqrt(var + 1e-5));
  float sc  = inv * gma[c];
  scale[c] = sc;
  shift[c] = bta[c] - (float)mu * sc;
}

// ---------- pool phase 1: BN+ReLU+partial per-graph sums (sorted batch) ----------
__global__ __launch_bounds__(256) void pool_partial(const float* __restrict__ y,
    const int* __restrict__ batch, const float* __restrict__ scale,
    const float* __restrict__ shift, float* __restrict__ pooled){
  const int t = threadIdx.x;
  const int c = t & 127;
  const int sub = t >> 7;
  const int per = (NN + PB - 1) / PB;
  const int n0 = blockIdx.x * per;
  int n1 = n0 + per; if (n1 > NN) n1 = NN;
  const float sc = scale[c], sh = shift[c];
  float acc = 0.f;
  int curg = -1;
  for (int n = n0 + sub; n < n1; n += 2){
    int g = batch[n];
    if (g != curg){
      if (curg >= 0) unsafeAtomicAdd(pooled + (size_t)curg*128 + c, acc);
      curg = g; acc = 0.f;
    }
    float v = y[(size_t)n*128 + c];
    acc += fmaxf(fmaf(v, sc, sh), 0.f);
  }
  if (curg >= 0) unsafeAtomicAdd(pooled + (size_t)curg*128 + c, acc);
}

// ---------- pool phase 2: mean + MLP head ----------
__global__ __launch_bounds__(128) void mlp_head(const float* __restrict__ pooled,
    const int* __restrict__ batch, const float* __restrict__ fc1w,
    const float* __restrict__ fc1b, const float* __restrict__ fc2w,
    const float* __restrict__ fc2b, float* __restrict__ out){
  __shared__ float psh[128];
  __shared__ float hid[32];
  const int g = blockIdx.x, t = threadIdx.x;
  int lo = 0, hi = NN;
  while (lo < hi){ int mid = (lo+hi)>>1; if (batch[mid] < g) lo = mid+1; else hi = mid; }
  const int beg = lo;
  lo = beg; hi = NN;
  while (lo < hi){ int mid = (lo+hi)>>1; if (batch[mid] < g+1) lo = mid+1; else hi = mid; }
  int cntn = lo - beg; if (cntn < 1) cntn = 1;
  psh[t] = pooled[(size_t)g*128 + t] / (float)cntn;
  __syncthreads();
  if (t < 32){
    float a = fc1b[t];
    for (int k=0;k<128;k++) a += psh[k]*fc1w[k*32+t];
    a = (a > 0.f) ? a : 0.f;
    hid[t] = a * fc2w[t];
  }
  __syncthreads();
  if (t == 0){
    float sacc = fc2b[0];
    #pragma unroll
    for (int j=0;j<32;j++) sacc += hid[j];
    out[g] = sacc;
  }
}

extern "C" void kernel_launch(void* const* d_in, const int* in_sizes, int n_in,
                              void* d_out, int out_size, void* d_ws, size_t ws_size,
                              hipStream_t stream){
  const float* x     = (const float*)d_in[0];
  const int*   ei    = (const int*)d_in[1];
  const int*   ntype = (const int*)d_in[2];
  const int*   batch = (const int*)d_in[3];
  const float* Wl[3]  = {(const float*)d_in[4],  (const float*)d_in[10], (const float*)d_in[16]};
  const float* asl[3] = {(const float*)d_in[5],  (const float*)d_in[11], (const float*)d_in[17]};
  const float* adl[3] = {(const float*)d_in[6],  (const float*)d_in[12], (const float*)d_in[18]};
  const float* bl[3]  = {(const float*)d_in[7],  (const float*)d_in[13], (const float*)d_in[19]};
  const float* gl[3]  = {(const float*)d_in[8],  (const float*)d_in[14], (const float*)d_in[20]};
  const float* bel[3] = {(const float*)d_in[9],  (const float*)d_in[15], (const float*)d_in[21]};
  const float* fc1w = (const float*)d_in[22];
  const float* fc1b = (const float*)d_in[23];
  const float* fc2w = (const float*)d_in[24];
  const float* fc2b = (const float*)d_in[25];

  char* base = (char*)d_ws;
  size_t off = 0;
  auto alloc = [&](size_t bytes)->char*{
    size_t o = (off + 255) & ~(size_t)255; off = o + bytes; return base + o;
  };
  float* hbuf    = (float*)alloc((size_t)NN*128*4);
  float* y       = (float*)alloc((size_t)NN*128*4);
  ushort* wfrag  = (ushort*)alloc((size_t)32768*2);
  float* esrc    = (float*)alloc((size_t)NN*4*4);
  float* edst    = (float*)alloc((size_t)NN*4*4);
  int*   cnt     = (int*)  alloc((size_t)NN*4);
  int*   rowptr  = (int*)  alloc((size_t)(NN+1)*4);
  int*   head    = (int*)  alloc((size_t)NN*4);
  int*   csr_src = (int*)  alloc((size_t)ET_*4);
  int*   bsum    = (int*)  alloc((size_t)NB*4);
  double* bnsum  = (double*)alloc(128*8);
  double* bnsumsq= (double*)alloc(128*8);
  float* scale   = (float*)alloc(128*4);
  float* shift   = (float*)alloc(128*4);
  float* pooled  = (float*)alloc((size_t)NG*128*4);
  if (off > ws_size) return;

  // ---- CSR build (once; reused by all 3 layers) ----
  hipMemsetAsync(cnt, 0, (size_t)NN*4, stream);
  hipMemsetAsync(pooled, 0, (size_t)NG*128*4, stream);
  hist_kernel<<<(ET_+255)/256, 256, 0, stream>>>(ei, cnt);
  scan_partial<<<NB, 256, 0, stream>>>(cnt, rowptr, bsum);
  scan_bsum<<<1, 256, 0, stream>>>(bsum);
  scan_add<<<NB, 256, 0, stream>>>(rowptr, bsum, head);
  scatter_kernel<<<(ET_+255)/256, 256, 0, stream>>>(ei, head, csr_src);

  for (int l = 0; l < 3; l++){
    const float* in = (l==0) ? x : y;
    const float* scl = (l==0) ? nullptr : scale;
    const float* shf = (l==0) ? nullptr : shift;
    hipMemsetAsync(bnsum, 0, 128*8*2, stream);
    convw<<<64, 256, 0, stream>>>(Wl[l], wfrag);
    gemm_fused<<<GB, 512, 0, stream>>>(in, wfrag, scl, shf, asl[l], adl[l],
                                       hbuf, esrc, edst, NN);
    gat_fused<<<(NN+3)/4, 256, 0, stream>>>(rowptr, csr_src, esrc, edst, hbuf, bl[l], ntype, y);
    epi_stats<<<256, 256, 0, stream>>>(y, bnsum, bnsumsq, NN);
    bn_final<<<1, 128, 0, stream>>>(bnsum, bnsumsq, gl[l], bel[l], scale, shift, NN);
  }
  pool_partial<<<PB, 256, 0, stream>>>(y, batch, scale, shift, pooled);
  mlp_head<<<NG, 128, 0, stream>>>(pooled, batch, fc1w, fc1b, fc2w, fc2b, (float*)d_out);
}

// Round 8
// 504.902 us; speedup vs baseline: 5.6428x; 1.1553x over previous
//
#include <hip/hip_runtime.h>
#include <hip/hip_bf16.h>
#include <math.h>

#define NN 50000
#define EE 800000
#define ET_ 850000
#define NG 64
#define NB 196   // ceil(NN/256)
#define PB 1024  // pool blocks
#define GB 391   // ceil(NN/128) gemm blocks

typedef __attribute__((ext_vector_type(8))) short bf16x8;
typedef __attribute__((ext_vector_type(4))) float f32x4;
typedef __attribute__((ext_vector_type(4))) _Float16 h16x4;

// ---- split f32 -> bf16 hi + bf16 lo (RNE both) ----
__device__ __forceinline__ void bsplit(float v, ushort& h, ushort& l){
  unsigned u = __float_as_uint(v);
  unsigned hb = (u + 0x7fffu + ((u >> 16) & 1u)) >> 16;
  h = (ushort)hb;
  float hf = __uint_as_float(hb << 16);
  float r = v - hf;
  unsigned ur = __float_as_uint(r);
  l = (ushort)((ur + 0x7fffu + ((ur >> 16) & 1u)) >> 16);
}

// ---------- convert W -> fragment-packed W^T bf16 hi/lo ----------
__global__ __launch_bounds__(256) void convw(const float* __restrict__ W,
    ushort* __restrict__ wfrag){
  int idx = blockIdx.x*256 + threadIdx.x;   // idx = k*128 + c
  if (idx >= 128*128) return;
  int c = idx & 127, k = idx >> 7;
  float v = W[idx];
  ushort h, lo;
  bsplit(v, h, lo);
  int dest = (((c>>4)*4 + (k>>5))*64 + (((k&31)>>3)<<4 | (c&15)))*8 + (k&7);
  wfrag[dest] = h;
  wfrag[16384 + dest] = lo;
}

// ---------- fused: [BN+ReLU] -> split-bf16 MFMA GEMM -> H(f16) + attention logits ----------
__global__ __launch_bounds__(512) void gemm_fused(const float* __restrict__ X,
    const ushort* __restrict__ wfrag,
    const float* __restrict__ scale, const float* __restrict__ shift,
    const float* __restrict__ av, const float* __restrict__ dv,
    _Float16* __restrict__ H, float* __restrict__ esrc, float* __restrict__ edst, int N){
  __shared__ ushort wl[32768];   // 64 KB: hi [0..16383], lo [16384..]
  const int tid = threadIdx.x;
  #pragma unroll
  for (int i = 0; i < 8; i++){
    int e = (i*512 + tid) * 8;
    *(bf16x8*)(wl + e) = *(const bf16x8*)(wfrag + e);
  }
  const int w  = tid >> 6;
  const int l  = tid & 63;
  const int lr = l & 15;
  const int lg = l >> 4;
  const int lk = lg * 8;
  const int arow = blockIdx.x*128 + w*16 + lr;
  const bool avl = (arow < N);
  const size_t abase = (size_t)(avl ? arow : 0) * 128;
  bf16x8 ahi[4], alo[4];
  #pragma unroll
  for (int kb = 0; kb < 4; kb++){
    float a[8];
    if (avl){
      *(float4*)(a)   = *(const float4*)(X + abase + kb*32 + lk);
      *(float4*)(a+4) = *(const float4*)(X + abase + kb*32 + lk + 4);
    } else {
      #pragma unroll
      for (int j=0;j<8;j++) a[j] = 0.f;
    }
    if (scale){
      float s[8], b[8];
      *(float4*)(s)   = *(const float4*)(scale + kb*32 + lk);
      *(float4*)(s+4) = *(const float4*)(scale + kb*32 + lk + 4);
      *(float4*)(b)   = *(const float4*)(shift + kb*32 + lk);
      *(float4*)(b+4) = *(const float4*)(shift + kb*32 + lk + 4);
      #pragma unroll
      for (int j=0;j<8;j++) a[j] = fmaxf(fmaf(a[j], s[j], b[j]), 0.f);
    }
    #pragma unroll
    for (int j=0;j<8;j++){
      ushort hh2, ll2;
      bsplit(a[j], hh2, ll2);
      ahi[kb][j] = (short)hh2;
      alo[kb][j] = (short)ll2;
    }
  }
  __syncthreads();
  float esp[4][4], edp[4][4];
  #pragma unroll
  for (int j=0;j<4;j++)
    #pragma unroll
    for (int h=0;h<4;h++){ esp[j][h]=0.f; edp[j][h]=0.f; }
  const int crowb = blockIdx.x*128 + w*16 + lg*4;
  #pragma unroll
  for (int ct = 0; ct < 8; ct++){
    f32x4 acc = {0.f,0.f,0.f,0.f};
    #pragma unroll
    for (int kb = 0; kb < 4; kb++){
      const int fi = ((ct*4 + kb)*64 + l) * 8;
      bf16x8 bhf = *(const bf16x8*)(wl + fi);
      bf16x8 blf = *(const bf16x8*)(wl + 16384 + fi);
      acc = __builtin_amdgcn_mfma_f32_16x16x32_bf16(ahi[kb], bhf, acc, 0, 0, 0);
      acc = __builtin_amdgcn_mfma_f32_16x16x32_bf16(ahi[kb], blf, acc, 0, 0, 0);
      acc = __builtin_amdgcn_mfma_f32_16x16x32_bf16(alo[kb], bhf, acc, 0, 0, 0);
    }
    const int h = ct >> 1;
    const float asv = av[h*32 + (ct&1)*16 + lr];
    const float adv = dv[h*32 + (ct&1)*16 + lr];
    #pragma unroll
    for (int j = 0; j < 4; j++){
      esp[j][h] = fmaf(acc[j], asv, esp[j][h]);
      edp[j][h] = fmaf(acc[j], adv, edp[j][h]);
      int r = crowb + j;
      if (r < N) H[(size_t)r*128 + ct*16 + lr] = (_Float16)acc[j];
    }
  }
  #pragma unroll
  for (int o = 1; o < 16; o <<= 1){
    #pragma unroll
    for (int j=0;j<4;j++)
      #pragma unroll
      for (int h=0;h<4;h++){
        esp[j][h] += __shfl_xor(esp[j][h], o);
        edp[j][h] += __shfl_xor(edp[j][h], o);
      }
  }
  const int jj = lr >> 2, hh = lr & 3;
  float eo = 0.f, dd = 0.f;
  #pragma unroll
  for (int j=0;j<4;j++)
    #pragma unroll
    for (int h=0;h<4;h++){
      bool m = (jj==j) & (hh==h);
      eo = m ? esp[j][h] : eo;
      dd = m ? edp[j][h] : dd;
    }
  const int rw = crowb + jj;
  if (rw < N){
    esrc[rw*4 + hh] = eo;
    edst[rw*4 + hh] = dd;
  }
}

// ---------- CSR build: histogram ----------
__global__ __launch_bounds__(256) void hist_kernel(const int* __restrict__ ei,
    int* __restrict__ cnt){
  int i = blockIdx.x*256 + threadIdx.x;
  if (i >= ET_) return;
  int d = (i < EE) ? ei[EE + i] : (i - EE);
  atomicAdd(cnt + d, 1);
}

// ---------- CSR build: parallel 3-phase scan ----------
__global__ __launch_bounds__(256) void scan_partial(const int* __restrict__ cnt,
    int* __restrict__ rowptr, int* __restrict__ bsum){
  __shared__ int sh[256];
  const int t = threadIdx.x;
  const int i = blockIdx.x*256 + t;
  int v = (i < NN) ? cnt[i] : 0;
  sh[t] = v; __syncthreads();
  for (int o=1;o<256;o<<=1){
    int u = (t>=o) ? sh[t-o] : 0;
    __syncthreads();
    sh[t] += u;
    __syncthreads();
  }
  if (i < NN) rowptr[i] = sh[t] - v;
  if (t == 255) bsum[blockIdx.x] = sh[255];
}

__global__ __launch_bounds__(256) void scan_bsum(int* __restrict__ bsum){
  __shared__ int sh[256];
  const int t = threadIdx.x;
  int v = (t < NB) ? bsum[t] : 0;
  sh[t] = v; __syncthreads();
  for (int o=1;o<256;o<<=1){
    int u = (t>=o) ? sh[t-o] : 0;
    __syncthreads();
    sh[t] += u;
    __syncthreads();
  }
  if (t < NB) bsum[t] = sh[t] - v;
}

__global__ __launch_bounds__(256) void scan_add(int* __restrict__ rowptr,
    const int* __restrict__ bsum, int* __restrict__ head){
  const int i = blockIdx.x*256 + threadIdx.x;
  if (i < NN){
    int r = rowptr[i] + bsum[blockIdx.x];
    rowptr[i] = r; head[i] = r;
  }
  if (i == NN) rowptr[NN] = ET_;
}

// ---------- CSR build: scatter src ids ----------
__global__ __launch_bounds__(256) void scatter_kernel(const int* __restrict__ ei,
    int* __restrict__ head, int* __restrict__ csr_src){
  int i = blockIdx.x*256 + threadIdx.x;
  if (i >= ET_) return;
  int s, d;
  if (i < EE){ s = ei[i]; d = ei[EE + i]; } else { s = i - EE; d = s; }
  int pos = atomicAdd(head + d, 1);
  csr_src[pos] = s;
}

// ---------- fused GAT aggregate: one wave per destination node, f16 gather ----------
__global__ __launch_bounds__(256) void gat_fused(const int* __restrict__ rowptr,
    const int* __restrict__ csr_src, const float* __restrict__ esrc,
    const float* __restrict__ edst, const _Float16* __restrict__ hbuf,
    const float* __restrict__ bias, const int* __restrict__ ntype,
    float* __restrict__ y){
  __shared__ int2 pk[4][64][4];   // (src, wt) replicated per head; 8 KB
  const int w    = threadIdx.x >> 6;
  const int lane = threadIdx.x & 63;
  const int wid  = blockIdx.x*4 + w;
  if (wid >= NN) return;
  const int d = wid;
  const int beg = rowptr[d], end = rowptr[d+1];
  const float4 ed4 = *(const float4*)(edst + (size_t)d*4);

  const int c4   = (lane & 31) * 4;
  const int eh   = lane >> 5;
  const int head = (lane & 31) >> 3;

  float dn0=0.f, dn1=0.f, dn2=0.f, dn3=0.f;
  float4 acc0 = make_float4(0.f,0.f,0.f,0.f);
  float4 acc1 = make_float4(0.f,0.f,0.f,0.f);

  const int2* pp = &pk[w][eh][head];   // advance 8 int2 per pair

  for (int j0 = beg; j0 < end; j0 += 64){
    int j = j0 + lane;
    int s = d;
    float ex0=0.f, ex1=0.f, ex2=0.f, ex3=0.f;
    if (j < end){
      s = csr_src[j];
      float4 es = *(const float4*)(esrc + (size_t)s*4);
      float e0 = es.x + ed4.x; e0 = (e0 > 0.f) ? e0 : 0.2f*e0;
      float e1 = es.y + ed4.y; e1 = (e1 > 0.f) ? e1 : 0.2f*e1;
      float e2 = es.z + ed4.z; e2 = (e2 > 0.f) ? e2 : 0.2f*e2;
      float e3 = es.w + ed4.w; e3 = (e3 > 0.f) ? e3 : 0.2f*e3;
      ex0 = expf(e0); ex1 = expf(e1); ex2 = expf(e2); ex3 = expf(e3);
      dn0 += ex0; dn1 += ex1; dn2 += ex2; dn3 += ex3;
    }
    int4 w0 = make_int4(s, __float_as_int(ex0), s, __float_as_int(ex1));
    int4 w1 = make_int4(s, __float_as_int(ex2), s, __float_as_int(ex3));
    *(int4*)&pk[w][lane][0] = w0;
    *(int4*)&pk[w][lane][2] = w1;
    int cnt2 = end - j0; if (cnt2 > 64) cnt2 = 64;
    const int npair = (cnt2 + 1) >> 1;
    int p = 0;
    #pragma unroll 2
    for (; p + 2 <= npair; p += 2){
      int2 va = pp[p*8];
      int2 vb = pp[p*8 + 8];
      float wa = __int_as_float(va.y);
      float wb = __int_as_float(vb.y);
      h16x4 ha = *(const h16x4*)(hbuf + (size_t)va.x*128 + c4);
      h16x4 hb = *(const h16x4*)(hbuf + (size_t)vb.x*128 + c4);
      acc0.x = fmaf((float)ha.x, wa, acc0.x);
      acc0.y = fmaf((float)ha.y, wa, acc0.y);
      acc0.z = fmaf((float)ha.z, wa, acc0.z);
      acc0.w = fmaf((float)ha.w, wa, acc0.w);
      acc1.x = fmaf((float)hb.x, wb, acc1.x);
      acc1.y = fmaf((float)hb.y, wb, acc1.y);
      acc1.z = fmaf((float)hb.z, wb, acc1.z);
      acc1.w = fmaf((float)hb.w, wb, acc1.w);
    }
    if (p < npair){
      int2 va = pp[p*8];
      float wa = __int_as_float(va.y);
      h16x4 ha = *(const h16x4*)(hbuf + (size_t)va.x*128 + c4);
      acc0.x = fmaf((float)ha.x, wa, acc0.x);
      acc0.y = fmaf((float)ha.y, wa, acc0.y);
      acc0.z = fmaf((float)ha.z, wa, acc0.z);
      acc0.w = fmaf((float)ha.w, wa, acc0.w);
    }
  }
  #pragma unroll
  for (int o = 32; o; o >>= 1){
    dn0 += __shfl_xor(dn0, o);
    dn1 += __shfl_xor(dn1, o);
    dn2 += __shfl_xor(dn2, o);
    dn3 += __shfl_xor(dn3, o);
  }
  float dsel = (head==0) ? dn0 : (head==1) ? dn1 : (head==2) ? dn2 : dn3;
  float inv = 1.f / (dsel + 1e-16f);
  float4 acc;
  acc.x = acc0.x + acc1.x;
  acc.y = acc0.y + acc1.y;
  acc.z = acc0.z + acc1.z;
  acc.w = acc0.w + acc1.w;
  acc.x += __shfl_xor(acc.x, 32);
  acc.y += __shfl_xor(acc.y, 32);
  acc.z += __shfl_xor(acc.z, 32);
  acc.w += __shfl_xor(acc.w, 32);
  if (eh == 0){
    float aw = (ntype[d] == 0) ? 1.5f : 1.0f;
    float4 bb = *(const float4*)(bias + c4);
    float4 o4;
    o4.x = (acc.x*inv + bb.x) * aw;
    o4.y = (acc.y*inv + bb.y) * aw;
    o4.z = (acc.z*inv + bb.z) * aw;
    o4.w = (acc.w*inv + bb.w) * aw;
    *(float4*)(y + (size_t)d*128 + c4) = o4;
  }
}

// ---------- BN stats (read-only) ----------
__global__ __launch_bounds__(256) void epi_stats(const float* __restrict__ y,
    double* __restrict__ bnsum, double* __restrict__ bnsumsq, int N){
  __shared__ float red[256][8];
  const int t = threadIdx.x;
  const int c4 = (t & 31) * 4;
  const int rowInBlk = t >> 5;
  const int stride = gridDim.x * 8;
  float s0=0,s1=0,s2=0,s3=0,q0=0,q1=0,q2=0,q3=0;
  for (int n = blockIdx.x*8 + rowInBlk; n < N; n += stride){
    float4 v = *(const float4*)(y + (size_t)n*128 + c4);
    s0+=v.x; s1+=v.y; s2+=v.z; s3+=v.w;
    q0+=v.x*v.x; q1+=v.y*v.y; q2+=v.z*v.z; q3+=v.w*v.w;
  }
  red[t][0]=s0; red[t][1]=s1; red[t][2]=s2; red[t][3]=s3;
  red[t][4]=q0; red[t][5]=q1; red[t][6]=q2; red[t][7]=q3;
  __syncthreads();
  if (t < 32){
    float a[8] = {0,0,0,0,0,0,0,0};
    for (int j=0;j<8;j++){
      #pragma unroll
      for (int k2=0;k2<8;k2++) a[k2] += red[j*32+t][k2];
    }
    atomicAdd(bnsum   + t*4+0, (double)a[0]);
    atomicAdd(bnsum   + t*4+1, (double)a[1]);
    atomicAdd(bnsum   + t*4+2, (double)a[2]);
    atomicAdd(bnsum   + t*4+3, (double)a[3]);
    atomicAdd(bnsumsq + t*4+0, (double)a[4]);
    atomicAdd(bnsumsq + t*4+1, (double)a[5]);
    atomicAdd(bnsumsq + t*4+2, (double)a[6]);
    atomicAdd(bnsumsq + t*4+3, (double)a[7]);
  }
}

// ---------- BN finalize ----------
__global__ void bn_final(const double* __restrict__ bnsum, const double* __restrict__ bnsumsq,
    const float* __restrict__ gma, const float* __restrict__ bta,
    float* __restrict__ scale, float* __restrict__ shift, int N){
  int c = threadIdx.x;
  double mu  = bnsum[c] / N;
  double var = bnsumsq[c] / N - mu*mu;
  if (var < 0.0) var = 0.0;
  float inv = (float)(1.0 / sqrt(var + 1e-5));
  float sc  = inv * gma[c];
  scale[c] = sc;
  shift[c] = bta[c] - (float)mu * sc;
}

// ---------- pool phase 1 ----------
__global__ __launch_bounds__(256) void pool_partial(const float* __restrict__ y,
    const int* __restrict__ batch, const float* __restrict__ scale,
    const float* __restrict__ shift, float* __restrict__ pooled){
  const int t = threadIdx.x;
  const int c = t & 127;
  const int sub = t >> 7;
  const int per = (NN + PB - 1) / PB;
  const int n0 = blockIdx.x * per;
  int n1 = n0 + per; if (n1 > NN) n1 = NN;
  const float sc = scale[c], sh = shift[c];
  float acc = 0.f;
  int curg = -1;
  for (int n = n0 + sub; n < n1; n += 2){
    int g = batch[n];
    if (g != curg){
      if (curg >= 0) unsafeAtomicAdd(pooled + (size_t)curg*128 + c, acc);
      curg = g; acc = 0.f;
    }
    float v = y[(size_t)n*128 + c];
    acc += fmaxf(fmaf(v, sc, sh), 0.f);
  }
  if (curg >= 0) unsafeAtomicAdd(pooled + (size_t)curg*128 + c, acc);
}

// ---------- pool phase 2: mean + MLP head ----------
__global__ __launch_bounds__(128) void mlp_head(const float* __restrict__ pooled,
    const int* __restrict__ batch, const float* __restrict__ fc1w,
    const float* __restrict__ fc1b, const float* __restrict__ fc2w,
    const float* __restrict__ fc2b, float* __restrict__ out){
  __shared__ float psh[128];
  __shared__ float hid[32];
  const int g = blockIdx.x, t = threadIdx.x;
  int lo = 0, hi = NN;
  while (lo < hi){ int mid = (lo+hi)>>1; if (batch[mid] < g) lo = mid+1; else hi = mid; }
  const int beg = lo;
  lo = beg; hi = NN;
  while (lo < hi){ int mid = (lo+hi)>>1; if (batch[mid] < g+1) lo = mid+1; else hi = mid; }
  int cntn = lo - beg; if (cntn < 1) cntn = 1;
  psh[t] = pooled[(size_t)g*128 + t] / (float)cntn;
  __syncthreads();
  if (t < 32){
    float a = fc1b[t];
    for (int k=0;k<128;k++) a += psh[k]*fc1w[k*32+t];
    a = (a > 0.f) ? a : 0.f;
    hid[t] = a * fc2w[t];
  }
  __syncthreads();
  if (t == 0){
    float sacc = fc2b[0];
    #pragma unroll
    for (int j=0;j<32;j++) sacc += hid[j];
    out[g] = sacc;
  }
}

extern "C" void kernel_launch(void* const* d_in, const int* in_sizes, int n_in,
                              void* d_out, int out_size, void* d_ws, size_t ws_size,
                              hipStream_t stream){
  const float* x     = (const float*)d_in[0];
  const int*   ei    = (const int*)d_in[1];
  const int*   ntype = (const int*)d_in[2];
  const int*   batch = (const int*)d_in[3];
  const float* Wl[3]  = {(const float*)d_in[4],  (const float*)d_in[10], (const float*)d_in[16]};
  const float* asl[3] = {(const float*)d_in[5],  (const float*)d_in[11], (const float*)d_in[17]};
  const float* adl[3] = {(const float*)d_in[6],  (const float*)d_in[12], (const float*)d_in[18]};
  const float* bl[3]  = {(const float*)d_in[7],  (const float*)d_in[13], (const float*)d_in[19]};
  const float* gl[3]  = {(const float*)d_in[8],  (const float*)d_in[14], (const float*)d_in[20]};
  const float* bel[3] = {(const float*)d_in[9],  (const float*)d_in[15], (const float*)d_in[21]};
  const float* fc1w = (const float*)d_in[22];
  const float* fc1b = (const float*)d_in[23];
  const float* fc2w = (const float*)d_in[24];
  const float* fc2b = (const float*)d_in[25];

  char* base = (char*)d_ws;
  size_t off = 0;
  auto alloc = [&](size_t bytes)->char*{
    size_t o = (off + 255) & ~(size_t)255; off = o + bytes; return base + o;
  };
  _Float16* hbuf = (_Float16*)alloc((size_t)NN*128*2);
  float* y       = (float*)alloc((size_t)NN*128*4);
  ushort* wfrag  = (ushort*)alloc((size_t)32768*2);
  float* esrc    = (float*)alloc((size_t)NN*4*4);
  float* edst    = (float*)alloc((size_t)NN*4*4);
  int*   cnt     = (int*)  alloc((size_t)NN*4);
  int*   rowptr  = (int*)  alloc((size_t)(NN+1)*4);
  int*   head    = (int*)  alloc((size_t)NN*4);
  int*   csr_src = (int*)  alloc((size_t)ET_*4);
  int*   bsum    = (int*)  alloc((size_t)NB*4);
  double* bnsum  = (double*)alloc(128*8);
  double* bnsumsq= (double*)alloc(128*8);
  float* scale   = (float*)alloc(128*4);
  float* shift   = (float*)alloc(128*4);
  float* pooled  = (float*)alloc((size_t)NG*128*4);
  if (off > ws_size) return;

  // ---- CSR build (once; reused by all 3 layers) ----
  hipMemsetAsync(cnt, 0, (size_t)NN*4, stream);
  hipMemsetAsync(pooled, 0, (size_t)NG*128*4, stream);
  hist_kernel<<<(ET_+255)/256, 256, 0, stream>>>(ei, cnt);
  scan_partial<<<NB, 256, 0, stream>>>(cnt, rowptr, bsum);
  scan_bsum<<<1, 256, 0, stream>>>(bsum);
  scan_add<<<NB, 256, 0, stream>>>(rowptr, bsum, head);
  scatter_kernel<<<(ET_+255)/256, 256, 0, stream>>>(ei, head, csr_src);

  for (int l = 0; l < 3; l++){
    const float* in = (l==0) ? x : y;
    const float* scl = (l==0) ? nullptr : scale;
    const float* shf = (l==0) ? nullptr : shift;
    hipMemsetAsync(bnsum, 0, 128*8*2, stream);
    convw<<<64, 256, 0, stream>>>(Wl[l], wfrag);
    gemm_fused<<<GB, 512, 0, stream>>>(in, wfrag, scl, shf, asl[l], adl[l],
                                       hbuf, esrc, edst, NN);
    gat_fused<<<(NN+3)/4, 256, 0, stream>>>(rowptr, csr_src, esrc, edst, hbuf, bl[l], ntype, y);
    epi_stats<<<256, 256, 0, stream>>>(y, bnsum, bnsumsq, NN);
    bn_final<<<1, 128, 0, stream>>>(bnsum, bnsumsq, gl[l], bel[l], scale, shift, NN);
  }
  pool_partial<<<PB, 256, 0, stream>>>(y, batch, scale, shift, pooled);
  mlp_head<<<NG, 128, 0, stream>>>(pooled, batch, fc1w, fc1b, fc2w, fc2b, (float*)d_out);
}

// Round 9
// 442.662 us; speedup vs baseline: 6.4362x; 1.1406x over previous
//
#include <hip/hip_runtime.h>
#include <hip/hip_bf16.h>
#include <math.h>

#define NN 50000
#define EE 800000
#define ET_ 850000
#define NG 64
#define NB 196    // ceil(NN/256)
#define PB 1024   // pool blocks
#define GB 391    // ceil(NN/128) gemm blocks
#define NBK 196   // buckets (dst>>8)
#define BCAP 5120 // bucket capacity (mean 4337, +11 sigma)

typedef __attribute__((ext_vector_type(8))) short bf16x8;
typedef __attribute__((ext_vector_type(4))) float f32x4;
typedef __attribute__((ext_vector_type(4))) _Float16 h16x4;

// ---- split f32 -> bf16 hi + bf16 lo (RNE both) ----
__device__ __forceinline__ void bsplit(float v, ushort& h, ushort& l){
  unsigned u = __float_as_uint(v);
  unsigned hb = (u + 0x7fffu + ((u >> 16) & 1u)) >> 16;
  h = (ushort)hb;
  float hf = __uint_as_float(hb << 16);
  float r = v - hf;
  unsigned ur = __float_as_uint(r);
  l = (ushort)((ur + 0x7fffu + ((ur >> 16) & 1u)) >> 16);
}

// ---------- convert W -> fragment-packed W^T bf16 hi/lo ----------
__global__ __launch_bounds__(256) void convw(const float* __restrict__ W,
    ushort* __restrict__ wfrag){
  int idx = blockIdx.x*256 + threadIdx.x;   // idx = k*128 + c
  if (idx >= 128*128) return;
  int c = idx & 127, k = idx >> 7;
  float v = W[idx];
  ushort h, lo;
  bsplit(v, h, lo);
  int dest = (((c>>4)*4 + (k>>5))*64 + (((k&31)>>3)<<4 | (c&15)))*8 + (k&7);
  wfrag[dest] = h;
  wfrag[16384 + dest] = lo;
}

// ---------- fused: [BN+ReLU] -> split-bf16 MFMA GEMM -> H(f16) + attention logits ----------
__global__ __launch_bounds__(512) void gemm_fused(const float* __restrict__ X,
    const ushort* __restrict__ wfrag,
    const float* __restrict__ scale, const float* __restrict__ shift,
    const float* __restrict__ av, const float* __restrict__ dv,
    _Float16* __restrict__ H, float* __restrict__ esrc, float* __restrict__ edst, int N){
  __shared__ ushort wl[32768];   // 64 KB: hi [0..16383], lo [16384..]
  const int tid = threadIdx.x;
  #pragma unroll
  for (int i = 0; i < 8; i++){
    int e = (i*512 + tid) * 8;
    *(bf16x8*)(wl + e) = *(const bf16x8*)(wfrag + e);
  }
  const int w  = tid >> 6;
  const int l  = tid & 63;
  const int lr = l & 15;
  const int lg = l >> 4;
  const int lk = lg * 8;
  const int arow = blockIdx.x*128 + w*16 + lr;
  const bool avl = (arow < N);
  const size_t abase = (size_t)(avl ? arow : 0) * 128;
  bf16x8 ahi[4], alo[4];
  #pragma unroll
  for (int kb = 0; kb < 4; kb++){
    float a[8];
    if (avl){
      *(float4*)(a)   = *(const float4*)(X + abase + kb*32 + lk);
      *(float4*)(a+4) = *(const float4*)(X + abase + kb*32 + lk + 4);
    } else {
      #pragma unroll
      for (int j=0;j<8;j++) a[j] = 0.f;
    }
    if (scale){
      float s[8], b[8];
      *(float4*)(s)   = *(const float4*)(scale + kb*32 + lk);
      *(float4*)(s+4) = *(const float4*)(scale + kb*32 + lk + 4);
      *(float4*)(b)   = *(const float4*)(shift + kb*32 + lk);
      *(float4*)(b+4) = *(const float4*)(shift + kb*32 + lk + 4);
      #pragma unroll
      for (int j=0;j<8;j++) a[j] = fmaxf(fmaf(a[j], s[j], b[j]), 0.f);
    }
    #pragma unroll
    for (int j=0;j<8;j++){
      ushort hh2, ll2;
      bsplit(a[j], hh2, ll2);
      ahi[kb][j] = (short)hh2;
      alo[kb][j] = (short)ll2;
    }
  }
  __syncthreads();
  float esp[4][4], edp[4][4];
  #pragma unroll
  for (int j=0;j<4;j++)
    #pragma unroll
    for (int h=0;h<4;h++){ esp[j][h]=0.f; edp[j][h]=0.f; }
  const int crowb = blockIdx.x*128 + w*16 + lg*4;
  #pragma unroll
  for (int ct = 0; ct < 8; ct++){
    f32x4 acc = {0.f,0.f,0.f,0.f};
    #pragma unroll
    for (int kb = 0; kb < 4; kb++){
      const int fi = ((ct*4 + kb)*64 + l) * 8;
      bf16x8 bhf = *(const bf16x8*)(wl + fi);
      bf16x8 blf = *(const bf16x8*)(wl + 16384 + fi);
      acc = __builtin_amdgcn_mfma_f32_16x16x32_bf16(ahi[kb], bhf, acc, 0, 0, 0);
      acc = __builtin_amdgcn_mfma_f32_16x16x32_bf16(ahi[kb], blf, acc, 0, 0, 0);
      acc = __builtin_amdgcn_mfma_f32_16x16x32_bf16(alo[kb], bhf, acc, 0, 0, 0);
    }
    const int h = ct >> 1;
    const float asv = av[h*32 + (ct&1)*16 + lr];
    const float adv = dv[h*32 + (ct&1)*16 + lr];
    #pragma unroll
    for (int j = 0; j < 4; j++){
      esp[j][h] = fmaf(acc[j], asv, esp[j][h]);
      edp[j][h] = fmaf(acc[j], adv, edp[j][h]);
      int r = crowb + j;
      if (r < N) H[(size_t)r*128 + ct*16 + lr] = (_Float16)acc[j];
    }
  }
  #pragma unroll
  for (int o = 1; o < 16; o <<= 1){
    #pragma unroll
    for (int j=0;j<4;j++)
      #pragma unroll
      for (int h=0;h<4;h++){
        esp[j][h] += __shfl_xor(esp[j][h], o);
        edp[j][h] += __shfl_xor(edp[j][h], o);
      }
  }
  const int jj = lr >> 2, hh = lr & 3;
  float eo = 0.f, dd = 0.f;
  #pragma unroll
  for (int j=0;j<4;j++)
    #pragma unroll
    for (int h=0;h<4;h++){
      bool m = (jj==j) & (hh==h);
      eo = m ? esp[j][h] : eo;
      dd = m ? edp[j][h] : dd;
    }
  const int rw = crowb + jj;
  if (rw < N){
    esrc[rw*4 + hh] = eo;
    edst[rw*4 + hh] = dd;
  }
}

// ---------- CSR build v2: bucketed two-level scatter ----------
// level 1: bin edges by dst>>8 with LDS-aggregated space reservation
__global__ __launch_bounds__(256) void bin_scatter(const int* __restrict__ ei,
    int* __restrict__ btail, int2* __restrict__ bkt){
  __shared__ int cnt[NBK];
  __shared__ int base[NBK];
  const int t = threadIdx.x;
  for (int i = t; i < NBK; i += 256) cnt[i] = 0;
  __syncthreads();
  int sv[8], dv[8], bv[8], lr[8];
  const int e0 = blockIdx.x*2048;
  #pragma unroll
  for (int k = 0; k < 8; k++){
    int i = e0 + k*256 + t;
    sv[k] = -1;
    if (i < ET_){
      int s, d;
      if (i < EE){ s = ei[i]; d = ei[EE + i]; } else { s = i - EE; d = s; }
      sv[k] = s; dv[k] = d; bv[k] = d >> 8;
      lr[k] = atomicAdd(&cnt[bv[k]], 1);
    }
  }
  __syncthreads();
  for (int i = t; i < NBK; i += 256){
    int c = cnt[i];
    base[i] = c ? atomicAdd(&btail[i], c) : 0;
  }
  __syncthreads();
  #pragma unroll
  for (int k = 0; k < 8; k++){
    if (sv[k] >= 0){
      int p = base[bv[k]] + lr[k];
      if (p < BCAP) bkt[bv[k]*BCAP + p] = make_int2(sv[k], dv[k]);
    }
  }
}

// level 2a: per-bucket node histogram (no global atomics)
__global__ __launch_bounds__(256) void bucket_count(const int* __restrict__ btail,
    const int2* __restrict__ bkt, int* __restrict__ cnt){
  __shared__ int c256[256];
  const int b = blockIdx.x, t = threadIdx.x;
  c256[t] = 0; __syncthreads();
  int n = btail[b]; if (n > BCAP) n = BCAP;
  for (int i = t; i < n; i += 256){
    int d = bkt[b*BCAP + i].y;
    atomicAdd(&c256[d & 255], 1);
  }
  __syncthreads();
  int node = b*256 + t;
  if (node < NN) cnt[node] = c256[t];
}

// ---------- CSR scan (3-phase) ----------
__global__ __launch_bounds__(256) void scan_partial(const int* __restrict__ cnt,
    int* __restrict__ rowptr, int* __restrict__ bsum){
  __shared__ int sh[256];
  const int t = threadIdx.x;
  const int i = blockIdx.x*256 + t;
  int v = (i < NN) ? cnt[i] : 0;
  sh[t] = v; __syncthreads();
  for (int o=1;o<256;o<<=1){
    int u = (t>=o) ? sh[t-o] : 0;
    __syncthreads();
    sh[t] += u;
    __syncthreads();
  }
  if (i < NN) rowptr[i] = sh[t] - v;
  if (t == 255) bsum[blockIdx.x] = sh[255];
}

__global__ __launch_bounds__(256) void scan_bsum(int* __restrict__ bsum){
  __shared__ int sh[256];
  const int t = threadIdx.x;
  int v = (t < NB) ? bsum[t] : 0;
  sh[t] = v; __syncthreads();
  for (int o=1;o<256;o<<=1){
    int u = (t>=o) ? sh[t-o] : 0;
    __syncthreads();
    sh[t] += u;
    __syncthreads();
  }
  if (t < NB) bsum[t] = sh[t] - v;
}

__global__ __launch_bounds__(256) void scan_add(int* __restrict__ rowptr,
    const int* __restrict__ bsum){
  const int i = blockIdx.x*256 + threadIdx.x;
  if (i < NN) rowptr[i] += bsum[blockIdx.x];
  if (i == NN) rowptr[NN] = ET_;
}

// level 2b: per-bucket scatter into contiguous CSR span
__global__ __launch_bounds__(256) void bucket_scatter(const int* __restrict__ btail,
    const int2* __restrict__ bkt, const int* __restrict__ rowptr,
    int* __restrict__ csr_src){
  __shared__ int h256[256];
  const int b = blockIdx.x, t = threadIdx.x;
  int node = b*256 + t;
  h256[t] = (node < NN) ? rowptr[node] : 0;
  __syncthreads();
  int n = btail[b]; if (n > BCAP) n = BCAP;
  for (int i = t; i < n; i += 256){
    int2 e = bkt[b*BCAP + i];
    int pos = atomicAdd(&h256[e.y & 255], 1);
    csr_src[pos] = e.x;
  }
}

// ---------- fused GAT aggregate: one wave per destination node, f16 gather ----------
__global__ __launch_bounds__(256) void gat_fused(const int* __restrict__ rowptr,
    const int* __restrict__ csr_src, const float* __restrict__ esrc,
    const float* __restrict__ edst, const _Float16* __restrict__ hbuf,
    const float* __restrict__ bias, const int* __restrict__ ntype,
    float* __restrict__ y){
  __shared__ int2 pk[4][64][4];   // (src, wt) replicated per head; 8 KB
  const int w    = threadIdx.x >> 6;
  const int lane = threadIdx.x & 63;
  const int wid  = blockIdx.x*4 + w;
  if (wid >= NN) return;
  const int d = wid;
  const int beg = rowptr[d], end = rowptr[d+1];
  const float4 ed4 = *(const float4*)(edst + (size_t)d*4);

  const int c4   = (lane & 31) * 4;
  const int eh   = lane >> 5;
  const int head = (lane & 31) >> 3;

  float dn0=0.f, dn1=0.f, dn2=0.f, dn3=0.f;
  float4 acc0 = make_float4(0.f,0.f,0.f,0.f);
  float4 acc1 = make_float4(0.f,0.f,0.f,0.f);

  const int2* pp = &pk[w][eh][head];   // advance 8 int2 per pair

  for (int j0 = beg; j0 < end; j0 += 64){
    int j = j0 + lane;
    int s = d;
    float ex0=0.f, ex1=0.f, ex2=0.f, ex3=0.f;
    if (j < end){
      s = csr_src[j];
      float4 es = *(const float4*)(esrc + (size_t)s*4);
      float e0 = es.x + ed4.x; e0 = (e0 > 0.f) ? e0 : 0.2f*e0;
      float e1 = es.y + ed4.y; e1 = (e1 > 0.f) ? e1 : 0.2f*e1;
      float e2 = es.z + ed4.z; e2 = (e2 > 0.f) ? e2 : 0.2f*e2;
      float e3 = es.w + ed4.w; e3 = (e3 > 0.f) ? e3 : 0.2f*e3;
      ex0 = expf(e0); ex1 = expf(e1); ex2 = expf(e2); ex3 = expf(e3);
      dn0 += ex0; dn1 += ex1; dn2 += ex2; dn3 += ex3;
    }
    int4 w0 = make_int4(s, __float_as_int(ex0), s, __float_as_int(ex1));
    int4 w1 = make_int4(s, __float_as_int(ex2), s, __float_as_int(ex3));
    *(int4*)&pk[w][lane][0] = w0;
    *(int4*)&pk[w][lane][2] = w1;
    int cnt2 = end - j0; if (cnt2 > 64) cnt2 = 64;
    const int npair = (cnt2 + 1) >> 1;
    int p = 0;
    #pragma unroll 2
    for (; p + 2 <= npair; p += 2){
      int2 va = pp[p*8];
      int2 vb = pp[p*8 + 8];
      float wa = __int_as_float(va.y);
      float wb = __int_as_float(vb.y);
      h16x4 ha = *(const h16x4*)(hbuf + (size_t)va.x*128 + c4);
      h16x4 hb = *(const h16x4*)(hbuf + (size_t)vb.x*128 + c4);
      acc0.x = fmaf((float)ha.x, wa, acc0.x);
      acc0.y = fmaf((float)ha.y, wa, acc0.y);
      acc0.z = fmaf((float)ha.z, wa, acc0.z);
      acc0.w = fmaf((float)ha.w, wa, acc0.w);
      acc1.x = fmaf((float)hb.x, wb, acc1.x);
      acc1.y = fmaf((float)hb.y, wb, acc1.y);
      acc1.z = fmaf((float)hb.z, wb, acc1.z);
      acc1.w = fmaf((float)hb.w, wb, acc1.w);
    }
    if (p < npair){
      int2 va = pp[p*8];
      float wa = __int_as_float(va.y);
      h16x4 ha = *(const h16x4*)(hbuf + (size_t)va.x*128 + c4);
      acc0.x = fmaf((float)ha.x, wa, acc0.x);
      acc0.y = fmaf((float)ha.y, wa, acc0.y);
      acc0.z = fmaf((float)ha.z, wa, acc0.z);
      acc0.w = fmaf((float)ha.w, wa, acc0.w);
    }
  }
  #pragma unroll
  for (int o = 32; o; o >>= 1){
    dn0 += __shfl_xor(dn0, o);
    dn1 += __shfl_xor(dn1, o);
    dn2 += __shfl_xor(dn2, o);
    dn3 += __shfl_xor(dn3, o);
  }
  float dsel = (head==0) ? dn0 : (head==1) ? dn1 : (head==2) ? dn2 : dn3;
  float inv = 1.f / (dsel + 1e-16f);
  float4 acc;
  acc.x = acc0.x + acc1.x;
  acc.y = acc0.y + acc1.y;
  acc.z = acc0.z + acc1.z;
  acc.w = acc0.w + acc1.w;
  acc.x += __shfl_xor(acc.x, 32);
  acc.y += __shfl_xor(acc.y, 32);
  acc.z += __shfl_xor(acc.z, 32);
  acc.w += __shfl_xor(acc.w, 32);
  if (eh == 0){
    float aw = (ntype[d] == 0) ? 1.5f : 1.0f;
    float4 bb = *(const float4*)(bias + c4);
    float4 o4;
    o4.x = (acc.x*inv + bb.x) * aw;
    o4.y = (acc.y*inv + bb.y) * aw;
    o4.z = (acc.z*inv + bb.z) * aw;
    o4.w = (acc.w*inv + bb.w) * aw;
    *(float4*)(y + (size_t)d*128 + c4) = o4;
  }
}

// ---------- BN stats (read-only) ----------
__global__ __launch_bounds__(256) void epi_stats(const float* __restrict__ y,
    double* __restrict__ bnsum, double* __restrict__ bnsumsq, int N){
  __shared__ float red[256][8];
  const int t = threadIdx.x;
  const int c4 = (t & 31) * 4;
  const int rowInBlk = t >> 5;
  const int stride = gridDim.x * 8;
  float s0=0,s1=0,s2=0,s3=0,q0=0,q1=0,q2=0,q3=0;
  for (int n = blockIdx.x*8 + rowInBlk; n < N; n += stride){
    float4 v = *(const float4*)(y + (size_t)n*128 + c4);
    s0+=v.x; s1+=v.y; s2+=v.z; s3+=v.w;
    q0+=v.x*v.x; q1+=v.y*v.y; q2+=v.z*v.z; q3+=v.w*v.w;
  }
  red[t][0]=s0; red[t][1]=s1; red[t][2]=s2; red[t][3]=s3;
  red[t][4]=q0; red[t][5]=q1; red[t][6]=q2; red[t][7]=q3;
  __syncthreads();
  if (t < 32){
    float a[8] = {0,0,0,0,0,0,0,0};
    for (int j=0;j<8;j++){
      #pragma unroll
      for (int k2=0;k2<8;k2++) a[k2] += red[j*32+t][k2];
    }
    atomicAdd(bnsum   + t*4+0, (double)a[0]);
    atomicAdd(bnsum   + t*4+1, (double)a[1]);
    atomicAdd(bnsum   + t*4+2, (double)a[2]);
    atomicAdd(bnsum   + t*4+3, (double)a[3]);
    atomicAdd(bnsumsq + t*4+0, (double)a[4]);
    atomicAdd(bnsumsq + t*4+1, (double)a[5]);
    atomicAdd(bnsumsq + t*4+2, (double)a[6]);
    atomicAdd(bnsumsq + t*4+3, (double)a[7]);
  }
}

// ---------- BN finalize ----------
__global__ void bn_final(const double* __restrict__ bnsum, const double* __restrict__ bnsumsq,
    const float* __restrict__ gma, const float* __restrict__ bta,
    float* __restrict__ scale, float* __restrict__ shift, int N){
  int c = threadIdx.x;
  double mu  = bnsum[c] / N;
  double var = bnsumsq[c] / N - mu*mu;
  if (var < 0.0) var = 0.0;
  float inv = (float)(1.0 / sqrt(var + 1e-5));
  float sc  = inv * gma[c];
  scale[c] = sc;
  shift[c] = bta[c] - (float)mu * sc;
}

// ---------- pool phase 1 ----------
__global__ __launch_bounds__(256) void pool_partial(const float* __restrict__ y,
    const int* __restrict__ batch, const float* __restrict__ scale,
    const float* __restrict__ shift, float* __restrict__ pooled){
  const int t = threadIdx.x;
  const int c = t & 127;
  const int sub = t >> 7;
  const int per = (NN + PB - 1) / PB;
  const int n0 = blockIdx.x * per;
  int n1 = n0 + per; if (n1 > NN) n1 = NN;
  const float sc = scale[c], sh = shift[c];
  float acc = 0.f;
  int curg = -1;
  for (int n = n0 + sub; n < n1; n += 2){
    int g = batch[n];
    if (g != curg){
      if (curg >= 0) unsafeAtomicAdd(pooled + (size_t)curg*128 + c, acc);
      curg = g; acc = 0.f;
    }
    float v = y[(size_t)n*128 + c];
    acc += fmaxf(fmaf(v, sc, sh), 0.f);
  }
  if (curg >= 0) unsafeAtomicAdd(pooled + (size_t)curg*128 + c, acc);
}

// ---------- pool phase 2: mean + MLP head ----------
__global__ __launch_bounds__(128) void mlp_head(const float* __restrict__ pooled,
    const int* __restrict__ batch, const float* __restrict__ fc1w,
    const float* __restrict__ fc1b, const float* __restrict__ fc2w,
    const float* __restrict__ fc2b, float* __restrict__ out){
  __shared__ float psh[128];
  __shared__ float hid[32];
  const int g = blockIdx.x, t = threadIdx.x;
  int lo = 0, hi = NN;
  while (lo < hi){ int mid = (lo+hi)>>1; if (batch[mid] < g) lo = mid+1; else hi = mid; }
  const int beg = lo;
  lo = beg; hi = NN;
  while (lo < hi){ int mid = (lo+hi)>>1; if (batch[mid] < g+1) lo = mid+1; else hi = mid; }
  int cntn = lo - beg; if (cntn < 1) cntn = 1;
  psh[t] = pooled[(size_t)g*128 + t] / (float)cntn;
  __syncthreads();
  if (t < 32){
    float a = fc1b[t];
    for (int k=0;k<128;k++) a += psh[k]*fc1w[k*32+t];
    a = (a > 0.f) ? a : 0.f;
    hid[t] = a * fc2w[t];
  }
  __syncthreads();
  if (t == 0){
    float sacc = fc2b[0];
    #pragma unroll
    for (int j=0;j<32;j++) sacc += hid[j];
    out[g] = sacc;
  }
}

extern "C" void kernel_launch(void* const* d_in, const int* in_sizes, int n_in,
                              void* d_out, int out_size, void* d_ws, size_t ws_size,
                              hipStream_t stream){
  const float* x     = (const float*)d_in[0];
  const int*   ei    = (const int*)d_in[1];
  const int*   ntype = (const int*)d_in[2];
  const int*   batch = (const int*)d_in[3];
  const float* Wl[3]  = {(const float*)d_in[4],  (const float*)d_in[10], (const float*)d_in[16]};
  const float* asl[3] = {(const float*)d_in[5],  (const float*)d_in[11], (const float*)d_in[17]};
  const float* adl[3] = {(const float*)d_in[6],  (const float*)d_in[12], (const float*)d_in[18]};
  const float* bl[3]  = {(const float*)d_in[7],  (const float*)d_in[13], (const float*)d_in[19]};
  const float* gl[3]  = {(const float*)d_in[8],  (const float*)d_in[14], (const float*)d_in[20]};
  const float* bel[3] = {(const float*)d_in[9],  (const float*)d_in[15], (const float*)d_in[21]};
  const float* fc1w = (const float*)d_in[22];
  const float* fc1b = (const float*)d_in[23];
  const float* fc2w = (const float*)d_in[24];
  const float* fc2b = (const float*)d_in[25];

  char* base = (char*)d_ws;
  size_t off = 0;
  auto alloc = [&](size_t bytes)->char*{
    size_t o = (off + 255) & ~(size_t)255; off = o + bytes; return base + o;
  };
  _Float16* hbuf = (_Float16*)alloc((size_t)NN*128*2);
  float* y       = (float*)alloc((size_t)NN*128*4);
  ushort* wfrag  = (ushort*)alloc((size_t)32768*2);
  float* esrc    = (float*)alloc((size_t)NN*4*4);
  float* edst    = (float*)alloc((size_t)NN*4*4);
  int*   cnt     = (int*)  alloc((size_t)NN*4);
  int*   rowptr  = (int*)  alloc((size_t)(NN+1)*4);
  int*   csr_src = (int*)  alloc((size_t)ET_*4);
  int*   btail   = (int*)  alloc((size_t)NBK*4);
  int2*  bkt     = (int2*) alloc((size_t)NBK*BCAP*8);
  int*   bsum    = (int*)  alloc((size_t)NB*4);
  double* bnsum  = (double*)alloc(128*8);
  double* bnsumsq= (double*)alloc(128*8);
  float* scale   = (float*)alloc(128*4);
  float* shift   = (float*)alloc(128*4);
  float* pooled  = (float*)alloc((size_t)NG*128*4);
  if (off > ws_size) return;

  // ---- CSR build v2 (once; reused by all 3 layers) ----
  hipMemsetAsync(btail, 0, (size_t)NBK*4, stream);
  hipMemsetAsync(pooled, 0, (size_t)NG*128*4, stream);
  bin_scatter<<<(ET_+2047)/2048, 256, 0, stream>>>(ei, btail, bkt);
  bucket_count<<<NBK, 256, 0, stream>>>(btail, bkt, cnt);
  scan_partial<<<NB, 256, 0, stream>>>(cnt, rowptr, bsum);
  scan_bsum<<<1, 256, 0, stream>>>(bsum);
  scan_add<<<NB, 256, 0, stream>>>(rowptr, bsum);
  bucket_scatter<<<NBK, 256, 0, stream>>>(btail, bkt, rowptr, csr_src);

  for (int l = 0; l < 3; l++){
    const float* in = (l==0) ? x : y;
    const float* scl = (l==0) ? nullptr : scale;
    const float* shf = (l==0) ? nullptr : shift;
    hipMemsetAsync(bnsum, 0, 128*8*2, stream);
    convw<<<64, 256, 0, stream>>>(Wl[l], wfrag);
    gemm_fused<<<GB, 512, 0, stream>>>(in, wfrag, scl, shf, asl[l], adl[l],
                                       hbuf, esrc, edst, NN);
    gat_fused<<<(NN+3)/4, 256, 0, stream>>>(rowptr, csr_src, esrc, edst, hbuf, bl[l], ntype, y);
    epi_stats<<<256, 256, 0, stream>>>(y, bnsum, bnsumsq, NN);
    bn_final<<<1, 128, 0, stream>>>(bnsum, bnsumsq, gl[l], bel[l], scale, shift, NN);
  }
  pool_partial<<<PB, 256, 0, stream>>>(y, batch, scale, shift, pooled);
  mlp_head<<<NG, 128, 0, stream>>>(pooled, batch, fc1w, fc1b, fc2w, fc2b, (float*)d_out);
}

// Round 11
// 435.156 us; speedup vs baseline: 6.5472x; 1.0172x over previous
//
#include <hip/hip_runtime.h>
#include <hip/hip_bf16.h>
#include <math.h>

#define NN 50000
#define EE 800000
#define ET_ 850000
#define NG 64
#define NB 196    // ceil(NN/256)
#define PB 1024   // pool blocks
#define GB 391    // ceil(NN/128) gemm blocks
#define NBK 196   // buckets (dst>>8)
#define BCAP 5120 // bucket capacity
#define GATB 2048 // gat blocks (grid-stride)

typedef __attribute__((ext_vector_type(8))) short bf16x8;
typedef __attribute__((ext_vector_type(4))) float f32x4;
typedef __attribute__((ext_vector_type(4))) _Float16 h16x4;

// ---- split f32 -> bf16 hi + bf16 lo (RNE both) ----
__device__ __forceinline__ void bsplit(float v, ushort& h, ushort& l){
  unsigned u = __float_as_uint(v);
  unsigned hb = (u + 0x7fffu + ((u >> 16) & 1u)) >> 16;
  h = (ushort)hb;
  float hf = __uint_as_float(hb << 16);
  float r = v - hf;
  unsigned ur = __float_as_uint(r);
  l = (ushort)((ur + 0x7fffu + ((ur >> 16) & 1u)) >> 16);
}

// ---------- convert W -> fragment-packed W^T bf16 hi/lo ----------
__global__ __launch_bounds__(256) void convw(const float* __restrict__ W,
    ushort* __restrict__ wfrag){
  int idx = blockIdx.x*256 + threadIdx.x;   // idx = k*128 + c
  if (idx >= 128*128) return;
  int c = idx & 127, k = idx >> 7;
  float v = W[idx];
  ushort h, lo;
  bsplit(v, h, lo);
  int dest = (((c>>4)*4 + (k>>5))*64 + (((k&31)>>3)<<4 | (c&15)))*8 + (k&7);
  wfrag[dest] = h;
  wfrag[16384 + dest] = lo;
}

// ---------- ea = W @ [a_src | a_dst] packed as B-fragments for the extra ct-tile ----------
// eafrag[(kb*64+l)*8+j] (hi), +2048 (lo): B[k][col], k=kb*32+(l>>4)*8+j, col=l&15
__global__ __launch_bounds__(256) void convea(const float* __restrict__ W,
    const float* __restrict__ as_, const float* __restrict__ ad_,
    ushort* __restrict__ eafrag){
  const int t = threadIdx.x;
  const int kb = t >> 6, l = t & 63;
  const int col = l & 15, krow = (l >> 4) * 8;
  #pragma unroll
  for (int j = 0; j < 8; j++){
    int k = kb*32 + krow + j;
    float v = 0.f;
    if (col < 8){
      int h = col & 3;
      const float* a  = (col < 4) ? (as_ + h*32) : (ad_ + h*32);
      const float* wr = W + (size_t)k*128 + h*32;
      float acc = 0.f;
      #pragma unroll
      for (int c = 0; c < 32; c++) acc += wr[c]*a[c];
      v = acc;
    }
    ushort hi, lo;
    bsplit(v, hi, lo);
    eafrag[(kb*64 + l)*8 + j] = hi;
    eafrag[2048 + (kb*64 + l)*8 + j] = lo;
  }
}

// ---------- fused: [BN+ReLU] -> split-bf16 MFMA GEMM -> H(f16) + logits via MFMA ----------
__global__ __launch_bounds__(512) void gemm_fused(const float* __restrict__ X,
    const ushort* __restrict__ wfrag, const ushort* __restrict__ eafrag,
    const float* __restrict__ scale, const float* __restrict__ shift,
    _Float16* __restrict__ H, float* __restrict__ esrc, float* __restrict__ edst, int N){
  __shared__ ushort wl[32768];   // 64 KB: hi [0..16383], lo [16384..]
  const int tid = threadIdx.x;
  #pragma unroll
  for (int i = 0; i < 8; i++){
    int e = (i*512 + tid) * 8;
    *(bf16x8*)(wl + e) = *(const bf16x8*)(wfrag + e);
  }
  const int w  = tid >> 6;
  const int l  = tid & 63;
  const int lr = l & 15;
  const int lg = l >> 4;
  const int lk = lg * 8;
  const int arow = blockIdx.x*128 + w*16 + lr;
  const bool avl = (arow < N);
  const size_t abase = (size_t)(avl ? arow : 0) * 128;
  bf16x8 ahi[4], alo[4];
  #pragma unroll
  for (int kb = 0; kb < 4; kb++){
    float a[8];
    if (avl){
      *(float4*)(a)   = *(const float4*)(X + abase + kb*32 + lk);
      *(float4*)(a+4) = *(const float4*)(X + abase + kb*32 + lk + 4);
    } else {
      #pragma unroll
      for (int j=0;j<8;j++) a[j] = 0.f;
    }
    if (scale){
      float s[8], b[8];
      *(float4*)(s)   = *(const float4*)(scale + kb*32 + lk);
      *(float4*)(s+4) = *(const float4*)(scale + kb*32 + lk + 4);
      *(float4*)(b)   = *(const float4*)(shift + kb*32 + lk);
      *(float4*)(b+4) = *(const float4*)(shift + kb*32 + lk + 4);
      #pragma unroll
      for (int j=0;j<8;j++) a[j] = fmaxf(fmaf(a[j], s[j], b[j]), 0.f);
    }
    #pragma unroll
    for (int j=0;j<8;j++){
      ushort hh2, ll2;
      bsplit(a[j], hh2, ll2);
      ahi[kb][j] = (short)hh2;
      alo[kb][j] = (short)ll2;
    }
  }
  __syncthreads();
  const int crowb = blockIdx.x*128 + w*16 + lg*4;
  #pragma unroll
  for (int ct = 0; ct < 8; ct++){
    f32x4 acc = {0.f,0.f,0.f,0.f};
    #pragma unroll
    for (int kb = 0; kb < 4; kb++){
      const int fi = ((ct*4 + kb)*64 + l) * 8;
      bf16x8 bhf = *(const bf16x8*)(wl + fi);
      bf16x8 blf = *(const bf16x8*)(wl + 16384 + fi);
      acc = __builtin_amdgcn_mfma_f32_16x16x32_bf16(ahi[kb], bhf, acc, 0, 0, 0);
      acc = __builtin_amdgcn_mfma_f32_16x16x32_bf16(ahi[kb], blf, acc, 0, 0, 0);
      acc = __builtin_amdgcn_mfma_f32_16x16x32_bf16(alo[kb], bhf, acc, 0, 0, 0);
    }
    #pragma unroll
    for (int j = 0; j < 4; j++){
      int r = crowb + j;
      if (r < N) H[(size_t)r*128 + ct*16 + lr] = (_Float16)acc[j];
    }
  }
  // extra ct-tile: logits e = X @ (W a)
  {
    f32x4 acc = {0.f,0.f,0.f,0.f};
    #pragma unroll
    for (int kb = 0; kb < 4; kb++){
      bf16x8 bhf = *(const bf16x8*)(eafrag + (kb*64 + l)*8);
      bf16x8 blf = *(const bf16x8*)(eafrag + 2048 + (kb*64 + l)*8);
      acc = __builtin_amdgcn_mfma_f32_16x16x32_bf16(ahi[kb], bhf, acc, 0, 0, 0);
      acc = __builtin_amdgcn_mfma_f32_16x16x32_bf16(ahi[kb], blf, acc, 0, 0, 0);
      acc = __builtin_amdgcn_mfma_f32_16x16x32_bf16(alo[kb], bhf, acc, 0, 0, 0);
    }
    if (lr < 8){
      #pragma unroll
      for (int j = 0; j < 4; j++){
        int r = crowb + j;
        if (r < N){
          if (lr < 4) esrc[r*4 + lr] = acc[j];
          else        edst[r*4 + lr - 4] = acc[j];
        }
      }
    }
  }
}

// ---------- CSR build v2: bucketed two-level scatter ----------
__global__ __launch_bounds__(256) void bin_scatter(const int* __restrict__ ei,
    int* __restrict__ btail, int2* __restrict__ bkt){
  __shared__ int cnt[NBK];
  __shared__ int base[NBK];
  const int t = threadIdx.x;
  for (int i = t; i < NBK; i += 256) cnt[i] = 0;
  __syncthreads();
  int sv[8], dv[8], bv[8], lr[8];
  const int e0 = blockIdx.x*2048;
  #pragma unroll
  for (int k = 0; k < 8; k++){
    int i = e0 + k*256 + t;
    sv[k] = -1;
    if (i < ET_){
      int s, d;
      if (i < EE){ s = ei[i]; d = ei[EE + i]; } else { s = i - EE; d = s; }
      sv[k] = s; dv[k] = d; bv[k] = d >> 8;
      lr[k] = atomicAdd(&cnt[bv[k]], 1);
    }
  }
  __syncthreads();
  for (int i = t; i < NBK; i += 256){
    int c = cnt[i];
    base[i] = c ? atomicAdd(&btail[i], c) : 0;
  }
  __syncthreads();
  #pragma unroll
  for (int k = 0; k < 8; k++){
    if (sv[k] >= 0){
      int p = base[bv[k]] + lr[k];
      if (p < BCAP) bkt[bv[k]*BCAP + p] = make_int2(sv[k], dv[k]);
    }
  }
}

__global__ __launch_bounds__(256) void bucket_count(const int* __restrict__ btail,
    const int2* __restrict__ bkt, int* __restrict__ cnt){
  __shared__ int c256[256];
  const int b = blockIdx.x, t = threadIdx.x;
  c256[t] = 0; __syncthreads();
  int n = btail[b]; if (n > BCAP) n = BCAP;
  for (int i = t; i < n; i += 256){
    int d = bkt[b*BCAP + i].y;
    atomicAdd(&c256[d & 255], 1);
  }
  __syncthreads();
  int node = b*256 + t;
  if (node < NN) cnt[node] = c256[t];
}

__global__ __launch_bounds__(256) void scan_partial(const int* __restrict__ cnt,
    int* __restrict__ rowptr, int* __restrict__ bsum){
  __shared__ int sh[256];
  const int t = threadIdx.x;
  const int i = blockIdx.x*256 + t;
  int v = (i < NN) ? cnt[i] : 0;
  sh[t] = v; __syncthreads();
  for (int o=1;o<256;o<<=1){
    int u = (t>=o) ? sh[t-o] : 0;
    __syncthreads();
    sh[t] += u;
    __syncthreads();
  }
  if (i < NN) rowptr[i] = sh[t] - v;
  if (t == 255) bsum[blockIdx.x] = sh[255];
}

__global__ __launch_bounds__(256) void scan_bsum(int* __restrict__ bsum){
  __shared__ int sh[256];
  const int t = threadIdx.x;
  int v = (t < NB) ? bsum[t] : 0;
  sh[t] = v; __syncthreads();
  for (int o=1;o<256;o<<=1){
    int u = (t>=o) ? sh[t-o] : 0;
    __syncthreads();
    sh[t] += u;
    __syncthreads();
  }
  if (t < NB) bsum[t] = sh[t] - v;
}

__global__ __launch_bounds__(256) void scan_add(int* __restrict__ rowptr,
    const int* __restrict__ bsum){
  const int i = blockIdx.x*256 + threadIdx.x;
  if (i < NN) rowptr[i] += bsum[blockIdx.x];
  if (i == NN) rowptr[NN] = ET_;
}

__global__ __launch_bounds__(256) void bucket_scatter(const int* __restrict__ btail,
    const int2* __restrict__ bkt, const int* __restrict__ rowptr,
    int* __restrict__ csr_src){
  __shared__ int h256[256];
  const int b = blockIdx.x, t = threadIdx.x;
  int node = b*256 + t;
  h256[t] = (node < NN) ? rowptr[node] : 0;
  __syncthreads();
  int n = btail[b]; if (n > BCAP) n = BCAP;
  for (int i = t; i < n; i += 256){
    int2 e = bkt[b*BCAP + i];
    int pos = atomicAdd(&h256[e.y & 255], 1);
    csr_src[pos] = e.x;
  }
}

// ---------- fused GAT aggregate (grid-stride) + BN-stat partials ----------
__global__ __launch_bounds__(256) void gat_fused(const int* __restrict__ rowptr,
    const int* __restrict__ csr_src, const float* __restrict__ esrc,
    const float* __restrict__ edst, const _Float16* __restrict__ hbuf,
    const float* __restrict__ bias, const int* __restrict__ ntype,
    float* __restrict__ y, float* __restrict__ bnpart){
  __shared__ int2 pk[4][64][4];   // (src, wt) replicated per head; 8 KB
  const int w    = threadIdx.x >> 6;
  const int lane = threadIdx.x & 63;
  const int c4   = (lane & 31) * 4;
  const int eh   = lane >> 5;
  const int head = (lane & 31) >> 3;
  const int2* pp = &pk[w][eh][head];

  float bs0=0.f,bs1=0.f,bs2=0.f,bs3=0.f,bq0=0.f,bq1=0.f,bq2=0.f,bq3=0.f;
  const float4 bb = *(const float4*)(bias + c4);

  for (int d = blockIdx.x*4 + w; d < NN; d += GATB*4){
    const int beg = rowptr[d], end = rowptr[d+1];
    const float4 ed4 = *(const float4*)(edst + (size_t)d*4);
    float dn0=0.f, dn1=0.f, dn2=0.f, dn3=0.f;
    float4 acc0 = make_float4(0.f,0.f,0.f,0.f);
    float4 acc1 = make_float4(0.f,0.f,0.f,0.f);

    for (int j0 = beg; j0 < end; j0 += 64){
      int j = j0 + lane;
      int s = d;
      float ex0=0.f, ex1=0.f, ex2=0.f, ex3=0.f;
      if (j < end){
        s = csr_src[j];
        float4 es = *(const float4*)(esrc + (size_t)s*4);
        float e0 = es.x + ed4.x; e0 = (e0 > 0.f) ? e0 : 0.2f*e0;
        float e1 = es.y + ed4.y; e1 = (e1 > 0.f) ? e1 : 0.2f*e1;
        float e2 = es.z + ed4.z; e2 = (e2 > 0.f) ? e2 : 0.2f*e2;
        float e3 = es.w + ed4.w; e3 = (e3 > 0.f) ? e3 : 0.2f*e3;
        ex0 = expf(e0); ex1 = expf(e1); ex2 = expf(e2); ex3 = expf(e3);
        dn0 += ex0; dn1 += ex1; dn2 += ex2; dn3 += ex3;
      }
      int4 w0 = make_int4(s, __float_as_int(ex0), s, __float_as_int(ex1));
      int4 w1 = make_int4(s, __float_as_int(ex2), s, __float_as_int(ex3));
      *(int4*)&pk[w][lane][0] = w0;
      *(int4*)&pk[w][lane][2] = w1;
      int cnt2 = end - j0; if (cnt2 > 64) cnt2 = 64;
      const int npair = (cnt2 + 1) >> 1;
      int p = 0;
      #pragma unroll 2
      for (; p + 2 <= npair; p += 2){
        int2 va = pp[p*8];
        int2 vb = pp[p*8 + 8];
        float wa = __int_as_float(va.y);
        float wb = __int_as_float(vb.y);
        h16x4 ha = *(const h16x4*)(hbuf + (size_t)va.x*128 + c4);
        h16x4 hb = *(const h16x4*)(hbuf + (size_t)vb.x*128 + c4);
        acc0.x = fmaf((float)ha.x, wa, acc0.x);
        acc0.y = fmaf((float)ha.y, wa, acc0.y);
        acc0.z = fmaf((float)ha.z, wa, acc0.z);
        acc0.w = fmaf((float)ha.w, wa, acc0.w);
        acc1.x = fmaf((float)hb.x, wb, acc1.x);
        acc1.y = fmaf((float)hb.y, wb, acc1.y);
        acc1.z = fmaf((float)hb.z, wb, acc1.z);
        acc1.w = fmaf((float)hb.w, wb, acc1.w);
      }
      if (p < npair){
        int2 va = pp[p*8];
        float wa = __int_as_float(va.y);
        h16x4 ha = *(const h16x4*)(hbuf + (size_t)va.x*128 + c4);
        acc0.x = fmaf((float)ha.x, wa, acc0.x);
        acc0.y = fmaf((float)ha.y, wa, acc0.y);
        acc0.z = fmaf((float)ha.z, wa, acc0.z);
        acc0.w = fmaf((float)ha.w, wa, acc0.w);
      }
    }
    #pragma unroll
    for (int o = 32; o; o >>= 1){
      dn0 += __shfl_xor(dn0, o);
      dn1 += __shfl_xor(dn1, o);
      dn2 += __shfl_xor(dn2, o);
      dn3 += __shfl_xor(dn3, o);
    }
    float dsel = (head==0) ? dn0 : (head==1) ? dn1 : (head==2) ? dn2 : dn3;
    float inv = 1.f / (dsel + 1e-16f);
    float4 acc;
    acc.x = acc0.x + acc1.x;
    acc.y = acc0.y + acc1.y;
    acc.z = acc0.z + acc1.z;
    acc.w = acc0.w + acc1.w;
    acc.x += __shfl_xor(acc.x, 32);
    acc.y += __shfl_xor(acc.y, 32);
    acc.z += __shfl_xor(acc.z, 32);
    acc.w += __shfl_xor(acc.w, 32);
    if (eh == 0){
      float aw = (ntype[d] == 0) ? 1.5f : 1.0f;
      float4 o4;
      o4.x = (acc.x*inv + bb.x) * aw;
      o4.y = (acc.y*inv + bb.y) * aw;
      o4.z = (acc.z*inv + bb.z) * aw;
      o4.w = (acc.w*inv + bb.w) * aw;
      *(float4*)(y + (size_t)d*128 + c4) = o4;
      bs0 += o4.x; bs1 += o4.y; bs2 += o4.z; bs3 += o4.w;
      bq0 += o4.x*o4.x; bq1 += o4.y*o4.y; bq2 += o4.z*o4.z; bq3 += o4.w*o4.w;
    }
  }
  // block-level BN-stat reduce (reuse pk LDS)
  __syncthreads();
  float* bnp = (float*)pk;   // [4][32][8]
  if (eh == 0){
    float* q = bnp + (w*32 + (lane & 31))*8;
    q[0]=bs0; q[1]=bs1; q[2]=bs2; q[3]=bs3;
    q[4]=bq0; q[5]=bq1; q[6]=bq2; q[7]=bq3;
  }
  __syncthreads();
  const int t = threadIdx.x;
  const int c = t & 127, stat = t >> 7;
  float v = 0.f;
  #pragma unroll
  for (int ww = 0; ww < 4; ww++)
    v += bnp[(ww*32 + (c>>2))*8 + stat*4 + (c&3)];
  bnpart[(size_t)blockIdx.x*256 + t] = v;
}

// ---------- BN partial reduce ----------
__global__ __launch_bounds__(256) void bn_reduce(const float* __restrict__ bnpart,
    double* __restrict__ bnsum, double* __restrict__ bnsumsq){
  const int t = threadIdx.x, b = blockIdx.x;   // 64 blocks
  float acc = 0.f;
  #pragma unroll 4
  for (int j = 0; j < GATB/64; j++)
    acc += bnpart[(size_t)(b*(GATB/64) + j)*256 + t];
  const int c = t & 127;
  if (t < 128) atomicAdd(bnsum + c, (double)acc);
  else         atomicAdd(bnsumsq + c, (double)acc);
}

// ---------- BN finalize ----------
__global__ void bn_final(const double* __restrict__ bnsum, const double* __restrict__ bnsumsq,
    const float* __restrict__ gma, const float* __restrict__ bta,
    float* __restrict__ scale, float* __restrict__ shift, int N){
  int c = threadIdx.x;
  double mu  = bnsum[c] / N;
  double var = bnsumsq[c] / N - mu*mu;
  if (var < 0.0) var = 0.0;
  float inv = (float)(1.0 / sqrt(var + 1e-5));
  float sc  = inv * gma[c];
  scale[c] = sc;
  shift[c] = bta[c] - (float)mu * sc;
}

// ---------- pool phase 1 ----------
__global__ __launch_bounds__(256) void pool_partial(const float* __restrict__ y,
    const int* __restrict__ batch, const float* __restrict__ scale,
    const float* __restrict__ shift, float* __restrict__ pooled){
  const int t = threadIdx.x;
  const int c = t & 127;
  const int sub = t >> 7;
  const int per = (NN + PB - 1) / PB;
  const int n0 = blockIdx.x * per;
  int n1 = n0 + per; if (n1 > NN) n1 = NN;
  const float sc = scale[c], sh = shift[c];
  float acc = 0.f;
  int curg = -1;
  for (int n = n0 + sub; n < n1; n += 2){
    int g = batch[n];
    if (g != curg){
      if (curg >= 0) unsafeAtomicAdd(pooled + (size_t)curg*128 + c, acc);
      curg = g; acc = 0.f;
    }
    float v = y[(size_t)n*128 + c];
    acc += fmaxf(fmaf(v, sc, sh), 0.f);
  }
  if (curg >= 0) unsafeAtomicAdd(pooled + (size_t)curg*128 + c, acc);
}

// ---------- pool phase 2: mean + MLP head ----------
__global__ __launch_bounds__(128) void mlp_head(const float* __restrict__ pooled,
    const int* __restrict__ batch, const float* __restrict__ fc1w,
    const float* __restrict__ fc1b, const float* __restrict__ fc2w,
    const float* __restrict__ fc2b, float* __restrict__ out){
  __shared__ float psh[128];
  __shared__ float hid[32];
  const int g = blockIdx.x, t = threadIdx.x;
  int lo = 0, hi = NN;
  while (lo < hi){ int mid = (lo+hi)>>1; if (batch[mid] < g) lo = mid+1; else hi = mid; }
  const int beg = lo;
  lo = beg; hi = NN;
  while (lo < hi){ int mid = (lo+hi)>>1; if (batch[mid] < g+1) lo = mid+1; else hi = mid; }
  int cntn = lo - beg; if (cntn < 1) cntn = 1;
  psh[t] = pooled[(size_t)g*128 + t] / (float)cntn;
  __syncthreads();
  if (t < 32){
    float a = fc1b[t];
    for (int k=0;k<128;k++) a += psh[k]*fc1w[k*32+t];
    a = (a > 0.f) ? a : 0.f;
    hid[t] = a * fc2w[t];
  }
  __syncthreads();
  if (t == 0){
    float sacc = fc2b[0];
    #pragma unroll
    for (int j=0;j<32;j++) sacc += hid[j];
    out[g] = sacc;
  }
}

extern "C" void kernel_launch(void* const* d_in, const int* in_sizes, int n_in,
                              void* d_out, int out_size, void* d_ws, size_t ws_size,
                              hipStream_t stream){
  const float* x     = (const float*)d_in[0];
  const int*   ei    = (const int*)d_in[1];
  const int*   ntype = (const int*)d_in[2];
  const int*   batch = (const int*)d_in[3];
  const float* Wl[3]  = {(const float*)d_in[4],  (const float*)d_in[10], (const float*)d_in[16]};
  const float* asl[3] = {(const float*)d_in[5],  (const float*)d_in[11], (const float*)d_in[17]};
  const float* adl[3] = {(const float*)d_in[6],  (const float*)d_in[12], (const float*)d_in[18]};
  const float* bl[3]  = {(const float*)d_in[7],  (const float*)d_in[13], (const float*)d_in[19]};
  const float* gl[3]  = {(const float*)d_in[8],  (const float*)d_in[14], (const float*)d_in[20]};
  const float* bel[3] = {(const float*)d_in[9],  (const float*)d_in[15], (const float*)d_in[21]};
  const float* fc1w = (const float*)d_in[22];
  const float* fc1b = (const float*)d_in[23];
  const float* fc2w = (const float*)d_in[24];
  const float* fc2b = (const float*)d_in[25];

  char* base = (char*)d_ws;
  size_t off = 0;
  auto alloc = [&](size_t bytes)->char*{
    size_t o = (off + 255) & ~(size_t)255; off = o + bytes; return base + o;
  };
  _Float16* hbuf = (_Float16*)alloc((size_t)NN*128*2);
  float* y       = (float*)alloc((size_t)NN*128*4);
  ushort* wfrag  = (ushort*)alloc((size_t)32768*2);
  ushort* eafrag = (ushort*)alloc((size_t)4096*2);
  float* esrc    = (float*)alloc((size_t)NN*4*4);
  float* edst    = (float*)alloc((size_t)NN*4*4);
  int*   cnt     = (int*)  alloc((size_t)NN*4);
  int*   rowptr  = (int*)  alloc((size_t)(NN+1)*4);
  int*   csr_src = (int*)  alloc((size_t)ET_*4);
  int*   btail   = (int*)  alloc((size_t)NBK*4);
  int2*  bkt     = (int2*) alloc((size_t)NBK*BCAP*8);
  int*   bsum    = (int*)  alloc((size_t)NB*4);
  float* bnpart  = (float*)alloc((size_t)GATB*256*4);
  double* bnsum  = (double*)alloc(128*8);
  double* bnsumsq= (double*)alloc(128*8);
  float* scale   = (float*)alloc(128*4);
  float* shift   = (float*)alloc(128*4);
  float* pooled  = (float*)alloc((size_t)NG*128*4);
  if (off > ws_size) return;

  // ---- CSR build v2 (once; reused by all 3 layers) ----
  hipMemsetAsync(btail, 0, (size_t)NBK*4, stream);
  hipMemsetAsync(pooled, 0, (size_t)NG*128*4, stream);
  bin_scatter<<<(ET_+2047)/2048, 256, 0, stream>>>(ei, btail, bkt);
  bucket_count<<<NBK, 256, 0, stream>>>(btail, bkt, cnt);
  scan_partial<<<NB, 256, 0, stream>>>(cnt, rowptr, bsum);
  scan_bsum<<<1, 256, 0, stream>>>(bsum);
  scan_add<<<NB, 256, 0, stream>>>(rowptr, bsum);
  bucket_scatter<<<NBK, 256, 0, stream>>>(btail, bkt, rowptr, csr_src);

  for (int l = 0; l < 3; l++){
    const float* in = (l==0) ? x : y;
    const float* scl = (l==0) ? nullptr : scale;
    const float* shf = (l==0) ? nullptr : shift;
    hipMemsetAsync(bnsum, 0, 128*8*2, stream);
    convw<<<64, 256, 0, stream>>>(Wl[l], wfrag);
    convea<<<1, 256, 0, stream>>>(Wl[l], asl[l], adl[l], eafrag);
    gemm_fused<<<GB, 512, 0, stream>>>(in, wfrag, eafrag, scl, shf,
                                       hbuf, esrc, edst, NN);
    gat_fused<<<GATB, 256, 0, stream>>>(rowptr, csr_src, esrc, edst, hbuf,
                                        bl[l], ntype, y, bnpart);
    bn_reduce<<<64, 256, 0, stream>>>(bnpart, bnsum, bnsumsq);
    bn_final<<<1, 128, 0, stream>>>(bnsum, bnsumsq, gl[l], bel[l], scale, shift, NN);
  }
  pool_partial<<<PB, 256, 0, stream>>>(y, batch, scale, shift, pooled);
  mlp_head<<<NG, 128, 0, stream>>>(pooled, batch, fc1w, fc1b, fc2w, fc2b, (float*)d_out);
}

// Round 12
// 432.286 us; speedup vs baseline: 6.5907x; 1.0066x over previous
//
#include <hip/hip_runtime.h>
#include <hip/hip_bf16.h>
#include <math.h>

#define NN 50000
#define EE 800000
#define ET_ 850000
#define NG 64
#define NB 196    // ceil(NN/256)
#define PB 1024   // pool blocks
#define GB 391    // ceil(NN/128) gemm blocks
#define NBK 196   // buckets (dst>>8)
#define BCAP 5120 // bucket capacity
#define GATB 6144 // gat blocks (grid-stride, 3x oversubscribed)

typedef __attribute__((ext_vector_type(8))) short bf16x8;
typedef __attribute__((ext_vector_type(4))) float f32x4;
typedef __attribute__((ext_vector_type(8))) _Float16 h16x8;

// ---- split f32 -> bf16 hi + bf16 lo (RNE both) ----
__device__ __forceinline__ void bsplit(float v, ushort& h, ushort& l){
  unsigned u = __float_as_uint(v);
  unsigned hb = (u + 0x7fffu + ((u >> 16) & 1u)) >> 16;
  h = (ushort)hb;
  float hf = __uint_as_float(hb << 16);
  float r = v - hf;
  unsigned ur = __float_as_uint(r);
  l = (ushort)((ur + 0x7fffu + ((ur >> 16) & 1u)) >> 16);
}

// ---------- W -> fragment-packed W^T hi/lo  AND  ea = W@[a_src|a_dst] (block 64) ----------
__global__ __launch_bounds__(256) void convwa(const float* __restrict__ W,
    const float* __restrict__ as_, const float* __restrict__ ad_,
    ushort* __restrict__ wfrag, ushort* __restrict__ eafrag){
  const int t = threadIdx.x;
  if (blockIdx.x < 64){
    int idx = blockIdx.x*256 + t;   // idx = k*128 + c
    int c = idx & 127, k = idx >> 7;
    float v = W[idx];
    ushort h, lo;
    bsplit(v, h, lo);
    int dest = (((c>>4)*4 + (k>>5))*64 + (((k&31)>>3)<<4 | (c&15)))*8 + (k&7);
    wfrag[dest] = h;
    wfrag[16384 + dest] = lo;
  } else {
    const int kb = t >> 6, l = t & 63;
    const int col = l & 15, krow = (l >> 4) * 8;
    #pragma unroll
    for (int j = 0; j < 8; j++){
      int k = kb*32 + krow + j;
      float v = 0.f;
      if (col < 8){
        int h = col & 3;
        const float* a  = (col < 4) ? (as_ + h*32) : (ad_ + h*32);
        const float* wr = W + (size_t)k*128 + h*32;
        float acc = 0.f;
        #pragma unroll
        for (int c = 0; c < 32; c++) acc += wr[c]*a[c];
        v = acc;
      }
      ushort hi, lo;
      bsplit(v, hi, lo);
      eafrag[(kb*64 + l)*8 + j] = hi;
      eafrag[2048 + (kb*64 + l)*8 + j] = lo;
    }
  }
}

// ---------- fused: [BN+ReLU] -> split-bf16 MFMA GEMM -> H(f16) + logits via MFMA ----------
__global__ __launch_bounds__(512) void gemm_fused(const float* __restrict__ X,
    const ushort* __restrict__ wfrag, const ushort* __restrict__ eafrag,
    const float* __restrict__ scale, const float* __restrict__ shift,
    _Float16* __restrict__ H, float* __restrict__ esrc, float* __restrict__ edst, int N){
  __shared__ ushort wl[32768];   // 64 KB: hi [0..16383], lo [16384..]
  const int tid = threadIdx.x;
  #pragma unroll
  for (int i = 0; i < 8; i++){
    int e = (i*512 + tid) * 8;
    *(bf16x8*)(wl + e) = *(const bf16x8*)(wfrag + e);
  }
  const int w  = tid >> 6;
  const int l  = tid & 63;
  const int lr = l & 15;
  const int lg = l >> 4;
  const int lk = lg * 8;
  const int arow = blockIdx.x*128 + w*16 + lr;
  const bool avl = (arow < N);
  const size_t abase = (size_t)(avl ? arow : 0) * 128;
  bf16x8 ahi[4], alo[4];
  #pragma unroll
  for (int kb = 0; kb < 4; kb++){
    float a[8];
    if (avl){
      *(float4*)(a)   = *(const float4*)(X + abase + kb*32 + lk);
      *(float4*)(a+4) = *(const float4*)(X + abase + kb*32 + lk + 4);
    } else {
      #pragma unroll
      for (int j=0;j<8;j++) a[j] = 0.f;
    }
    if (scale){
      float s[8], b[8];
      *(float4*)(s)   = *(const float4*)(scale + kb*32 + lk);
      *(float4*)(s+4) = *(const float4*)(scale + kb*32 + lk + 4);
      *(float4*)(b)   = *(const float4*)(shift + kb*32 + lk);
      *(float4*)(b+4) = *(const float4*)(shift + kb*32 + lk + 4);
      #pragma unroll
      for (int j=0;j<8;j++) a[j] = fmaxf(fmaf(a[j], s[j], b[j]), 0.f);
    }
    #pragma unroll
    for (int j=0;j<8;j++){
      ushort hh2, ll2;
      bsplit(a[j], hh2, ll2);
      ahi[kb][j] = (short)hh2;
      alo[kb][j] = (short)ll2;
    }
  }
  __syncthreads();
  const int crowb = blockIdx.x*128 + w*16 + lg*4;
  #pragma unroll
  for (int ct = 0; ct < 8; ct++){
    f32x4 acc = {0.f,0.f,0.f,0.f};
    #pragma unroll
    for (int kb = 0; kb < 4; kb++){
      const int fi = ((ct*4 + kb)*64 + l) * 8;
      bf16x8 bhf = *(const bf16x8*)(wl + fi);
      bf16x8 blf = *(const bf16x8*)(wl + 16384 + fi);
      acc = __builtin_amdgcn_mfma_f32_16x16x32_bf16(ahi[kb], bhf, acc, 0, 0, 0);
      acc = __builtin_amdgcn_mfma_f32_16x16x32_bf16(ahi[kb], blf, acc, 0, 0, 0);
      acc = __builtin_amdgcn_mfma_f32_16x16x32_bf16(alo[kb], bhf, acc, 0, 0, 0);
    }
    #pragma unroll
    for (int j = 0; j < 4; j++){
      int r = crowb + j;
      if (r < N) H[(size_t)r*128 + ct*16 + lr] = (_Float16)acc[j];
    }
  }
  // extra ct-tile: logits e = X @ (W a)
  {
    f32x4 acc = {0.f,0.f,0.f,0.f};
    #pragma unroll
    for (int kb = 0; kb < 4; kb++){
      bf16x8 bhf = *(const bf16x8*)(eafrag + (kb*64 + l)*8);
      bf16x8 blf = *(const bf16x8*)(eafrag + 2048 + (kb*64 + l)*8);
      acc = __builtin_amdgcn_mfma_f32_16x16x32_bf16(ahi[kb], bhf, acc, 0, 0, 0);
      acc = __builtin_amdgcn_mfma_f32_16x16x32_bf16(ahi[kb], blf, acc, 0, 0, 0);
      acc = __builtin_amdgcn_mfma_f32_16x16x32_bf16(alo[kb], bhf, acc, 0, 0, 0);
    }
    if (lr < 8){
      #pragma unroll
      for (int j = 0; j < 4; j++){
        int r = crowb + j;
        if (r < N){
          if (lr < 4) esrc[r*4 + lr] = acc[j];
          else        edst[r*4 + lr - 4] = acc[j];
        }
      }
    }
  }
}

// ---------- CSR build v2: bucketed two-level scatter ----------
__global__ __launch_bounds__(256) void bin_scatter(const int* __restrict__ ei,
    int* __restrict__ btail, int2* __restrict__ bkt){
  __shared__ int cnt[NBK];
  __shared__ int base[NBK];
  const int t = threadIdx.x;
  for (int i = t; i < NBK; i += 256) cnt[i] = 0;
  __syncthreads();
  int sv[8], dv[8], bv[8], lr[8];
  const int e0 = blockIdx.x*2048;
  #pragma unroll
  for (int k = 0; k < 8; k++){
    int i = e0 + k*256 + t;
    sv[k] = -1;
    if (i < ET_){
      int s, d;
      if (i < EE){ s = ei[i]; d = ei[EE + i]; } else { s = i - EE; d = s; }
      sv[k] = s; dv[k] = d; bv[k] = d >> 8;
      lr[k] = atomicAdd(&cnt[bv[k]], 1);
    }
  }
  __syncthreads();
  for (int i = t; i < NBK; i += 256){
    int c = cnt[i];
    base[i] = c ? atomicAdd(&btail[i], c) : 0;
  }
  __syncthreads();
  #pragma unroll
  for (int k = 0; k < 8; k++){
    if (sv[k] >= 0){
      int p = base[bv[k]] + lr[k];
      if (p < BCAP) bkt[bv[k]*BCAP + p] = make_int2(sv[k], dv[k]);
    }
  }
}

__global__ __launch_bounds__(256) void bucket_count(const int* __restrict__ btail,
    const int2* __restrict__ bkt, int* __restrict__ cnt){
  __shared__ int c256[256];
  const int b = blockIdx.x, t = threadIdx.x;
  c256[t] = 0; __syncthreads();
  int n = btail[b]; if (n > BCAP) n = BCAP;
  for (int i = t; i < n; i += 256){
    int d = bkt[b*BCAP + i].y;
    atomicAdd(&c256[d & 255], 1);
  }
  __syncthreads();
  int node = b*256 + t;
  if (node < NN) cnt[node] = c256[t];
}

__global__ __launch_bounds__(256) void scan_partial(const int* __restrict__ cnt,
    int* __restrict__ rowptr, int* __restrict__ bsum){
  __shared__ int sh[256];
  const int t = threadIdx.x;
  const int i = blockIdx.x*256 + t;
  int v = (i < NN) ? cnt[i] : 0;
  sh[t] = v; __syncthreads();
  for (int o=1;o<256;o<<=1){
    int u = (t>=o) ? sh[t-o] : 0;
    __syncthreads();
    sh[t] += u;
    __syncthreads();
  }
  if (i < NN) rowptr[i] = sh[t] - v;
  if (t == 255) bsum[blockIdx.x] = sh[255];
}

__global__ __launch_bounds__(256) void scan_bsum(int* __restrict__ bsum){
  __shared__ int sh[256];
  const int t = threadIdx.x;
  int v = (t < NB) ? bsum[t] : 0;
  sh[t] = v; __syncthreads();
  for (int o=1;o<256;o<<=1){
    int u = (t>=o) ? sh[t-o] : 0;
    __syncthreads();
    sh[t] += u;
    __syncthreads();
  }
  if (t < NB) bsum[t] = sh[t] - v;
}

__global__ __launch_bounds__(256) void scan_add(int* __restrict__ rowptr,
    const int* __restrict__ bsum){
  const int i = blockIdx.x*256 + threadIdx.x;
  if (i < NN) rowptr[i] += bsum[blockIdx.x];
  if (i == NN) rowptr[NN] = ET_;
}

__global__ __launch_bounds__(256) void bucket_scatter(const int* __restrict__ btail,
    const int2* __restrict__ bkt, const int* __restrict__ rowptr,
    int* __restrict__ csr_src){
  __shared__ int h256[256];
  const int b = blockIdx.x, t = threadIdx.x;
  int node = b*256 + t;
  h256[t] = (node < NN) ? rowptr[node] : 0;
  __syncthreads();
  int n = btail[b]; if (n > BCAP) n = BCAP;
  for (int i = t; i < n; i += 256){
    int2 e = bkt[b*BCAP + i];
    int pos = atomicAdd(&h256[e.y & 255], 1);
    csr_src[pos] = e.x;
  }
}

// ---------- fused GAT aggregate (grid-stride, 4 edges/iter) + BN-stat partials ----------
__global__ __launch_bounds__(256) void gat_fused(const int* __restrict__ rowptr,
    const int* __restrict__ csr_src, const float* __restrict__ esrc,
    const float* __restrict__ edst, const _Float16* __restrict__ hbuf,
    const float* __restrict__ bias, const int* __restrict__ ntype,
    float* __restrict__ y, float* __restrict__ bnpart){
  __shared__ int2 pk[4][64][4];   // (src, wt) replicated per head; 8 KB
  const int w    = threadIdx.x >> 6;
  const int lane = threadIdx.x & 63;
  const int e    = lane >> 4;        // edge-in-group 0..3
  const int c8   = lane & 15;        // channel octet 0..15 (channels c8*8..+7)
  const int hd   = c8 >> 2;          // head of this lane's channels
  const int2* pg = &pk[w][e][hd];    // +16 int2 per 4-edge group

  float bs[8], bq[8];
  #pragma unroll
  for (int k=0;k<8;k++){ bs[k]=0.f; bq[k]=0.f; }
  const float4 bbA = *(const float4*)(bias + c8*8);
  const float4 bbB = *(const float4*)(bias + c8*8 + 4);

  for (int d = blockIdx.x*4 + w; d < NN; d += GATB*4){
    const int beg = rowptr[d], end = rowptr[d+1];
    const float4 ed4 = *(const float4*)(edst + (size_t)d*4);
    float dn0=0.f, dn1=0.f, dn2=0.f, dn3=0.f;
    float acc[8];
    #pragma unroll
    for (int k=0;k<8;k++) acc[k]=0.f;

    for (int j0 = beg; j0 < end; j0 += 64){
      int j = j0 + lane;
      int s = d;
      float ex0=0.f, ex1=0.f, ex2=0.f, ex3=0.f;
      if (j < end){
        s = csr_src[j];
        float4 es = *(const float4*)(esrc + (size_t)s*4);
        float e0 = es.x + ed4.x; e0 = (e0 > 0.f) ? e0 : 0.2f*e0;
        float e1 = es.y + ed4.y; e1 = (e1 > 0.f) ? e1 : 0.2f*e1;
        float e2 = es.z + ed4.z; e2 = (e2 > 0.f) ? e2 : 0.2f*e2;
        float e3 = es.w + ed4.w; e3 = (e3 > 0.f) ? e3 : 0.2f*e3;
        ex0 = expf(e0); ex1 = expf(e1); ex2 = expf(e2); ex3 = expf(e3);
        dn0 += ex0; dn1 += ex1; dn2 += ex2; dn3 += ex3;
      }
      int4 w0 = make_int4(s, __float_as_int(ex0), s, __float_as_int(ex1));
      int4 w1 = make_int4(s, __float_as_int(ex2), s, __float_as_int(ex3));
      *(int4*)&pk[w][lane][0] = w0;
      *(int4*)&pk[w][lane][2] = w1;
      int cnt2 = end - j0; if (cnt2 > 64) cnt2 = 64;
      const int ngrp = (cnt2 + 3) >> 2;   // padded slots have wt=0, src=d (safe)
      #pragma unroll 2
      for (int g = 0; g < ngrp; g++){
        int2 v = pg[g*16];
        float wg = __int_as_float(v.y);
        h16x8 hv = *(const h16x8*)(hbuf + (size_t)v.x*128 + c8*8);
        #pragma unroll
        for (int k=0;k<8;k++) acc[k] = fmaf((float)hv[k], wg, acc[k]);
      }
    }
    #pragma unroll
    for (int o = 32; o; o >>= 1){
      dn0 += __shfl_xor(dn0, o);
      dn1 += __shfl_xor(dn1, o);
      dn2 += __shfl_xor(dn2, o);
      dn3 += __shfl_xor(dn3, o);
    }
    float dsel = (hd==0) ? dn0 : (hd==1) ? dn1 : (hd==2) ? dn2 : dn3;
    float inv = 1.f / (dsel + 1e-16f);
    #pragma unroll
    for (int k=0;k<8;k++){
      acc[k] += __shfl_xor(acc[k], 16);
      acc[k] += __shfl_xor(acc[k], 32);
    }
    if (e == 0){
      float aw = (ntype[d] == 0) ? 1.5f : 1.0f;
      float o8[8];
      o8[0] = (acc[0]*inv + bbA.x) * aw;
      o8[1] = (acc[1]*inv + bbA.y) * aw;
      o8[2] = (acc[2]*inv + bbA.z) * aw;
      o8[3] = (acc[3]*inv + bbA.w) * aw;
      o8[4] = (acc[4]*inv + bbB.x) * aw;
      o8[5] = (acc[5]*inv + bbB.y) * aw;
      o8[6] = (acc[6]*inv + bbB.z) * aw;
      o8[7] = (acc[7]*inv + bbB.w) * aw;
      *(float4*)(y + (size_t)d*128 + c8*8)     = make_float4(o8[0],o8[1],o8[2],o8[3]);
      *(float4*)(y + (size_t)d*128 + c8*8 + 4) = make_float4(o8[4],o8[5],o8[6],o8[7]);
      #pragma unroll
      for (int k=0;k<8;k++){ bs[k] += o8[k]; bq[k] += o8[k]*o8[k]; }
    }
  }
  // block-level BN-stat reduce (reuse pk LDS as float[4][16][16])
  __syncthreads();
  float* bnp = (float*)pk;
  if (e == 0){
    float* q = bnp + (w*16 + c8)*16;
    #pragma unroll
    for (int k=0;k<8;k++){ q[k] = bs[k]; q[8+k] = bq[k]; }
  }
  __syncthreads();
  const int t = threadIdx.x;
  const int c = t & 127, stat = t >> 7;
  float v = 0.f;
  #pragma unroll
  for (int ww = 0; ww < 4; ww++)
    v += bnp[(ww*16 + (c>>3))*16 + stat*8 + (c&7)];
  bnpart[(size_t)blockIdx.x*256 + t] = v;
}

// ---------- BN partial reduce ----------
__global__ __launch_bounds__(256) void bn_reduce(const float* __restrict__ bnpart,
    double* __restrict__ bnsum, double* __restrict__ bnsumsq){
  const int t = threadIdx.x, b = blockIdx.x;   // 64 blocks
  float acc = 0.f;
  #pragma unroll 4
  for (int j = 0; j < GATB/64; j++)
    acc += bnpart[(size_t)(b*(GATB/64) + j)*256 + t];
  const int c = t & 127;
  if (t < 128) atomicAdd(bnsum + c, (double)acc);
  else         atomicAdd(bnsumsq + c, (double)acc);
}

// ---------- BN finalize ----------
__global__ void bn_final(const double* __restrict__ bnsum, const double* __restrict__ bnsumsq,
    const float* __restrict__ gma, const float* __restrict__ bta,
    float* __restrict__ scale, float* __restrict__ shift, int N){
  int c = threadIdx.x;
  double mu  = bnsum[c] / N;
  double var = bnsumsq[c] / N - mu*mu;
  if (var < 0.0) var = 0.0;
  float inv = (float)(1.0 / sqrt(var + 1e-5));
  float sc  = inv * gma[c];
  scale[c] = sc;
  shift[c] = bta[c] - (float)mu * sc;
}

// ---------- pool phase 1 ----------
__global__ __launch_bounds__(256) void pool_partial(const float* __restrict__ y,
    const int* __restrict__ batch, const float* __restrict__ scale,
    const float* __restrict__ shift, float* __restrict__ pooled){
  const int t = threadIdx.x;
  const int c = t & 127;
  const int sub = t >> 7;
  const int per = (NN + PB - 1) / PB;
  const int n0 = blockIdx.x * per;
  int n1 = n0 + per; if (n1 > NN) n1 = NN;
  const float sc = scale[c], sh = shift[c];
  float acc = 0.f;
  int curg = -1;
  for (int n = n0 + sub; n < n1; n += 2){
    int g = batch[n];
    if (g != curg){
      if (curg >= 0) unsafeAtomicAdd(pooled + (size_t)curg*128 + c, acc);
      curg = g; acc = 0.f;
    }
    float v = y[(size_t)n*128 + c];
    acc += fmaxf(fmaf(v, sc, sh), 0.f);
  }
  if (curg >= 0) unsafeAtomicAdd(pooled + (size_t)curg*128 + c, acc);
}

// ---------- pool phase 2: mean + MLP head ----------
__global__ __launch_bounds__(128) void mlp_head(const float* __restrict__ pooled,
    const int* __restrict__ batch, const float* __restrict__ fc1w,
    const float* __restrict__ fc1b, const float* __restrict__ fc2w,
    const float* __restrict__ fc2b, float* __restrict__ out){
  __shared__ float psh[128];
  __shared__ float hid[32];
  const int g = blockIdx.x, t = threadIdx.x;
  int lo = 0, hi = NN;
  while (lo < hi){ int mid = (lo+hi)>>1; if (batch[mid] < g) lo = mid+1; else hi = mid; }
  const int beg = lo;
  lo = beg; hi = NN;
  while (lo < hi){ int mid = (lo+hi)>>1; if (batch[mid] < g+1) lo = mid+1; else hi = mid; }
  int cntn = lo - beg; if (cntn < 1) cntn = 1;
  psh[t] = pooled[(size_t)g*128 + t] / (float)cntn;
  __syncthreads();
  if (t < 32){
    float a = fc1b[t];
    for (int k=0;k<128;k++) a += psh[k]*fc1w[k*32+t];
    a = (a > 0.f) ? a : 0.f;
    hid[t] = a * fc2w[t];
  }
  __syncthreads();
  if (t == 0){
    float sacc = fc2b[0];
    #pragma unroll
    for (int j=0;j<32;j++) sacc += hid[j];
    out[g] = sacc;
  }
}

extern "C" void kernel_launch(void* const* d_in, const int* in_sizes, int n_in,
                              void* d_out, int out_size, void* d_ws, size_t ws_size,
                              hipStream_t stream){
  const float* x     = (const float*)d_in[0];
  const int*   ei    = (const int*)d_in[1];
  const int*   ntype = (const int*)d_in[2];
  const int*   batch = (const int*)d_in[3];
  const float* Wl[3]  = {(const float*)d_in[4],  (const float*)d_in[10], (const float*)d_in[16]};
  const float* asl[3] = {(const float*)d_in[5],  (const float*)d_in[11], (const float*)d_in[17]};
  const float* adl[3] = {(const float*)d_in[6],  (const float*)d_in[12], (const float*)d_in[18]};
  const float* bl[3]  = {(const float*)d_in[7],  (const float*)d_in[13], (const float*)d_in[19]};
  const float* gl[3]  = {(const float*)d_in[8],  (const float*)d_in[14], (const float*)d_in[20]};
  const float* bel[3] = {(const float*)d_in[9],  (const float*)d_in[15], (const float*)d_in[21]};
  const float* fc1w = (const float*)d_in[22];
  const float* fc1b = (const float*)d_in[23];
  const float* fc2w = (const float*)d_in[24];
  const float* fc2b = (const float*)d_in[25];

  char* base = (char*)d_ws;
  size_t off = 0;
  auto alloc = [&](size_t bytes)->char*{
    size_t o = (off + 255) & ~(size_t)255; off = o + bytes; return base + o;
  };
  _Float16* hbuf = (_Float16*)alloc((size_t)NN*128*2);
  float* y       = (float*)alloc((size_t)NN*128*4);
  ushort* wfrag  = (ushort*)alloc((size_t)32768*2);
  ushort* eafrag = (ushort*)alloc((size_t)4096*2);
  float* esrc    = (float*)alloc((size_t)NN*4*4);
  float* edst    = (float*)alloc((size_t)NN*4*4);
  int*   cnt     = (int*)  alloc((size_t)NN*4);
  int*   rowptr  = (int*)  alloc((size_t)(NN+1)*4);
  int*   csr_src = (int*)  alloc((size_t)ET_*4);
  int*   btail   = (int*)  alloc((size_t)NBK*4);
  int2*  bkt     = (int2*) alloc((size_t)NBK*BCAP*8);
  int*   bsum    = (int*)  alloc((size_t)NB*4);
  float* bnpart  = (float*)alloc((size_t)GATB*256*4);
  double* bnsum  = (double*)alloc(128*8);
  double* bnsumsq= (double*)alloc(128*8);
  float* scale   = (float*)alloc(128*4);
  float* shift   = (float*)alloc(128*4);
  float* pooled  = (float*)alloc((size_t)NG*128*4);
  if (off > ws_size) return;

  // ---- CSR build v2 (once; reused by all 3 layers) ----
  hipMemsetAsync(btail, 0, (size_t)NBK*4, stream);
  hipMemsetAsync(pooled, 0, (size_t)NG*128*4, stream);
  bin_scatter<<<(ET_+2047)/2048, 256, 0, stream>>>(ei, btail, bkt);
  bucket_count<<<NBK, 256, 0, stream>>>(btail, bkt, cnt);
  scan_partial<<<NB, 256, 0, stream>>>(cnt, rowptr, bsum);
  scan_bsum<<<1, 256, 0, stream>>>(bsum);
  scan_add<<<NB, 256, 0, stream>>>(rowptr, bsum);
  bucket_scatter<<<NBK, 256, 0, stream>>>(btail, bkt, rowptr, csr_src);

  for (int l = 0; l < 3; l++){
    const float* in = (l==0) ? x : y;
    const float* scl = (l==0) ? nullptr : scale;
    const float* shf = (l==0) ? nullptr : shift;
    hipMemsetAsync(bnsum, 0, 128*8*2, stream);
    convwa<<<65, 256, 0, stream>>>(Wl[l], asl[l], adl[l], wfrag, eafrag);
    gemm_fused<<<GB, 512, 0, stream>>>(in, wfrag, eafrag, scl, shf,
                                       hbuf, esrc, edst, NN);
    gat_fused<<<GATB, 256, 0, stream>>>(rowptr, csr_src, esrc, edst, hbuf,
                                        bl[l], ntype, y, bnpart);
    bn_reduce<<<64, 256, 0, stream>>>(bnpart, bnsum, bnsumsq);
    bn_final<<<1, 128, 0, stream>>>(bnsum, bnsumsq, gl[l], bel[l], scale, shift, NN);
  }
  pool_partial<<<PB, 256, 0, stream>>>(y, batch, scale, shift, pooled);
  mlp_head<<<NG, 128, 0, stream>>>(pooled, batch, fc1w, fc1b, fc2w, fc2b, (float*)d_out);
}